// Round 8
// baseline (389.675 us; speedup 1.0000x reference)
//
#include <hip/hip_runtime.h>
#include <math.h>

#define N_NODES 10000
#define N_EDGES 320000
#define N_AUG   (N_EDGES + N_NODES)
#define HID     256

// bf16 round-to-nearest-even, as the low 16 bits of a uint
static __device__ __forceinline__ unsigned bf16rne(float f) {
  unsigned u = __float_as_uint(f);
  return (u + 0x7FFFu + ((u >> 16) & 1u)) >> 16;
}

// ---------------- degree + edge_attr segment sum ----------------
__global__ void k_deg(const int* __restrict__ dst, const float* __restrict__ ea,
                      int* __restrict__ deg, float* __restrict__ asum) {
  int e = blockIdx.x * blockDim.x + threadIdx.x;
  if (e < N_EDGES) {
    int d = dst[e];
    atomicAdd(&deg[d], 1);
    atomicAdd(&asum[d], ea[e]);
  }
}

// ------- exclusive scan of (deg+1) over 10000 nodes (parallel), + loop_attr --
__global__ void __launch_bounds__(256) k_scan(
    const int* __restrict__ deg, const float* __restrict__ asum,
    int* __restrict__ offs, float* __restrict__ lattr) {
  __shared__ int wsum[4];
  int t = threadIdx.x;
  int base = t * 40;
  int s = 0;
  for (int i = 0; i < 40; i++) {
    int n = base + i;
    if (n < N_NODES) s += deg[n] + 1;
  }
  int v = s;
  #pragma unroll
  for (int d = 1; d < 64; d <<= 1) {
    int u = __shfl_up(v, d);
    if ((t & 63) >= d) v += u;
  }
  if ((t & 63) == 63) wsum[t >> 6] = v;
  __syncthreads();
  int wb = 0;
  for (int i = 0; i < (t >> 6); i++) wb += wsum[i];
  int run = wb + v - s;
  for (int i = 0; i < 40; i++) {
    int n = base + i;
    if (n < N_NODES) {
      offs[n] = run;
      int d = deg[n];
      run += d + 1;
      lattr[n] = asum[n] / (float)max(d, 1);
    }
  }
  if (t == 255) offs[N_NODES] = wb + v;
}

// ------- scatter edges (incl. self loops) into CSR by dst, packed (src,ea) --
__global__ void k_scatter(const int* __restrict__ src, const int* __restrict__ dst,
                          const float* __restrict__ ea, const float* __restrict__ lattr,
                          const int* __restrict__ offs, int* __restrict__ cursor,
                          int2* __restrict__ cpk) {
  int e = blockIdx.x * blockDim.x + threadIdx.x;
  if (e >= N_AUG) return;
  int s, d; float a;
  if (e < N_EDGES) { s = src[e]; d = dst[e]; a = ea[e]; }
  else             { s = e - N_EDGES; d = s; a = lattr[s]; }
  int pos = offs[d] + atomicAdd(&cursor[d], 1);
  cpk[pos] = make_int2(s, __float_as_int(a));
}

// ---------------- conv1: fully fused, vector broadcast loads, 8-edge unroll -
#define C1_EDGE(xs, av, l0, l1, l2, l3, p)                                              \
  {                                                                                     \
    l0 = fmaf(xs.x,wl0.x, fmaf(xs.y,wl1.x, fmaf(xs.z,wl2.x, fmaf(xs.w,wl3.x, blv.x)))); \
    l1 = fmaf(xs.x,wl0.y, fmaf(xs.y,wl1.y, fmaf(xs.z,wl2.y, fmaf(xs.w,wl3.y, blv.y)))); \
    l2 = fmaf(xs.x,wl0.z, fmaf(xs.y,wl1.z, fmaf(xs.z,wl2.z, fmaf(xs.w,wl3.z, blv.z)))); \
    l3 = fmaf(xs.x,wl0.w, fmaf(xs.y,wl1.w, fmaf(xs.z,wl2.w, fmaf(xs.w,wl3.w, blv.w)))); \
    float m0 = l0 + fmaf(av, we.x, r4.x); m0 = fmaxf(m0, 0.2f*m0);                      \
    float m1 = l1 + fmaf(av, we.y, r4.y); m1 = fmaxf(m1, 0.2f*m1);                      \
    float m2 = l2 + fmaf(av, we.z, r4.z); m2 = fmaxf(m2, 0.2f*m2);                      \
    float m3 = l3 + fmaf(av, we.w, r4.w); m3 = fmaxf(m3, 0.2f*m3);                      \
    p = m0*at.x + m1*at.y + m2*at.z + m3*at.w;                                          \
  }

__global__ void __launch_bounds__(256) k_conv1(
    const float* __restrict__ x,
    const float* __restrict__ Wl, const float* __restrict__ bl,
    const float* __restrict__ Wr, const float* __restrict__ br,
    const float* __restrict__ We, const float* __restrict__ att,
    const int* __restrict__ offs, const int2* __restrict__ cpk,
    const float* __restrict__ bias, const float* __restrict__ g,
    const float* __restrict__ be, float* __restrict__ hout) {
  int t = threadIdx.x;
  int n = blockIdx.x * 4 + (t >> 6);
  int c = 4 * (t & 63);

  float4 wl0 = *(const float4*)&Wl[0*HID + c];
  float4 wl1 = *(const float4*)&Wl[1*HID + c];
  float4 wl2 = *(const float4*)&Wl[2*HID + c];
  float4 wl3 = *(const float4*)&Wl[3*HID + c];
  float4 blv = *(const float4*)&bl[c];
  float4 we  = *(const float4*)&We[c];
  float4 at  = *(const float4*)&att[c];

  float4 xn = *(const float4*)&x[n*4];
  float4 r4;
  {
    float4 wr0 = *(const float4*)&Wr[0*HID + c];
    float4 wr1 = *(const float4*)&Wr[1*HID + c];
    float4 wr2 = *(const float4*)&Wr[2*HID + c];
    float4 wr3 = *(const float4*)&Wr[3*HID + c];
    float4 brv = *(const float4*)&br[c];
    r4.x = fmaf(xn.x,wr0.x, fmaf(xn.y,wr1.x, fmaf(xn.z,wr2.x, fmaf(xn.w,wr3.x, brv.x))));
    r4.y = fmaf(xn.x,wr0.y, fmaf(xn.y,wr1.y, fmaf(xn.z,wr2.y, fmaf(xn.w,wr3.y, brv.y))));
    r4.z = fmaf(xn.x,wr0.z, fmaf(xn.y,wr1.z, fmaf(xn.z,wr2.z, fmaf(xn.w,wr3.z, brv.z))));
    r4.w = fmaf(xn.x,wr0.w, fmaf(xn.y,wr1.w, fmaf(xn.z,wr2.w, fmaf(xn.w,wr3.w, brv.w))));
  }

  int js = __builtin_amdgcn_readfirstlane(offs[n]);
  int je = __builtin_amdgcn_readfirstlane(offs[n+1]);

  float D = 0.f, a0 = 0.f, a1 = 0.f, a2 = 0.f, a3 = 0.f;

  int j = js;
  for (; j + 7 < je; j += 8) {
    int2 eA = cpk[j],   eB = cpk[j+1], eC = cpk[j+2], eD = cpk[j+3];
    int2 eE = cpk[j+4], eF = cpk[j+5], eG = cpk[j+6], eH = cpk[j+7];
    float4 xA = *(const float4*)&x[eA.x*4];
    float4 xB = *(const float4*)&x[eB.x*4];
    float4 xC = *(const float4*)&x[eC.x*4];
    float4 xD = *(const float4*)&x[eD.x*4];
    float4 xE = *(const float4*)&x[eE.x*4];
    float4 xF = *(const float4*)&x[eF.x*4];
    float4 xG = *(const float4*)&x[eG.x*4];
    float4 xH = *(const float4*)&x[eH.x*4];
    float avA = __int_as_float(eA.y), avB = __int_as_float(eB.y);
    float avC = __int_as_float(eC.y), avD = __int_as_float(eD.y);
    float avE = __int_as_float(eE.y), avF = __int_as_float(eF.y);
    float avG = __int_as_float(eG.y), avH = __int_as_float(eH.y);

    float lA0,lA1,lA2,lA3,pA, lB0,lB1,lB2,lB3,pB;
    float lC0,lC1,lC2,lC3,pC, lD0,lD1,lD2,lD3,pD;
    float lE0,lE1,lE2,lE3,pE, lF0,lF1,lF2,lF3,pF;
    float lG0,lG1,lG2,lG3,pG, lH0,lH1,lH2,lH3,pH;
    C1_EDGE(xA, avA, lA0,lA1,lA2,lA3, pA);
    C1_EDGE(xB, avB, lB0,lB1,lB2,lB3, pB);
    C1_EDGE(xC, avC, lC0,lC1,lC2,lC3, pC);
    C1_EDGE(xD, avD, lD0,lD1,lD2,lD3, pD);
    C1_EDGE(xE, avE, lE0,lE1,lE2,lE3, pE);
    C1_EDGE(xF, avF, lF0,lF1,lF2,lF3, pF);
    C1_EDGE(xG, avG, lG0,lG1,lG2,lG3, pG);
    C1_EDGE(xH, avH, lH0,lH1,lH2,lH3, pH);

    #pragma unroll
    for (int msk = 1; msk < 16; msk <<= 1) {
      pA += __shfl_xor(pA, msk); pB += __shfl_xor(pB, msk);
      pC += __shfl_xor(pC, msk); pD += __shfl_xor(pD, msk);
      pE += __shfl_xor(pE, msk); pF += __shfl_xor(pF, msk);
      pG += __shfl_xor(pG, msk); pH += __shfl_xor(pH, msk);
    }
    float eAx = expf(pA), eBx = expf(pB), eCx = expf(pC), eDx = expf(pD);
    float eEx = expf(pE), eFx = expf(pF), eGx = expf(pG), eHx = expf(pH);
    D += ((eAx + eBx) + (eCx + eDx)) + ((eEx + eFx) + (eGx + eHx));
    a0 = fmaf(eDx, lD0, fmaf(eCx, lC0, fmaf(eBx, lB0, fmaf(eAx, lA0, a0))));
    a0 = fmaf(eHx, lH0, fmaf(eGx, lG0, fmaf(eFx, lF0, fmaf(eEx, lE0, a0))));
    a1 = fmaf(eDx, lD1, fmaf(eCx, lC1, fmaf(eBx, lB1, fmaf(eAx, lA1, a1))));
    a1 = fmaf(eHx, lH1, fmaf(eGx, lG1, fmaf(eFx, lF1, fmaf(eEx, lE1, a1))));
    a2 = fmaf(eDx, lD2, fmaf(eCx, lC2, fmaf(eBx, lB2, fmaf(eAx, lA2, a2))));
    a2 = fmaf(eHx, lH2, fmaf(eGx, lG2, fmaf(eFx, lF2, fmaf(eEx, lE2, a2))));
    a3 = fmaf(eDx, lD3, fmaf(eCx, lC3, fmaf(eBx, lB3, fmaf(eAx, lA3, a3))));
    a3 = fmaf(eHx, lH3, fmaf(eGx, lG3, fmaf(eFx, lF3, fmaf(eEx, lE3, a3))));
  }
  for (; j < je; j++) {
    int2 eA = cpk[j];
    float4 xA = *(const float4*)&x[eA.x*4];
    float avA = __int_as_float(eA.y);
    float lA0,lA1,lA2,lA3,pA;
    C1_EDGE(xA, avA, lA0,lA1,lA2,lA3, pA);
    #pragma unroll
    for (int msk = 1; msk < 16; msk <<= 1) pA += __shfl_xor(pA, msk);
    float eAx = expf(pA);
    D += eAx;
    a0 = fmaf(eAx, lA0, a0);
    a1 = fmaf(eAx, lA1, a1);
    a2 = fmaf(eAx, lA2, a2);
    a3 = fmaf(eAx, lA3, a3);
  }

  float inv = 1.f / D;
  float4 b4 = *(const float4*)&bias[c];
  float o0 = fmaf(a0, inv, b4.x);
  float o1 = fmaf(a1, inv, b4.y);
  float o2 = fmaf(a2, inv, b4.z);
  float o3 = fmaf(a3, inv, b4.w);

  float s = o0 + o1 + o2 + o3;
  #pragma unroll
  for (int msk = 1; msk < 64; msk <<= 1) s += __shfl_xor(s, msk);
  float mu = s * (1.f / 256.f);
  float d0 = o0 - mu, d1 = o1 - mu, d2 = o2 - mu, d3 = o3 - mu;
  float sq = d0*d0 + d1*d1 + d2*d2 + d3*d3;
  #pragma unroll
  for (int msk = 1; msk < 64; msk <<= 1) sq += __shfl_xor(sq, msk);
  float rstd = rsqrtf(sq * (1.f / 256.f) + 1e-5f);
  float4 g4  = *(const float4*)&g[c];
  float4 be4 = *(const float4*)&be[c];
  float4 o;
  o.x = fmaxf(fmaf(d0 * rstd, g4.x, be4.x), 0.f);
  o.y = fmaxf(fmaf(d1 * rstd, g4.y, be4.y), 0.f);
  o.z = fmaxf(fmaf(d2 * rstd, g4.z, be4.z), 0.f);
  o.w = fmaxf(fmaf(d3 * rstd, g4.w, be4.w), 0.f);
  *(float4*)&hout[n*HID + c] = o;
}

// ---------------- conv2: bf16-packed gather, no online max, 8-edge unroll ---
#define C2_LOAD(q, xs)                                  \
  float4 xs;                                            \
  xs.x = __uint_as_float(q.x << 16);                    \
  xs.y = __uint_as_float(q.x & 0xFFFF0000u);            \
  xs.z = __uint_as_float(q.y << 16);                    \
  xs.w = __uint_as_float(q.y & 0xFFFF0000u);

#define C2_EDGE(xs, av, p)                                        \
  {                                                               \
    float m0 = xs.x + fmaf(av, we.x, r4.x); m0 = fmaxf(m0, 0.2f*m0); \
    float m1 = xs.y + fmaf(av, we.y, r4.y); m1 = fmaxf(m1, 0.2f*m1); \
    float m2 = xs.z + fmaf(av, we.z, r4.z); m2 = fmaxf(m2, 0.2f*m2); \
    float m3 = xs.w + fmaf(av, we.w, r4.w); m3 = fmaxf(m3, 0.2f*m3); \
    p = m0*at.x + m1*at.y + m2*at.z + m3*at.w;                    \
  }

__global__ void __launch_bounds__(256) k_conv2(
    const uint2* __restrict__ xlb, const float* __restrict__ xr,
    const int* __restrict__ offs, const int2* __restrict__ cpk,
    const float* __restrict__ We, const float* __restrict__ att,
    const float* __restrict__ bias, const float* __restrict__ g,
    const float* __restrict__ be, float* __restrict__ hout) {
  int t = threadIdx.x;
  int n = blockIdx.x * 4 + (t >> 6);
  int lane = t & 63;
  int c = 4 * lane;
  float4 r4 = *(const float4*)&xr[n*HID + c];
  float4 we = *(const float4*)&We[c];
  float4 at = *(const float4*)&att[c];
  int js = __builtin_amdgcn_readfirstlane(offs[n]);
  int je = __builtin_amdgcn_readfirstlane(offs[n+1]);

  float D = 0.f, a0 = 0.f, a1 = 0.f, a2 = 0.f, a3 = 0.f;

  int j = js;
  for (; j + 7 < je; j += 8) {
    int2 e0 = cpk[j],   e1 = cpk[j+1], e2 = cpk[j+2], e3 = cpk[j+3];
    int2 e4 = cpk[j+4], e5 = cpk[j+5], e6 = cpk[j+6], e7 = cpk[j+7];
    uint2 q0 = xlb[e0.x*64 + lane];
    uint2 q1 = xlb[e1.x*64 + lane];
    uint2 q2 = xlb[e2.x*64 + lane];
    uint2 q3 = xlb[e3.x*64 + lane];
    uint2 q4 = xlb[e4.x*64 + lane];
    uint2 q5 = xlb[e5.x*64 + lane];
    uint2 q6 = xlb[e6.x*64 + lane];
    uint2 q7 = xlb[e7.x*64 + lane];
    C2_LOAD(q0, xs0); C2_LOAD(q1, xs1); C2_LOAD(q2, xs2); C2_LOAD(q3, xs3);
    C2_LOAD(q4, xs4); C2_LOAD(q5, xs5); C2_LOAD(q6, xs6); C2_LOAD(q7, xs7);
    float av0 = __int_as_float(e0.y), av1 = __int_as_float(e1.y);
    float av2 = __int_as_float(e2.y), av3 = __int_as_float(e3.y);
    float av4 = __int_as_float(e4.y), av5 = __int_as_float(e5.y);
    float av6 = __int_as_float(e6.y), av7 = __int_as_float(e7.y);

    float p0,p1,p2,p3,p4,p5,p6,p7;
    C2_EDGE(xs0, av0, p0); C2_EDGE(xs1, av1, p1);
    C2_EDGE(xs2, av2, p2); C2_EDGE(xs3, av3, p3);
    C2_EDGE(xs4, av4, p4); C2_EDGE(xs5, av5, p5);
    C2_EDGE(xs6, av6, p6); C2_EDGE(xs7, av7, p7);
    #pragma unroll
    for (int msk = 1; msk < 64; msk <<= 1) {
      p0 += __shfl_xor(p0, msk); p1 += __shfl_xor(p1, msk);
      p2 += __shfl_xor(p2, msk); p3 += __shfl_xor(p3, msk);
      p4 += __shfl_xor(p4, msk); p5 += __shfl_xor(p5, msk);
      p6 += __shfl_xor(p6, msk); p7 += __shfl_xor(p7, msk);
    }
    float x0 = expf(p0), x1 = expf(p1), x2 = expf(p2), x3 = expf(p3);
    float x4 = expf(p4), x5 = expf(p5), x6 = expf(p6), x7 = expf(p7);
    D += ((x0 + x1) + (x2 + x3)) + ((x4 + x5) + (x6 + x7));
    a0 = fmaf(x3, xs3.x, fmaf(x2, xs2.x, fmaf(x1, xs1.x, fmaf(x0, xs0.x, a0))));
    a0 = fmaf(x7, xs7.x, fmaf(x6, xs6.x, fmaf(x5, xs5.x, fmaf(x4, xs4.x, a0))));
    a1 = fmaf(x3, xs3.y, fmaf(x2, xs2.y, fmaf(x1, xs1.y, fmaf(x0, xs0.y, a1))));
    a1 = fmaf(x7, xs7.y, fmaf(x6, xs6.y, fmaf(x5, xs5.y, fmaf(x4, xs4.y, a1))));
    a2 = fmaf(x3, xs3.z, fmaf(x2, xs2.z, fmaf(x1, xs1.z, fmaf(x0, xs0.z, a2))));
    a2 = fmaf(x7, xs7.z, fmaf(x6, xs6.z, fmaf(x5, xs5.z, fmaf(x4, xs4.z, a2))));
    a3 = fmaf(x3, xs3.w, fmaf(x2, xs2.w, fmaf(x1, xs1.w, fmaf(x0, xs0.w, a3))));
    a3 = fmaf(x7, xs7.w, fmaf(x6, xs6.w, fmaf(x5, xs5.w, fmaf(x4, xs4.w, a3))));
  }
  for (; j < je; j++) {
    int2 e0 = cpk[j];
    float av0 = __int_as_float(e0.y);
    uint2 q0 = xlb[e0.x*64 + lane];
    C2_LOAD(q0, xs0);
    float p0;
    C2_EDGE(xs0, av0, p0);
    #pragma unroll
    for (int msk = 1; msk < 64; msk <<= 1) p0 += __shfl_xor(p0, msk);
    float x0 = expf(p0);
    D += x0;
    a0 = fmaf(x0, xs0.x, a0);
    a1 = fmaf(x0, xs0.y, a1);
    a2 = fmaf(x0, xs0.z, a2);
    a3 = fmaf(x0, xs0.w, a3);
  }

  float inv = 1.f / D;
  float4 b4 = *(const float4*)&bias[c];
  float o0 = fmaf(a0, inv, b4.x);
  float o1 = fmaf(a1, inv, b4.y);
  float o2 = fmaf(a2, inv, b4.z);
  float o3 = fmaf(a3, inv, b4.w);

  float s = o0 + o1 + o2 + o3;
  #pragma unroll
  for (int msk = 1; msk < 64; msk <<= 1) s += __shfl_xor(s, msk);
  float mu = s * (1.f / 256.f);
  float d0 = o0 - mu, d1 = o1 - mu, d2 = o2 - mu, d3 = o3 - mu;
  float sq = d0*d0 + d1*d1 + d2*d2 + d3*d3;
  #pragma unroll
  for (int msk = 1; msk < 64; msk <<= 1) sq += __shfl_xor(sq, msk);
  float rstd = rsqrtf(sq * (1.f / 256.f) + 1e-5f);
  float4 g4  = *(const float4*)&g[c];
  float4 be4 = *(const float4*)&be[c];
  float4 o;
  o.x = fmaxf(fmaf(d0 * rstd, g4.x, be4.x), 0.f);
  o.y = fmaxf(fmaf(d1 * rstd, g4.y, be4.y), 0.f);
  o.z = fmaxf(fmaf(d2 * rstd, g4.z, be4.z), 0.f);
  o.w = fmaxf(fmaf(d3 * rstd, g4.w, be4.w), 0.f);
  *(float4*)&hout[n*HID + c] = o;
}

// ---------------- dual GEMM v3: W from L2, A staged per 128-k phase ---------
// 64x64 tile x2 outputs, 4x4/thread, 256 thr, grid (157,4) = 2512 waves.
// LDS = As[128][68] (34.8KB, 4 blocks/CU); only 2 barrier pairs total; the
// k-loop's W loads (256B/wave/k, L2-hot) pipeline freely -> VALU-bound.
__global__ void __launch_bounds__(256) k_gemm_dual(
    const float* __restrict__ A,
    const float* __restrict__ W1, const float* __restrict__ b1,
    const float* __restrict__ W2, const float* __restrict__ b2,
    uint2* __restrict__ O1b, float* __restrict__ O2) {
  __shared__ __align__(16) float As[128][68];
  int t = threadIdx.x;
  int r0 = blockIdx.x * 64;
  int c0 = blockIdx.y * 64;
  int tx = t & 15, ty = t >> 4;

  float acc1[4][4] = {{0}};
  float acc2[4][4] = {{0}};

  int sr = t >> 2;                 // staging row 0..63
  int kq = (t & 3) * 4;            // staging k-quarter base
  int arow = min(r0 + sr, N_NODES - 1);
  const float* W1p = W1 + c0 + 4*tx;
  const float* W2p = W2 + c0 + 4*tx;

  #pragma unroll
  for (int p = 0; p < 2; p++) {
    int kb = p * 128;
    const float* Ap = &A[arow*HID + kb + kq];
    __syncthreads();
    #pragma unroll
    for (int i = 0; i < 8; i++) {
      float4 av = *(const float4*)&Ap[16*i];
      As[kq + 16*i + 0][sr] = av.x;
      As[kq + 16*i + 1][sr] = av.y;
      As[kq + 16*i + 2][sr] = av.z;
      As[kq + 16*i + 3][sr] = av.w;
    }
    __syncthreads();
    #pragma unroll 16
    for (int k = 0; k < 128; k++) {
      float4 a4  = *(const float4*)&As[k][4*ty];
      float4 w14 = *(const float4*)&W1p[(kb + k)*HID];
      float4 w24 = *(const float4*)&W2p[(kb + k)*HID];
      const float aa[4]  = {a4.x, a4.y, a4.z, a4.w};
      const float ww1[4] = {w14.x, w14.y, w14.z, w14.w};
      const float ww2[4] = {w24.x, w24.y, w24.z, w24.w};
      #pragma unroll
      for (int i = 0; i < 4; i++)
        #pragma unroll
        for (int jj = 0; jj < 4; jj++) {
          acc1[i][jj] = fmaf(aa[i], ww1[jj], acc1[i][jj]);
          acc2[i][jj] = fmaf(aa[i], ww2[jj], acc2[i][jj]);
        }
    }
  }
  int cb = c0 + 4*tx;
  float4 b1v = *(const float4*)&b1[cb];
  float4 b2v = *(const float4*)&b2[cb];
  #pragma unroll
  for (int i = 0; i < 4; i++) {
    int r = r0 + 4*ty + i;
    if (r < N_NODES) {
      float o10 = acc1[i][0]+b1v.x, o11 = acc1[i][1]+b1v.y;
      float o12 = acc1[i][2]+b1v.z, o13 = acc1[i][3]+b1v.w;
      uint2 pk;
      pk.x = bf16rne(o10) | (bf16rne(o11) << 16);
      pk.y = bf16rne(o12) | (bf16rne(o13) << 16);
      O1b[r*64 + (cb >> 2)] = pk;
      float4 o2 = {acc2[i][0]+b2v.x, acc2[i][1]+b2v.y, acc2[i][2]+b2v.z, acc2[i][3]+b2v.w};
      *(float4*)&O2[r*HID + cb] = o2;
    }
  }
}

// ------- fused policy head v3: Wp1 from L2, A staged per 128-k phase --------
__global__ void __launch_bounds__(128) k_policy(
    const float* __restrict__ h,
    const float* __restrict__ Wp1, const float* __restrict__ bp1,
    const float* __restrict__ Wp2, const float* __restrict__ bp2,
    float* __restrict__ elg, float* __restrict__ tot) {
  __shared__ __align__(16) float smem[128 * 68];   // As[128][68] / hidl[64][132]
  __shared__ float wred[2];
  int t = threadIdx.x;
  int r0 = blockIdx.x * 64;
  int tx = t & 15, ty = t >> 4;   // tx: 8-col group, ty: 8-row group

  float acc[8][8] = {{0}};

  int sr = t >> 1;                 // staging row 0..63
  int kq = (t & 1) * 4;            // staging k base 0/4
  int arow = min(r0 + sr, N_NODES - 1);
  const float* Wp = Wp1 + 8*tx;

  #pragma unroll
  for (int p = 0; p < 2; p++) {
    int kb = p * 128;
    const float* Ap = &h[arow*HID + kb + kq];
    __syncthreads();
    #pragma unroll
    for (int i = 0; i < 16; i++) {
      float4 av = *(const float4*)&Ap[8*i];
      smem[(kq + 8*i + 0)*68 + sr] = av.x;
      smem[(kq + 8*i + 1)*68 + sr] = av.y;
      smem[(kq + 8*i + 2)*68 + sr] = av.z;
      smem[(kq + 8*i + 3)*68 + sr] = av.w;
    }
    __syncthreads();
    #pragma unroll 8
    for (int k = 0; k < 128; k++) {
      float4 aA = *(const float4*)&smem[k*68 + 8*ty];
      float4 aB = *(const float4*)&smem[k*68 + 8*ty + 4];
      float4 wA = *(const float4*)&Wp[(kb + k)*128];
      float4 wB = *(const float4*)&Wp[(kb + k)*128 + 4];
      const float aa[8] = {aA.x,aA.y,aA.z,aA.w, aB.x,aB.y,aB.z,aB.w};
      const float ww[8] = {wA.x,wA.y,wA.z,wA.w, wB.x,wB.y,wB.z,wB.w};
      #pragma unroll
      for (int i = 0; i < 8; i++)
        #pragma unroll
        for (int jj = 0; jj < 8; jj++)
          acc[i][jj] = fmaf(aa[i], ww[jj], acc[i][jj]);
    }
  }
  __syncthreads();   // As dead; smem becomes hidl[64][132]
  float* hidl = smem;
  int cbase = tx*8;
  float4 bA = *(const float4*)&bp1[cbase];
  float4 bB = *(const float4*)&bp1[cbase+4];
  const float bb[8] = {bA.x,bA.y,bA.z,bA.w, bB.x,bB.y,bB.z,bB.w};
  #pragma unroll
  for (int i = 0; i < 8; i++) {
    int r = ty*8 + i;
    float4 oA = {fmaxf(acc[i][0]+bb[0],0.f), fmaxf(acc[i][1]+bb[1],0.f),
                 fmaxf(acc[i][2]+bb[2],0.f), fmaxf(acc[i][3]+bb[3],0.f)};
    float4 oB = {fmaxf(acc[i][4]+bb[4],0.f), fmaxf(acc[i][5]+bb[5],0.f),
                 fmaxf(acc[i][6]+bb[6],0.f), fmaxf(acc[i][7]+bb[7],0.f)};
    *(float4*)&hidl[r*132 + cbase]     = oA;
    *(float4*)&hidl[r*132 + cbase + 4] = oB;
  }
  __syncthreads();
  float esum = 0.f;
  #pragma unroll
  for (int rep = 0; rep < 2; rep++) {
    int o = t + rep * 128;
    int nl = o >> 2, i = o & 3;
    float s = bp2[i];
    for (int k = 0; k < 128; k += 4) {
      float4 hv = *(const float4*)&hidl[nl*132 + k];
      s = fmaf(hv.x, Wp2[(k+0)*4 + i],
          fmaf(hv.y, Wp2[(k+1)*4 + i],
          fmaf(hv.z, Wp2[(k+2)*4 + i],
          fmaf(hv.w, Wp2[(k+3)*4 + i], s))));
    }
    int n = r0 + nl;
    if (n < N_NODES) {
      float e = expf(s);
      elg[n*4 + i] = e;
      esum += e;
    }
  }
  #pragma unroll
  for (int msk = 1; msk < 64; msk <<= 1) esum += __shfl_xor(esum, msk);
  if ((t & 63) == 0) wred[t >> 6] = esum;
  __syncthreads();
  if (t == 0) atomicAdd(tot, wred[0] + wred[1]);
}

// ---------------- normalize: out = elg * (1/tot) ----------------------------
__global__ void __launch_bounds__(1024) k_sm_final(const float* __restrict__ elg,
                                                   const float* __restrict__ tot,
                                                   float* __restrict__ out) {
  int i = blockIdx.x * 1024 + threadIdx.x;
  float inv = 1.f / tot[0];
  if (i < N_NODES * 4) out[i] = elg[i] * inv;
}

extern "C" void kernel_launch(void* const* d_in, const int* in_sizes, int n_in,
                              void* d_out, int out_size, void* d_ws, size_t ws_size,
                              hipStream_t stream) {
  const float* x    = (const float*)d_in[0];
  const int*   ei   = (const int*)  d_in[1];
  const float* ea   = (const float*)d_in[2];
  const float* Wl1  = (const float*)d_in[3];
  const float* bl1  = (const float*)d_in[4];
  const float* Wr1  = (const float*)d_in[5];
  const float* br1  = (const float*)d_in[6];
  const float* We1  = (const float*)d_in[7];
  const float* att1 = (const float*)d_in[8];
  const float* bias1= (const float*)d_in[9];
  const float* g1   = (const float*)d_in[10];
  const float* be1  = (const float*)d_in[11];
  const float* Wl2  = (const float*)d_in[12];
  const float* bl2  = (const float*)d_in[13];
  const float* Wr2  = (const float*)d_in[14];
  const float* br2  = (const float*)d_in[15];
  const float* We2  = (const float*)d_in[16];
  const float* att2 = (const float*)d_in[17];
  const float* bias2= (const float*)d_in[18];
  const float* g2   = (const float*)d_in[19];
  const float* be2  = (const float*)d_in[20];
  const float* Wp1  = (const float*)d_in[21];
  const float* bp1  = (const float*)d_in[22];
  const float* Wp2  = (const float*)d_in[23];
  const float* bp2  = (const float*)d_in[24];
  float* out = (float*)d_out;

  const int* srcp = ei;
  const int* dstp = ei + N_EDGES;

  // workspace layout: [deg | cursor | asum | tot] zeroed in ONE memset
  int*   deg    = (int*)d_ws;               // 10240
  int*   cursor = deg + 10240;              // 10240
  float* asum   = (float*)(cursor + 10240); // 10240
  float* tot    = asum + 10240;             // 16
  int*   offs   = (int*)(tot + 16);         // 10240
  float* lattr  = (float*)(offs + 10240);   // 10240
  int2*  cpk    = (int2*)(lattr + 10240);   // N_AUG (+pad) int2
  float* h1     = (float*)(cpk + 330752);   // 2560000 floats
  uint2* xl2b   = (uint2*)(h1 + 2560000);   // 640000 uint2 (bf16-packed xl2)
  float* xr2    = (float*)(xl2b + 640000);  // 2560000 floats
  float* elg    = xr2 + 2560000;            // 40960
  float* h2     = h1;                       // h1 dead after gemm

  hipMemsetAsync(deg, 0, (3 * 10240 + 16) * sizeof(int), stream);

  k_deg    <<<(N_EDGES + 255)/256, 256, 0, stream>>>(dstp, ea, deg, asum);
  k_scan   <<<1, 256, 0, stream>>>(deg, asum, offs, lattr);
  k_scatter<<<(N_AUG + 255)/256, 256, 0, stream>>>(srcp, dstp, ea, lattr, offs,
                                                   cursor, cpk);
  k_conv1  <<<N_NODES/4, 256, 0, stream>>>(x, Wl1, bl1, Wr1, br1, We1, att1,
                                           offs, cpk, bias1, g1, be1, h1);
  k_gemm_dual<<<dim3(157, 4), 256, 0, stream>>>(h1, Wl2, bl2, Wr2, br2, xl2b, xr2);
  k_conv2  <<<N_NODES/4, 256, 0, stream>>>(xl2b, xr2, offs, cpk,
                                           We2, att2, bias2, g2, be2, h2);
  k_policy <<<157, 128, 0, stream>>>(h2, Wp1, bp1, Wp2, bp2, elg, tot);
  k_sm_final<<<40, 1024, 0, stream>>>(elg, tot, out);
}

// Round 9
// 338.939 us; speedup vs baseline: 1.1497x; 1.1497x over previous
//
#include <hip/hip_runtime.h>
#include <math.h>

#define N_NODES 10000
#define N_EDGES 320000
#define N_AUG   (N_EDGES + N_NODES)
#define HID     256

typedef short short8 __attribute__((ext_vector_type(8)));
typedef float floatx16 __attribute__((ext_vector_type(16)));

// bf16 round-to-nearest-even, as the low 16 bits of a uint
static __device__ __forceinline__ unsigned bf16rne(float f) {
  unsigned u = __float_as_uint(f);
  return (u + 0x7FFFu + ((u >> 16) & 1u)) >> 16;
}

// ---------------- degree + edge_attr segment sum ----------------
__global__ void k_deg(const int* __restrict__ dst, const float* __restrict__ ea,
                      int* __restrict__ deg, float* __restrict__ asum) {
  int e = blockIdx.x * blockDim.x + threadIdx.x;
  if (e < N_EDGES) {
    int d = dst[e];
    atomicAdd(&deg[d], 1);
    atomicAdd(&asum[d], ea[e]);
  }
}

// ------- exclusive scan of (deg+1) over 10000 nodes (parallel), + loop_attr --
__global__ void __launch_bounds__(256) k_scan(
    const int* __restrict__ deg, const float* __restrict__ asum,
    int* __restrict__ offs, float* __restrict__ lattr) {
  __shared__ int wsum[4];
  int t = threadIdx.x;
  int base = t * 40;
  int s = 0;
  for (int i = 0; i < 40; i++) {
    int n = base + i;
    if (n < N_NODES) s += deg[n] + 1;
  }
  int v = s;
  #pragma unroll
  for (int d = 1; d < 64; d <<= 1) {
    int u = __shfl_up(v, d);
    if ((t & 63) >= d) v += u;
  }
  if ((t & 63) == 63) wsum[t >> 6] = v;
  __syncthreads();
  int wb = 0;
  for (int i = 0; i < (t >> 6); i++) wb += wsum[i];
  int run = wb + v - s;
  for (int i = 0; i < 40; i++) {
    int n = base + i;
    if (n < N_NODES) {
      offs[n] = run;
      int d = deg[n];
      run += d + 1;
      lattr[n] = asum[n] / (float)max(d, 1);
    }
  }
  if (t == 255) offs[N_NODES] = wb + v;
}

// ------- scatter edges (incl. self loops) into CSR by dst, packed (src,ea) --
__global__ void k_scatter(const int* __restrict__ src, const int* __restrict__ dst,
                          const float* __restrict__ ea, const float* __restrict__ lattr,
                          const int* __restrict__ offs, int* __restrict__ cursor,
                          int2* __restrict__ cpk) {
  int e = blockIdx.x * blockDim.x + threadIdx.x;
  if (e >= N_AUG) return;
  int s, d; float a;
  if (e < N_EDGES) { s = src[e]; d = dst[e]; a = ea[e]; }
  else             { s = e - N_EDGES; d = s; a = lattr[s]; }
  int pos = offs[d] + atomicAdd(&cursor[d], 1);
  cpk[pos] = make_int2(s, __float_as_int(a));
}

// ------- convert W1|W2 (fp32 [k][n]) -> Wt (bf16 [n][k], n in 0..511) -------
__global__ void __launch_bounds__(256) k_cvtw(
    const float* __restrict__ W1, const float* __restrict__ W2,
    unsigned short* __restrict__ Wt) {
  __shared__ float tile[32][33];
  const float* W = blockIdx.z ? W2 : W1;
  int rowoff = blockIdx.z * 256;
  int kb = blockIdx.x * 32, nb = blockIdx.y * 32;
  int t = threadIdx.x;
  int tx = t & 31, ty = t >> 5;
  #pragma unroll
  for (int rep = 0; rep < 4; rep++)
    tile[ty + 8*rep][tx] = W[(kb + ty + 8*rep)*HID + nb + tx];
  __syncthreads();
  #pragma unroll
  for (int rep = 0; rep < 4; rep++) {
    int n = nb + ty + 8*rep;
    Wt[(rowoff + n)*256 + kb + tx] = (unsigned short)bf16rne(tile[tx][ty + 8*rep]);
  }
}

// ---------------- conv1: fully fused, 8-edge unroll, bf16-packed output -----
#define C1_EDGE(xs, av, l0, l1, l2, l3, p)                                              \
  {                                                                                     \
    l0 = fmaf(xs.x,wl0.x, fmaf(xs.y,wl1.x, fmaf(xs.z,wl2.x, fmaf(xs.w,wl3.x, blv.x)))); \
    l1 = fmaf(xs.x,wl0.y, fmaf(xs.y,wl1.y, fmaf(xs.z,wl2.y, fmaf(xs.w,wl3.y, blv.y)))); \
    l2 = fmaf(xs.x,wl0.z, fmaf(xs.y,wl1.z, fmaf(xs.z,wl2.z, fmaf(xs.w,wl3.z, blv.z)))); \
    l3 = fmaf(xs.x,wl0.w, fmaf(xs.y,wl1.w, fmaf(xs.z,wl2.w, fmaf(xs.w,wl3.w, blv.w)))); \
    float m0 = l0 + fmaf(av, we.x, r4.x); m0 = fmaxf(m0, 0.2f*m0);                      \
    float m1 = l1 + fmaf(av, we.y, r4.y); m1 = fmaxf(m1, 0.2f*m1);                      \
    float m2 = l2 + fmaf(av, we.z, r4.z); m2 = fmaxf(m2, 0.2f*m2);                      \
    float m3 = l3 + fmaf(av, we.w, r4.w); m3 = fmaxf(m3, 0.2f*m3);                      \
    p = m0*at.x + m1*at.y + m2*at.z + m3*at.w;                                          \
  }

__global__ void __launch_bounds__(256) k_conv1(
    const float* __restrict__ x,
    const float* __restrict__ Wl, const float* __restrict__ bl,
    const float* __restrict__ Wr, const float* __restrict__ br,
    const float* __restrict__ We, const float* __restrict__ att,
    const int* __restrict__ offs, const int2* __restrict__ cpk,
    const float* __restrict__ bias, const float* __restrict__ g,
    const float* __restrict__ be, uint2* __restrict__ h1b) {
  int t = threadIdx.x;
  int n = blockIdx.x * 4 + (t >> 6);
  int c = 4 * (t & 63);

  float4 wl0 = *(const float4*)&Wl[0*HID + c];
  float4 wl1 = *(const float4*)&Wl[1*HID + c];
  float4 wl2 = *(const float4*)&Wl[2*HID + c];
  float4 wl3 = *(const float4*)&Wl[3*HID + c];
  float4 blv = *(const float4*)&bl[c];
  float4 we  = *(const float4*)&We[c];
  float4 at  = *(const float4*)&att[c];

  float4 xn = *(const float4*)&x[n*4];
  float4 r4;
  {
    float4 wr0 = *(const float4*)&Wr[0*HID + c];
    float4 wr1 = *(const float4*)&Wr[1*HID + c];
    float4 wr2 = *(const float4*)&Wr[2*HID + c];
    float4 wr3 = *(const float4*)&Wr[3*HID + c];
    float4 brv = *(const float4*)&br[c];
    r4.x = fmaf(xn.x,wr0.x, fmaf(xn.y,wr1.x, fmaf(xn.z,wr2.x, fmaf(xn.w,wr3.x, brv.x))));
    r4.y = fmaf(xn.x,wr0.y, fmaf(xn.y,wr1.y, fmaf(xn.z,wr2.y, fmaf(xn.w,wr3.y, brv.y))));
    r4.z = fmaf(xn.x,wr0.z, fmaf(xn.y,wr1.z, fmaf(xn.z,wr2.z, fmaf(xn.w,wr3.z, brv.z))));
    r4.w = fmaf(xn.x,wr0.w, fmaf(xn.y,wr1.w, fmaf(xn.z,wr2.w, fmaf(xn.w,wr3.w, brv.w))));
  }

  int js = __builtin_amdgcn_readfirstlane(offs[n]);
  int je = __builtin_amdgcn_readfirstlane(offs[n+1]);

  float D = 0.f, a0 = 0.f, a1 = 0.f, a2 = 0.f, a3 = 0.f;

  int j = js;
  for (; j + 7 < je; j += 8) {
    int2 eA = cpk[j],   eB = cpk[j+1], eC = cpk[j+2], eD = cpk[j+3];
    int2 eE = cpk[j+4], eF = cpk[j+5], eG = cpk[j+6], eH = cpk[j+7];
    float4 xA = *(const float4*)&x[eA.x*4];
    float4 xB = *(const float4*)&x[eB.x*4];
    float4 xC = *(const float4*)&x[eC.x*4];
    float4 xD = *(const float4*)&x[eD.x*4];
    float4 xE = *(const float4*)&x[eE.x*4];
    float4 xF = *(const float4*)&x[eF.x*4];
    float4 xG = *(const float4*)&x[eG.x*4];
    float4 xH = *(const float4*)&x[eH.x*4];
    float avA = __int_as_float(eA.y), avB = __int_as_float(eB.y);
    float avC = __int_as_float(eC.y), avD = __int_as_float(eD.y);
    float avE = __int_as_float(eE.y), avF = __int_as_float(eF.y);
    float avG = __int_as_float(eG.y), avH = __int_as_float(eH.y);

    float lA0,lA1,lA2,lA3,pA, lB0,lB1,lB2,lB3,pB;
    float lC0,lC1,lC2,lC3,pC, lD0,lD1,lD2,lD3,pD;
    float lE0,lE1,lE2,lE3,pE, lF0,lF1,lF2,lF3,pF;
    float lG0,lG1,lG2,lG3,pG, lH0,lH1,lH2,lH3,pH;
    C1_EDGE(xA, avA, lA0,lA1,lA2,lA3, pA);
    C1_EDGE(xB, avB, lB0,lB1,lB2,lB3, pB);
    C1_EDGE(xC, avC, lC0,lC1,lC2,lC3, pC);
    C1_EDGE(xD, avD, lD0,lD1,lD2,lD3, pD);
    C1_EDGE(xE, avE, lE0,lE1,lE2,lE3, pE);
    C1_EDGE(xF, avF, lF0,lF1,lF2,lF3, pF);
    C1_EDGE(xG, avG, lG0,lG1,lG2,lG3, pG);
    C1_EDGE(xH, avH, lH0,lH1,lH2,lH3, pH);

    #pragma unroll
    for (int msk = 1; msk < 16; msk <<= 1) {
      pA += __shfl_xor(pA, msk); pB += __shfl_xor(pB, msk);
      pC += __shfl_xor(pC, msk); pD += __shfl_xor(pD, msk);
      pE += __shfl_xor(pE, msk); pF += __shfl_xor(pF, msk);
      pG += __shfl_xor(pG, msk); pH += __shfl_xor(pH, msk);
    }
    float eAx = expf(pA), eBx = expf(pB), eCx = expf(pC), eDx = expf(pD);
    float eEx = expf(pE), eFx = expf(pF), eGx = expf(pG), eHx = expf(pH);
    D += ((eAx + eBx) + (eCx + eDx)) + ((eEx + eFx) + (eGx + eHx));
    a0 = fmaf(eDx, lD0, fmaf(eCx, lC0, fmaf(eBx, lB0, fmaf(eAx, lA0, a0))));
    a0 = fmaf(eHx, lH0, fmaf(eGx, lG0, fmaf(eFx, lF0, fmaf(eEx, lE0, a0))));
    a1 = fmaf(eDx, lD1, fmaf(eCx, lC1, fmaf(eBx, lB1, fmaf(eAx, lA1, a1))));
    a1 = fmaf(eHx, lH1, fmaf(eGx, lG1, fmaf(eFx, lF1, fmaf(eEx, lE1, a1))));
    a2 = fmaf(eDx, lD2, fmaf(eCx, lC2, fmaf(eBx, lB2, fmaf(eAx, lA2, a2))));
    a2 = fmaf(eHx, lH2, fmaf(eGx, lG2, fmaf(eFx, lF2, fmaf(eEx, lE2, a2))));
    a3 = fmaf(eDx, lD3, fmaf(eCx, lC3, fmaf(eBx, lB3, fmaf(eAx, lA3, a3))));
    a3 = fmaf(eHx, lH3, fmaf(eGx, lG3, fmaf(eFx, lF3, fmaf(eEx, lE3, a3))));
  }
  for (; j < je; j++) {
    int2 eA = cpk[j];
    float4 xA = *(const float4*)&x[eA.x*4];
    float avA = __int_as_float(eA.y);
    float lA0,lA1,lA2,lA3,pA;
    C1_EDGE(xA, avA, lA0,lA1,lA2,lA3, pA);
    #pragma unroll
    for (int msk = 1; msk < 16; msk <<= 1) pA += __shfl_xor(pA, msk);
    float eAx = expf(pA);
    D += eAx;
    a0 = fmaf(eAx, lA0, a0);
    a1 = fmaf(eAx, lA1, a1);
    a2 = fmaf(eAx, lA2, a2);
    a3 = fmaf(eAx, lA3, a3);
  }

  float inv = 1.f / D;
  float4 b4 = *(const float4*)&bias[c];
  float o0 = fmaf(a0, inv, b4.x);
  float o1 = fmaf(a1, inv, b4.y);
  float o2 = fmaf(a2, inv, b4.z);
  float o3 = fmaf(a3, inv, b4.w);

  float s = o0 + o1 + o2 + o3;
  #pragma unroll
  for (int msk = 1; msk < 64; msk <<= 1) s += __shfl_xor(s, msk);
  float mu = s * (1.f / 256.f);
  float d0 = o0 - mu, d1 = o1 - mu, d2 = o2 - mu, d3 = o3 - mu;
  float sq = d0*d0 + d1*d1 + d2*d2 + d3*d3;
  #pragma unroll
  for (int msk = 1; msk < 64; msk <<= 1) sq += __shfl_xor(sq, msk);
  float rstd = rsqrtf(sq * (1.f / 256.f) + 1e-5f);
  float4 g4  = *(const float4*)&g[c];
  float4 be4 = *(const float4*)&be[c];
  float oy0 = fmaxf(fmaf(d0 * rstd, g4.x, be4.x), 0.f);
  float oy1 = fmaxf(fmaf(d1 * rstd, g4.y, be4.y), 0.f);
  float oy2 = fmaxf(fmaf(d2 * rstd, g4.z, be4.z), 0.f);
  float oy3 = fmaxf(fmaf(d3 * rstd, g4.w, be4.w), 0.f);
  uint2 pk;
  pk.x = bf16rne(oy0) | (bf16rne(oy1) << 16);
  pk.y = bf16rne(oy2) | (bf16rne(oy3) << 16);
  h1b[n*64 + (t & 63)] = pk;
}

// ---------------- conv2: bf16-packed gather, no online max, 8-edge unroll ---
#define C2_LOAD(q, xs)                                  \
  float4 xs;                                            \
  xs.x = __uint_as_float(q.x << 16);                    \
  xs.y = __uint_as_float(q.x & 0xFFFF0000u);            \
  xs.z = __uint_as_float(q.y << 16);                    \
  xs.w = __uint_as_float(q.y & 0xFFFF0000u);

#define C2_EDGE(xs, av, p)                                        \
  {                                                               \
    float m0 = xs.x + fmaf(av, we.x, r4.x); m0 = fmaxf(m0, 0.2f*m0); \
    float m1 = xs.y + fmaf(av, we.y, r4.y); m1 = fmaxf(m1, 0.2f*m1); \
    float m2 = xs.z + fmaf(av, we.z, r4.z); m2 = fmaxf(m2, 0.2f*m2); \
    float m3 = xs.w + fmaf(av, we.w, r4.w); m3 = fmaxf(m3, 0.2f*m3); \
    p = m0*at.x + m1*at.y + m2*at.z + m3*at.w;                    \
  }

__global__ void __launch_bounds__(256) k_conv2(
    const uint2* __restrict__ xlb, const float* __restrict__ xr,
    const int* __restrict__ offs, const int2* __restrict__ cpk,
    const float* __restrict__ We, const float* __restrict__ att,
    const float* __restrict__ bias, const float* __restrict__ g,
    const float* __restrict__ be, float* __restrict__ hout) {
  int t = threadIdx.x;
  int n = blockIdx.x * 4 + (t >> 6);
  int lane = t & 63;
  int c = 4 * lane;
  float4 r4 = *(const float4*)&xr[n*HID + c];
  float4 we = *(const float4*)&We[c];
  float4 at = *(const float4*)&att[c];
  int js = __builtin_amdgcn_readfirstlane(offs[n]);
  int je = __builtin_amdgcn_readfirstlane(offs[n+1]);

  float D = 0.f, a0 = 0.f, a1 = 0.f, a2 = 0.f, a3 = 0.f;

  int j = js;
  for (; j + 7 < je; j += 8) {
    int2 e0 = cpk[j],   e1 = cpk[j+1], e2 = cpk[j+2], e3 = cpk[j+3];
    int2 e4 = cpk[j+4], e5 = cpk[j+5], e6 = cpk[j+6], e7 = cpk[j+7];
    uint2 q0 = xlb[e0.x*64 + lane];
    uint2 q1 = xlb[e1.x*64 + lane];
    uint2 q2 = xlb[e2.x*64 + lane];
    uint2 q3 = xlb[e3.x*64 + lane];
    uint2 q4 = xlb[e4.x*64 + lane];
    uint2 q5 = xlb[e5.x*64 + lane];
    uint2 q6 = xlb[e6.x*64 + lane];
    uint2 q7 = xlb[e7.x*64 + lane];
    C2_LOAD(q0, xs0); C2_LOAD(q1, xs1); C2_LOAD(q2, xs2); C2_LOAD(q3, xs3);
    C2_LOAD(q4, xs4); C2_LOAD(q5, xs5); C2_LOAD(q6, xs6); C2_LOAD(q7, xs7);
    float av0 = __int_as_float(e0.y), av1 = __int_as_float(e1.y);
    float av2 = __int_as_float(e2.y), av3 = __int_as_float(e3.y);
    float av4 = __int_as_float(e4.y), av5 = __int_as_float(e5.y);
    float av6 = __int_as_float(e6.y), av7 = __int_as_float(e7.y);

    float p0,p1,p2,p3,p4,p5,p6,p7;
    C2_EDGE(xs0, av0, p0); C2_EDGE(xs1, av1, p1);
    C2_EDGE(xs2, av2, p2); C2_EDGE(xs3, av3, p3);
    C2_EDGE(xs4, av4, p4); C2_EDGE(xs5, av5, p5);
    C2_EDGE(xs6, av6, p6); C2_EDGE(xs7, av7, p7);
    #pragma unroll
    for (int msk = 1; msk < 64; msk <<= 1) {
      p0 += __shfl_xor(p0, msk); p1 += __shfl_xor(p1, msk);
      p2 += __shfl_xor(p2, msk); p3 += __shfl_xor(p3, msk);
      p4 += __shfl_xor(p4, msk); p5 += __shfl_xor(p5, msk);
      p6 += __shfl_xor(p6, msk); p7 += __shfl_xor(p7, msk);
    }
    float x0 = expf(p0), x1 = expf(p1), x2 = expf(p2), x3 = expf(p3);
    float x4 = expf(p4), x5 = expf(p5), x6 = expf(p6), x7 = expf(p7);
    D += ((x0 + x1) + (x2 + x3)) + ((x4 + x5) + (x6 + x7));
    a0 = fmaf(x3, xs3.x, fmaf(x2, xs2.x, fmaf(x1, xs1.x, fmaf(x0, xs0.x, a0))));
    a0 = fmaf(x7, xs7.x, fmaf(x6, xs6.x, fmaf(x5, xs5.x, fmaf(x4, xs4.x, a0))));
    a1 = fmaf(x3, xs3.y, fmaf(x2, xs2.y, fmaf(x1, xs1.y, fmaf(x0, xs0.y, a1))));
    a1 = fmaf(x7, xs7.y, fmaf(x6, xs6.y, fmaf(x5, xs5.y, fmaf(x4, xs4.y, a1))));
    a2 = fmaf(x3, xs3.z, fmaf(x2, xs2.z, fmaf(x1, xs1.z, fmaf(x0, xs0.z, a2))));
    a2 = fmaf(x7, xs7.z, fmaf(x6, xs6.z, fmaf(x5, xs5.z, fmaf(x4, xs4.z, a2))));
    a3 = fmaf(x3, xs3.w, fmaf(x2, xs2.w, fmaf(x1, xs1.w, fmaf(x0, xs0.w, a3))));
    a3 = fmaf(x7, xs7.w, fmaf(x6, xs6.w, fmaf(x5, xs5.w, fmaf(x4, xs4.w, a3))));
  }
  for (; j < je; j++) {
    int2 e0 = cpk[j];
    float av0 = __int_as_float(e0.y);
    uint2 q0 = xlb[e0.x*64 + lane];
    C2_LOAD(q0, xs0);
    float p0;
    C2_EDGE(xs0, av0, p0);
    #pragma unroll
    for (int msk = 1; msk < 64; msk <<= 1) p0 += __shfl_xor(p0, msk);
    float x0 = expf(p0);
    D += x0;
    a0 = fmaf(x0, xs0.x, a0);
    a1 = fmaf(x0, xs0.y, a1);
    a2 = fmaf(x0, xs0.z, a2);
    a3 = fmaf(x0, xs0.w, a3);
  }

  float inv = 1.f / D;
  float4 b4 = *(const float4*)&bias[c];
  float o0 = fmaf(a0, inv, b4.x);
  float o1 = fmaf(a1, inv, b4.y);
  float o2 = fmaf(a2, inv, b4.z);
  float o3 = fmaf(a3, inv, b4.w);

  float s = o0 + o1 + o2 + o3;
  #pragma unroll
  for (int msk = 1; msk < 64; msk <<= 1) s += __shfl_xor(s, msk);
  float mu = s * (1.f / 256.f);
  float d0 = o0 - mu, d1 = o1 - mu, d2 = o2 - mu, d3 = o3 - mu;
  float sq = d0*d0 + d1*d1 + d2*d2 + d3*d3;
  #pragma unroll
  for (int msk = 1; msk < 64; msk <<= 1) sq += __shfl_xor(sq, msk);
  float rstd = rsqrtf(sq * (1.f / 256.f) + 1e-5f);
  float4 g4  = *(const float4*)&g[c];
  float4 be4 = *(const float4*)&be[c];
  float4 o;
  o.x = fmaxf(fmaf(d0 * rstd, g4.x, be4.x), 0.f);
  o.y = fmaxf(fmaf(d1 * rstd, g4.y, be4.y), 0.f);
  o.z = fmaxf(fmaf(d2 * rstd, g4.z, be4.z), 0.f);
  o.w = fmaxf(fmaf(d3 * rstd, g4.w, be4.w), 0.f);
  *(float4*)&hout[n*HID + c] = o;
}

// ---------------- dual GEMM v4: bf16 MFMA 32x32x16 --------------------------
// C[10000 x 512] = A(bf16) @ [W1|W2](bf16). Block: 64M x 128N, 4 waves, each
// wave 32x64 (2 accs). K staged 64-deep in LDS. Grid (157,4) = 2512 waves.
// y<2 -> O1 (bf16 out), y>=2 -> O2 (fp32 out).
__global__ void __launch_bounds__(256) k_gemm_dual(
    const unsigned short* __restrict__ h1b, const unsigned short* __restrict__ Wt,
    const float* __restrict__ b1, const float* __restrict__ b2,
    unsigned short* __restrict__ O1b, float* __restrict__ O2) {
  __shared__ unsigned short A_lds[64][72];
  __shared__ unsigned short W_lds[128][72];
  int t = threadIdx.x;
  int r0 = blockIdx.x * 64;
  int nb0 = blockIdx.y * 128;
  int l = t & 63;
  int wave = t >> 6;
  int wr = wave >> 1, wc = wave & 1;

  floatx16 acc[2] = {{0}, {0}};

  int sar = t >> 2, sak = (t & 3) * 16;
  int arow = min(r0 + sar, N_NODES - 1);
  int swn = t >> 1, swk = (t & 1) * 32;
  const unsigned short* Wrow = &Wt[(nb0 + swn) * 256];

  for (int kb = 0; kb < 256; kb += 64) {
    uint4 av0 = *(const uint4*)&h1b[arow*256 + kb + sak];
    uint4 av1 = *(const uint4*)&h1b[arow*256 + kb + sak + 8];
    uint4 wv0 = *(const uint4*)&Wrow[kb + swk];
    uint4 wv1 = *(const uint4*)&Wrow[kb + swk + 8];
    uint4 wv2 = *(const uint4*)&Wrow[kb + swk + 16];
    uint4 wv3 = *(const uint4*)&Wrow[kb + swk + 24];
    __syncthreads();
    *(uint4*)&A_lds[sar][sak]     = av0;
    *(uint4*)&A_lds[sar][sak + 8] = av1;
    *(uint4*)&W_lds[swn][swk]      = wv0;
    *(uint4*)&W_lds[swn][swk +  8] = wv1;
    *(uint4*)&W_lds[swn][swk + 16] = wv2;
    *(uint4*)&W_lds[swn][swk + 24] = wv3;
    __syncthreads();
    #pragma unroll
    for (int ks = 0; ks < 64; ks += 16) {
      short8 af  = *(const short8*)&A_lds[wr*32 + (l & 31)][ks + 8*(l >> 5)];
      short8 bf0 = *(const short8*)&W_lds[wc*64      + (l & 31)][ks + 8*(l >> 5)];
      short8 bf1 = *(const short8*)&W_lds[wc*64 + 32 + (l & 31)][ks + 8*(l >> 5)];
      acc[0] = __builtin_amdgcn_mfma_f32_32x32x16_bf16(af, bf0, acc[0], 0, 0, 0);
      acc[1] = __builtin_amdgcn_mfma_f32_32x32x16_bf16(af, bf1, acc[1], 0, 0, 0);
    }
  }

  bool isO1 = (nb0 < 256);
  #pragma unroll
  for (int tile = 0; tile < 2; tile++) {
    int col = nb0 + wc*64 + tile*32 + (l & 31);
    float bias = isO1 ? b1[col] : b2[col - 256];
    #pragma unroll
    for (int reg = 0; reg < 16; reg++) {
      int row = (reg & 3) + 8*(reg >> 2) + 4*(l >> 5);
      int r = r0 + wr*32 + row;
      if (r < N_NODES) {
        float v = acc[tile][reg] + bias;
        if (isO1) O1b[r*256 + col] = (unsigned short)bf16rne(v);
        else      O2[r*256 + (col - 256)] = v;
      }
    }
  }
}

// ------- fused policy head (R7): 64x128 tile, 8x8/thread, 128-dot + exp -----
__global__ void __launch_bounds__(128) k_policy(
    const float* __restrict__ h,
    const float* __restrict__ Wp1, const float* __restrict__ bp1,
    const float* __restrict__ Wp2, const float* __restrict__ bp2,
    float* __restrict__ elg, float* __restrict__ tot) {
  __shared__ __align__(16) float As[16][68];
  __shared__ __align__(16) float Ws[16][132];
  __shared__ __align__(16) float hidl[64][132];
  __shared__ float wred[2];
  int t = threadIdx.x;
  int r0 = blockIdx.x * 64;
  int tx = t & 15, ty = t >> 4;

  float acc[8][8] = {{0}};

  int ar  = t >> 1;
  int akh = (t & 1) * 8;
  int arow = min(r0 + ar, N_NODES - 1);
  int wk = t >> 3;
  int wc = (t & 7) * 16;

  for (int k0 = 0; k0 < HID; k0 += 16) {
    const float* Ap = &h[arow*HID + k0 + akh];
    float4 av0 = *(const float4*)&Ap[0];
    float4 av1 = *(const float4*)&Ap[4];
    const float* Wp = &Wp1[(k0+wk)*128 + wc];
    float4 wv0 = *(const float4*)&Wp[0];
    float4 wv1 = *(const float4*)&Wp[4];
    float4 wv2 = *(const float4*)&Wp[8];
    float4 wv3 = *(const float4*)&Wp[12];
    __syncthreads();
    As[akh+0][ar]=av0.x; As[akh+1][ar]=av0.y; As[akh+2][ar]=av0.z; As[akh+3][ar]=av0.w;
    As[akh+4][ar]=av1.x; As[akh+5][ar]=av1.y; As[akh+6][ar]=av1.z; As[akh+7][ar]=av1.w;
    *(float4*)&Ws[wk][wc+ 0] = wv0;
    *(float4*)&Ws[wk][wc+ 4] = wv1;
    *(float4*)&Ws[wk][wc+ 8] = wv2;
    *(float4*)&Ws[wk][wc+12] = wv3;
    __syncthreads();
    #pragma unroll
    for (int k = 0; k < 16; k++) {
      float4 aA = *(const float4*)&As[k][ty*8];
      float4 aB = *(const float4*)&As[k][ty*8+4];
      float4 wA = *(const float4*)&Ws[k][tx*8];
      float4 wB = *(const float4*)&Ws[k][tx*8+4];
      const float aa[8] = {aA.x,aA.y,aA.z,aA.w, aB.x,aB.y,aB.z,aB.w};
      const float ww[8] = {wA.x,wA.y,wA.z,wA.w, wB.x,wB.y,wB.z,wB.w};
      #pragma unroll
      for (int i = 0; i < 8; i++)
        #pragma unroll
        for (int jj = 0; jj < 8; jj++)
          acc[i][jj] = fmaf(aa[i], ww[jj], acc[i][jj]);
    }
  }
  int cbase = tx*8;
  float4 bA = *(const float4*)&bp1[cbase];
  float4 bB = *(const float4*)&bp1[cbase+4];
  const float bb[8] = {bA.x,bA.y,bA.z,bA.w, bB.x,bB.y,bB.z,bB.w};
  #pragma unroll
  for (int i = 0; i < 8; i++) {
    int r = ty*8 + i;
    float4 oA = {fmaxf(acc[i][0]+bb[0],0.f), fmaxf(acc[i][1]+bb[1],0.f),
                 fmaxf(acc[i][2]+bb[2],0.f), fmaxf(acc[i][3]+bb[3],0.f)};
    float4 oB = {fmaxf(acc[i][4]+bb[4],0.f), fmaxf(acc[i][5]+bb[5],0.f),
                 fmaxf(acc[i][6]+bb[6],0.f), fmaxf(acc[i][7]+bb[7],0.f)};
    *(float4*)&hidl[r][cbase]   = oA;
    *(float4*)&hidl[r][cbase+4] = oB;
  }
  __syncthreads();
  float esum = 0.f;
  #pragma unroll
  for (int rep = 0; rep < 2; rep++) {
    int o = t + rep * 128;
    int nl = o >> 2, i = o & 3;
    float s = bp2[i];
    for (int k = 0; k < 128; k += 4) {
      float4 hv = *(const float4*)&hidl[nl][k];
      s = fmaf(hv.x, Wp2[(k+0)*4 + i],
          fmaf(hv.y, Wp2[(k+1)*4 + i],
          fmaf(hv.z, Wp2[(k+2)*4 + i],
          fmaf(hv.w, Wp2[(k+3)*4 + i], s))));
    }
    int n = r0 + nl;
    if (n < N_NODES) {
      float e = expf(s);
      elg[n*4 + i] = e;
      esum += e;
    }
  }
  #pragma unroll
  for (int msk = 1; msk < 64; msk <<= 1) esum += __shfl_xor(esum, msk);
  if ((t & 63) == 0) wred[t >> 6] = esum;
  __syncthreads();
  if (t == 0) atomicAdd(tot, wred[0] + wred[1]);
}

// ---------------- normalize: out = elg * (1/tot) ----------------------------
__global__ void __launch_bounds__(1024) k_sm_final(const float* __restrict__ elg,
                                                   const float* __restrict__ tot,
                                                   float* __restrict__ out) {
  int i = blockIdx.x * 1024 + threadIdx.x;
  float inv = 1.f / tot[0];
  if (i < N_NODES * 4) out[i] = elg[i] * inv;
}

extern "C" void kernel_launch(void* const* d_in, const int* in_sizes, int n_in,
                              void* d_out, int out_size, void* d_ws, size_t ws_size,
                              hipStream_t stream) {
  const float* x    = (const float*)d_in[0];
  const int*   ei   = (const int*)  d_in[1];
  const float* ea   = (const float*)d_in[2];
  const float* Wl1  = (const float*)d_in[3];
  const float* bl1  = (const float*)d_in[4];
  const float* Wr1  = (const float*)d_in[5];
  const float* br1  = (const float*)d_in[6];
  const float* We1  = (const float*)d_in[7];
  const float* att1 = (const float*)d_in[8];
  const float* bias1= (const float*)d_in[9];
  const float* g1   = (const float*)d_in[10];
  const float* be1  = (const float*)d_in[11];
  const float* Wl2  = (const float*)d_in[12];
  const float* bl2  = (const float*)d_in[13];
  const float* Wr2  = (const float*)d_in[14];
  const float* br2  = (const float*)d_in[15];
  const float* We2  = (const float*)d_in[16];
  const float* att2 = (const float*)d_in[17];
  const float* bias2= (const float*)d_in[18];
  const float* g2   = (const float*)d_in[19];
  const float* be2  = (const float*)d_in[20];
  const float* Wp1  = (const float*)d_in[21];
  const float* bp1  = (const float*)d_in[22];
  const float* Wp2  = (const float*)d_in[23];
  const float* bp2  = (const float*)d_in[24];
  float* out = (float*)d_out;

  const int* srcp = ei;
  const int* dstp = ei + N_EDGES;

  // workspace layout: [deg | cursor | asum | tot] zeroed in ONE memset
  int*   deg    = (int*)d_ws;                // 10240
  int*   cursor = deg + 10240;               // 10240
  float* asum   = (float*)(cursor + 10240);  // 10240
  float* tot    = asum + 10240;              // 16
  int*   offs   = (int*)(tot + 16);          // 10240
  float* lattr  = (float*)(offs + 10240);    // 10240
  int2*  cpk    = (int2*)(lattr + 10240);    // N_AUG (+pad) int2
  unsigned short* h1b = (unsigned short*)(cpk + 330752);  // 10000x256 bf16 (5.12MB)
  float* h2     = (float*)h1b;               // fp32 conv2 output (reuses region)
  unsigned short* xl2bf = (unsigned short*)(h2 + 2560000); // 10000x256 bf16
  float* xr2    = (float*)(xl2bf + 2560000); // 2560000 floats
  float* elg    = xr2 + 2560000;             // 40960
  unsigned short* Wt = (unsigned short*)(elg + 40960);    // 512x256 bf16

  hipMemsetAsync(deg, 0, (3 * 10240 + 16) * sizeof(int), stream);

  k_cvtw   <<<dim3(8, 8, 2), 256, 0, stream>>>(Wl2, Wr2, Wt);
  k_deg    <<<(N_EDGES + 255)/256, 256, 0, stream>>>(dstp, ea, deg, asum);
  k_scan   <<<1, 256, 0, stream>>>(deg, asum, offs, lattr);
  k_scatter<<<(N_AUG + 255)/256, 256, 0, stream>>>(srcp, dstp, ea, lattr, offs,
                                                   cursor, cpk);
  k_conv1  <<<N_NODES/4, 256, 0, stream>>>(x, Wl1, bl1, Wr1, br1, We1, att1,
                                           offs, cpk, bias1, g1, be1, (uint2*)h1b);
  k_gemm_dual<<<dim3(157, 4), 256, 0, stream>>>(h1b, Wt, bl2, br2, xl2bf, xr2);
  k_conv2  <<<N_NODES/4, 256, 0, stream>>>((const uint2*)xl2bf, xr2, offs, cpk,
                                           We2, att2, bias2, g2, be2, h2);
  k_policy <<<157, 128, 0, stream>>>(h2, Wp1, bp1, Wp2, bp2, elg, tot);
  k_sm_final<<<40, 1024, 0, stream>>>(elg, tot, out);
}

// Round 10
// 314.444 us; speedup vs baseline: 1.2392x; 1.0779x over previous
//
#include <hip/hip_runtime.h>
#include <math.h>

#define N_NODES 10000
#define N_EDGES 320000
#define N_AUG   (N_EDGES + N_NODES)
#define HID     256

typedef short short8 __attribute__((ext_vector_type(8)));
typedef float floatx16 __attribute__((ext_vector_type(16)));

// bf16 round-to-nearest-even, as the low 16 bits of a uint
static __device__ __forceinline__ unsigned bf16rne(float f) {
  unsigned u = __float_as_uint(f);
  return (u + 0x7FFFu + ((u >> 16) & 1u)) >> 16;
}

// ---------------- degree + edge_attr segment sum ----------------
__global__ void k_deg(const int* __restrict__ dst, const float* __restrict__ ea,
                      int* __restrict__ deg, float* __restrict__ asum) {
  int e = blockIdx.x * blockDim.x + threadIdx.x;
  if (e < N_EDGES) {
    int d = dst[e];
    atomicAdd(&deg[d], 1);
    atomicAdd(&asum[d], ea[e]);
  }
}

// ------- exclusive scan of (deg+1) over 10000 nodes (parallel), + loop_attr --
__global__ void __launch_bounds__(256) k_scan(
    const int* __restrict__ deg, const float* __restrict__ asum,
    int* __restrict__ offs, float* __restrict__ lattr) {
  __shared__ int wsum[4];
  int t = threadIdx.x;
  int base = t * 40;
  int s = 0;
  for (int i = 0; i < 40; i++) {
    int n = base + i;
    if (n < N_NODES) s += deg[n] + 1;
  }
  int v = s;
  #pragma unroll
  for (int d = 1; d < 64; d <<= 1) {
    int u = __shfl_up(v, d);
    if ((t & 63) >= d) v += u;
  }
  if ((t & 63) == 63) wsum[t >> 6] = v;
  __syncthreads();
  int wb = 0;
  for (int i = 0; i < (t >> 6); i++) wb += wsum[i];
  int run = wb + v - s;
  for (int i = 0; i < 40; i++) {
    int n = base + i;
    if (n < N_NODES) {
      offs[n] = run;
      int d = deg[n];
      run += d + 1;
      lattr[n] = asum[n] / (float)max(d, 1);
    }
  }
  if (t == 255) offs[N_NODES] = wb + v;
}

// ------- scatter edges (incl. self loops) into CSR by dst, packed (src,ea) --
__global__ void k_scatter(const int* __restrict__ src, const int* __restrict__ dst,
                          const float* __restrict__ ea, const float* __restrict__ lattr,
                          const int* __restrict__ offs, int* __restrict__ cursor,
                          int2* __restrict__ cpk) {
  int e = blockIdx.x * blockDim.x + threadIdx.x;
  if (e >= N_AUG) return;
  int s, d; float a;
  if (e < N_EDGES) { s = src[e]; d = dst[e]; a = ea[e]; }
  else             { s = e - N_EDGES; d = s; a = lattr[s]; }
  int pos = offs[d] + atomicAdd(&cursor[d], 1);
  cpk[pos] = make_int2(s, __float_as_int(a));
}

// ------- convert W1|W2 (fp32 [k][n]) -> Wt (bf16 [n][k], n in 0..511) -------
__global__ void __launch_bounds__(256) k_cvtw(
    const float* __restrict__ W1, const float* __restrict__ W2,
    unsigned short* __restrict__ Wt) {
  __shared__ float tile[32][33];
  const float* W = blockIdx.z ? W2 : W1;
  int rowoff = blockIdx.z * 256;
  int kb = blockIdx.x * 32, nb = blockIdx.y * 32;
  int t = threadIdx.x;
  int tx = t & 31, ty = t >> 5;
  #pragma unroll
  for (int rep = 0; rep < 4; rep++)
    tile[ty + 8*rep][tx] = W[(kb + ty + 8*rep)*HID + nb + tx];
  __syncthreads();
  #pragma unroll
  for (int rep = 0; rep < 4; rep++) {
    int n = nb + ty + 8*rep;
    Wt[(rowoff + n)*256 + kb + tx] = (unsigned short)bf16rne(tile[tx][ty + 8*rep]);
  }
}

// ------- convert Wp1 (fp32 [256][128]) -> Wp1t (bf16 [n:128][k:256]) --------
__global__ void __launch_bounds__(256) k_cvtwp(
    const float* __restrict__ Wp1, unsigned short* __restrict__ Wp1t) {
  __shared__ float tile[32][33];
  int kb = blockIdx.x * 32, nb = blockIdx.y * 32;
  int t = threadIdx.x;
  int tx = t & 31, ty = t >> 5;
  #pragma unroll
  for (int rep = 0; rep < 4; rep++)
    tile[ty + 8*rep][tx] = Wp1[(kb + ty + 8*rep)*128 + nb + tx];
  __syncthreads();
  #pragma unroll
  for (int rep = 0; rep < 4; rep++) {
    int n = nb + ty + 8*rep;
    Wp1t[n*256 + kb + tx] = (unsigned short)bf16rne(tile[tx][ty + 8*rep]);
  }
}

// ---------------- conv1: fused xform recompute, 8-edge pipelined ------------
#define C1_EDGE(xs, av, l0, l1, l2, l3, p)                                              \
  {                                                                                     \
    l0 = fmaf(xs.x,wl0.x, fmaf(xs.y,wl1.x, fmaf(xs.z,wl2.x, fmaf(xs.w,wl3.x, blv.x)))); \
    l1 = fmaf(xs.x,wl0.y, fmaf(xs.y,wl1.y, fmaf(xs.z,wl2.y, fmaf(xs.w,wl3.y, blv.y)))); \
    l2 = fmaf(xs.x,wl0.z, fmaf(xs.y,wl1.z, fmaf(xs.z,wl2.z, fmaf(xs.w,wl3.z, blv.z)))); \
    l3 = fmaf(xs.x,wl0.w, fmaf(xs.y,wl1.w, fmaf(xs.z,wl2.w, fmaf(xs.w,wl3.w, blv.w)))); \
    float m0 = l0 + fmaf(av, we.x, r4.x); m0 = fmaxf(m0, 0.2f*m0);                      \
    float m1 = l1 + fmaf(av, we.y, r4.y); m1 = fmaxf(m1, 0.2f*m1);                      \
    float m2 = l2 + fmaf(av, we.z, r4.z); m2 = fmaxf(m2, 0.2f*m2);                      \
    float m3 = l3 + fmaf(av, we.w, r4.w); m3 = fmaxf(m3, 0.2f*m3);                      \
    p = m0*at.x + m1*at.y + m2*at.z + m3*at.w;                                          \
  }

// processes 8 resident edge records eA..eH
#define C1_PROC8()                                                              \
  {                                                                             \
    float4 xA = *(const float4*)&x[eA.x*4];                                     \
    float4 xB = *(const float4*)&x[eB.x*4];                                     \
    float4 xC = *(const float4*)&x[eC.x*4];                                     \
    float4 xD = *(const float4*)&x[eD.x*4];                                     \
    float4 xE = *(const float4*)&x[eE.x*4];                                     \
    float4 xF = *(const float4*)&x[eF.x*4];                                     \
    float4 xG = *(const float4*)&x[eG.x*4];                                     \
    float4 xH = *(const float4*)&x[eH.x*4];                                     \
    float avA = __int_as_float(eA.y), avB = __int_as_float(eB.y);               \
    float avC = __int_as_float(eC.y), avD = __int_as_float(eD.y);               \
    float avE = __int_as_float(eE.y), avF = __int_as_float(eF.y);               \
    float avG = __int_as_float(eG.y), avH = __int_as_float(eH.y);               \
    float lA0,lA1,lA2,lA3,pA, lB0,lB1,lB2,lB3,pB;                               \
    float lC0,lC1,lC2,lC3,pC, lD0,lD1,lD2,lD3,pD;                               \
    float lE0,lE1,lE2,lE3,pE, lF0,lF1,lF2,lF3,pF;                               \
    float lG0,lG1,lG2,lG3,pG, lH0,lH1,lH2,lH3,pH;                               \
    C1_EDGE(xA, avA, lA0,lA1,lA2,lA3, pA);                                      \
    C1_EDGE(xB, avB, lB0,lB1,lB2,lB3, pB);                                      \
    C1_EDGE(xC, avC, lC0,lC1,lC2,lC3, pC);                                      \
    C1_EDGE(xD, avD, lD0,lD1,lD2,lD3, pD);                                      \
    C1_EDGE(xE, avE, lE0,lE1,lE2,lE3, pE);                                      \
    C1_EDGE(xF, avF, lF0,lF1,lF2,lF3, pF);                                      \
    C1_EDGE(xG, avG, lG0,lG1,lG2,lG3, pG);                                      \
    C1_EDGE(xH, avH, lH0,lH1,lH2,lH3, pH);                                      \
    _Pragma("unroll")                                                           \
    for (int msk = 1; msk < 16; msk <<= 1) {                                    \
      pA += __shfl_xor(pA, msk); pB += __shfl_xor(pB, msk);                     \
      pC += __shfl_xor(pC, msk); pD += __shfl_xor(pD, msk);                     \
      pE += __shfl_xor(pE, msk); pF += __shfl_xor(pF, msk);                     \
      pG += __shfl_xor(pG, msk); pH += __shfl_xor(pH, msk);                     \
    }                                                                           \
    float eAx = expf(pA), eBx = expf(pB), eCx = expf(pC), eDx = expf(pD);       \
    float eEx = expf(pE), eFx = expf(pF), eGx = expf(pG), eHx = expf(pH);       \
    D += ((eAx + eBx) + (eCx + eDx)) + ((eEx + eFx) + (eGx + eHx));             \
    a0 = fmaf(eDx, lD0, fmaf(eCx, lC0, fmaf(eBx, lB0, fmaf(eAx, lA0, a0))));    \
    a0 = fmaf(eHx, lH0, fmaf(eGx, lG0, fmaf(eFx, lF0, fmaf(eEx, lE0, a0))));    \
    a1 = fmaf(eDx, lD1, fmaf(eCx, lC1, fmaf(eBx, lB1, fmaf(eAx, lA1, a1))));    \
    a1 = fmaf(eHx, lH1, fmaf(eGx, lG1, fmaf(eFx, lF1, fmaf(eEx, lE1, a1))));    \
    a2 = fmaf(eDx, lD2, fmaf(eCx, lC2, fmaf(eBx, lB2, fmaf(eAx, lA2, a2))));    \
    a2 = fmaf(eHx, lH2, fmaf(eGx, lG2, fmaf(eFx, lF2, fmaf(eEx, lE2, a2))));    \
    a3 = fmaf(eDx, lD3, fmaf(eCx, lC3, fmaf(eBx, lB3, fmaf(eAx, lA3, a3))));    \
    a3 = fmaf(eHx, lH3, fmaf(eGx, lG3, fmaf(eFx, lF3, fmaf(eEx, lE3, a3))));    \
  }

__global__ void __launch_bounds__(256) k_conv1(
    const float* __restrict__ x,
    const float* __restrict__ Wl, const float* __restrict__ bl,
    const float* __restrict__ Wr, const float* __restrict__ br,
    const float* __restrict__ We, const float* __restrict__ att,
    const int* __restrict__ offs, const int2* __restrict__ cpk,
    const float* __restrict__ bias, const float* __restrict__ g,
    const float* __restrict__ be, uint2* __restrict__ h1b) {
  int t = threadIdx.x;
  int n = blockIdx.x * 4 + (t >> 6);
  int c = 4 * (t & 63);

  float4 wl0 = *(const float4*)&Wl[0*HID + c];
  float4 wl1 = *(const float4*)&Wl[1*HID + c];
  float4 wl2 = *(const float4*)&Wl[2*HID + c];
  float4 wl3 = *(const float4*)&Wl[3*HID + c];
  float4 blv = *(const float4*)&bl[c];
  float4 we  = *(const float4*)&We[c];
  float4 at  = *(const float4*)&att[c];

  float4 xn = *(const float4*)&x[n*4];
  float4 r4;
  {
    float4 wr0 = *(const float4*)&Wr[0*HID + c];
    float4 wr1 = *(const float4*)&Wr[1*HID + c];
    float4 wr2 = *(const float4*)&Wr[2*HID + c];
    float4 wr3 = *(const float4*)&Wr[3*HID + c];
    float4 brv = *(const float4*)&br[c];
    r4.x = fmaf(xn.x,wr0.x, fmaf(xn.y,wr1.x, fmaf(xn.z,wr2.x, fmaf(xn.w,wr3.x, brv.x))));
    r4.y = fmaf(xn.x,wr0.y, fmaf(xn.y,wr1.y, fmaf(xn.z,wr2.y, fmaf(xn.w,wr3.y, brv.y))));
    r4.z = fmaf(xn.x,wr0.z, fmaf(xn.y,wr1.z, fmaf(xn.z,wr2.z, fmaf(xn.w,wr3.z, brv.z))));
    r4.w = fmaf(xn.x,wr0.w, fmaf(xn.y,wr1.w, fmaf(xn.z,wr2.w, fmaf(xn.w,wr3.w, brv.w))));
  }

  int js = __builtin_amdgcn_readfirstlane(offs[n]);
  int je = __builtin_amdgcn_readfirstlane(offs[n+1]);

  float D = 0.f, a0 = 0.f, a1 = 0.f, a2 = 0.f, a3 = 0.f;

  int j = js;
  if (j + 7 < je) {
    // prologue: load first batch
    int2 eA = cpk[j],   eB = cpk[j+1], eC = cpk[j+2], eD = cpk[j+3];
    int2 eE = cpk[j+4], eF = cpk[j+5], eG = cpk[j+6], eH = cpk[j+7];
    for (; j + 7 < je; j += 8) {
      // prefetch next batch (cpk has >=752 edges of tail padding: safe)
      int2 nA = cpk[j+8],  nB = cpk[j+9],  nC = cpk[j+10], nD = cpk[j+11];
      int2 nE = cpk[j+12], nF = cpk[j+13], nG = cpk[j+14], nH = cpk[j+15];
      C1_PROC8();
      eA = nA; eB = nB; eC = nC; eD = nD;
      eE = nE; eF = nF; eG = nG; eH = nH;
    }
  }
  for (; j < je; j++) {
    int2 eA = cpk[j];
    float4 xA = *(const float4*)&x[eA.x*4];
    float avA = __int_as_float(eA.y);
    float lA0,lA1,lA2,lA3,pA;
    C1_EDGE(xA, avA, lA0,lA1,lA2,lA3, pA);
    #pragma unroll
    for (int msk = 1; msk < 16; msk <<= 1) pA += __shfl_xor(pA, msk);
    float eAx = expf(pA);
    D += eAx;
    a0 = fmaf(eAx, lA0, a0);
    a1 = fmaf(eAx, lA1, a1);
    a2 = fmaf(eAx, lA2, a2);
    a3 = fmaf(eAx, lA3, a3);
  }

  float inv = 1.f / D;
  float4 b4 = *(const float4*)&bias[c];
  float o0 = fmaf(a0, inv, b4.x);
  float o1 = fmaf(a1, inv, b4.y);
  float o2 = fmaf(a2, inv, b4.z);
  float o3 = fmaf(a3, inv, b4.w);

  float s = o0 + o1 + o2 + o3;
  #pragma unroll
  for (int msk = 1; msk < 64; msk <<= 1) s += __shfl_xor(s, msk);
  float mu = s * (1.f / 256.f);
  float d0 = o0 - mu, d1 = o1 - mu, d2 = o2 - mu, d3 = o3 - mu;
  float sq = d0*d0 + d1*d1 + d2*d2 + d3*d3;
  #pragma unroll
  for (int msk = 1; msk < 64; msk <<= 1) sq += __shfl_xor(sq, msk);
  float rstd = rsqrtf(sq * (1.f / 256.f) + 1e-5f);
  float4 g4  = *(const float4*)&g[c];
  float4 be4 = *(const float4*)&be[c];
  float oy0 = fmaxf(fmaf(d0 * rstd, g4.x, be4.x), 0.f);
  float oy1 = fmaxf(fmaf(d1 * rstd, g4.y, be4.y), 0.f);
  float oy2 = fmaxf(fmaf(d2 * rstd, g4.z, be4.z), 0.f);
  float oy3 = fmaxf(fmaf(d3 * rstd, g4.w, be4.w), 0.f);
  uint2 pk;
  pk.x = bf16rne(oy0) | (bf16rne(oy1) << 16);
  pk.y = bf16rne(oy2) | (bf16rne(oy3) << 16);
  h1b[n*64 + (t & 63)] = pk;
}

// ---------------- conv2: bf16 gather, 8-edge pipelined, bf16 output ---------
#define C2_LOAD(q, xs)                                  \
  float4 xs;                                            \
  xs.x = __uint_as_float(q.x << 16);                    \
  xs.y = __uint_as_float(q.x & 0xFFFF0000u);            \
  xs.z = __uint_as_float(q.y << 16);                    \
  xs.w = __uint_as_float(q.y & 0xFFFF0000u);

#define C2_EDGE(xs, av, p)                                           \
  {                                                                  \
    float m0 = xs.x + fmaf(av, we.x, r4.x); m0 = fmaxf(m0, 0.2f*m0); \
    float m1 = xs.y + fmaf(av, we.y, r4.y); m1 = fmaxf(m1, 0.2f*m1); \
    float m2 = xs.z + fmaf(av, we.z, r4.z); m2 = fmaxf(m2, 0.2f*m2); \
    float m3 = xs.w + fmaf(av, we.w, r4.w); m3 = fmaxf(m3, 0.2f*m3); \
    p = m0*at.x + m1*at.y + m2*at.z + m3*at.w;                       \
  }

#define C2_PROC8()                                                              \
  {                                                                             \
    uint2 q0 = xlb[e0.x*64 + lane];                                             \
    uint2 q1 = xlb[e1.x*64 + lane];                                             \
    uint2 q2 = xlb[e2.x*64 + lane];                                             \
    uint2 q3 = xlb[e3.x*64 + lane];                                             \
    uint2 q4 = xlb[e4.x*64 + lane];                                             \
    uint2 q5 = xlb[e5.x*64 + lane];                                             \
    uint2 q6 = xlb[e6.x*64 + lane];                                             \
    uint2 q7 = xlb[e7.x*64 + lane];                                             \
    C2_LOAD(q0, xs0); C2_LOAD(q1, xs1); C2_LOAD(q2, xs2); C2_LOAD(q3, xs3);     \
    C2_LOAD(q4, xs4); C2_LOAD(q5, xs5); C2_LOAD(q6, xs6); C2_LOAD(q7, xs7);     \
    float av0 = __int_as_float(e0.y), av1 = __int_as_float(e1.y);               \
    float av2 = __int_as_float(e2.y), av3 = __int_as_float(e3.y);               \
    float av4 = __int_as_float(e4.y), av5 = __int_as_float(e5.y);               \
    float av6 = __int_as_float(e6.y), av7 = __int_as_float(e7.y);               \
    float p0,p1,p2,p3,p4,p5,p6,p7;                                              \
    C2_EDGE(xs0, av0, p0); C2_EDGE(xs1, av1, p1);                               \
    C2_EDGE(xs2, av2, p2); C2_EDGE(xs3, av3, p3);                               \
    C2_EDGE(xs4, av4, p4); C2_EDGE(xs5, av5, p5);                               \
    C2_EDGE(xs6, av6, p6); C2_EDGE(xs7, av7, p7);                               \
    _Pragma("unroll")                                                           \
    for (int msk = 1; msk < 64; msk <<= 1) {                                    \
      p0 += __shfl_xor(p0, msk); p1 += __shfl_xor(p1, msk);                     \
      p2 += __shfl_xor(p2, msk); p3 += __shfl_xor(p3, msk);                     \
      p4 += __shfl_xor(p4, msk); p5 += __shfl_xor(p5, msk);                     \
      p6 += __shfl_xor(p6, msk); p7 += __shfl_xor(p7, msk);                     \
    }                                                                           \
    float x0 = expf(p0), x1 = expf(p1), x2 = expf(p2), x3 = expf(p3);           \
    float x4 = expf(p4), x5 = expf(p5), x6 = expf(p6), x7 = expf(p7);           \
    D += ((x0 + x1) + (x2 + x3)) + ((x4 + x5) + (x6 + x7));                     \
    a0 = fmaf(x3, xs3.x, fmaf(x2, xs2.x, fmaf(x1, xs1.x, fmaf(x0, xs0.x, a0))));\
    a0 = fmaf(x7, xs7.x, fmaf(x6, xs6.x, fmaf(x5, xs5.x, fmaf(x4, xs4.x, a0))));\
    a1 = fmaf(x3, xs3.y, fmaf(x2, xs2.y, fmaf(x1, xs1.y, fmaf(x0, xs0.y, a1))));\
    a1 = fmaf(x7, xs7.y, fmaf(x6, xs6.y, fmaf(x5, xs5.y, fmaf(x4, xs4.y, a1))));\
    a2 = fmaf(x3, xs3.z, fmaf(x2, xs2.z, fmaf(x1, xs1.z, fmaf(x0, xs0.z, a2))));\
    a2 = fmaf(x7, xs7.z, fmaf(x6, xs6.z, fmaf(x5, xs5.z, fmaf(x4, xs4.z, a2))));\
    a3 = fmaf(x3, xs3.w, fmaf(x2, xs2.w, fmaf(x1, xs1.w, fmaf(x0, xs0.w, a3))));\
    a3 = fmaf(x7, xs7.w, fmaf(x6, xs6.w, fmaf(x5, xs5.w, fmaf(x4, xs4.w, a3))));\
  }

__global__ void __launch_bounds__(256) k_conv2(
    const uint2* __restrict__ xlb, const float* __restrict__ xr,
    const int* __restrict__ offs, const int2* __restrict__ cpk,
    const float* __restrict__ We, const float* __restrict__ att,
    const float* __restrict__ bias, const float* __restrict__ g,
    const float* __restrict__ be, uint2* __restrict__ h2b) {
  int t = threadIdx.x;
  int n = blockIdx.x * 4 + (t >> 6);
  int lane = t & 63;
  int c = 4 * lane;
  float4 r4 = *(const float4*)&xr[n*HID + c];
  float4 we = *(const float4*)&We[c];
  float4 at = *(const float4*)&att[c];
  int js = __builtin_amdgcn_readfirstlane(offs[n]);
  int je = __builtin_amdgcn_readfirstlane(offs[n+1]);

  float D = 0.f, a0 = 0.f, a1 = 0.f, a2 = 0.f, a3 = 0.f;

  int j = js;
  if (j + 7 < je) {
    int2 e0 = cpk[j],   e1 = cpk[j+1], e2 = cpk[j+2], e3 = cpk[j+3];
    int2 e4 = cpk[j+4], e5 = cpk[j+5], e6 = cpk[j+6], e7 = cpk[j+7];
    for (; j + 7 < je; j += 8) {
      int2 n0 = cpk[j+8],  n1 = cpk[j+9],  n2 = cpk[j+10], n3 = cpk[j+11];
      int2 n4 = cpk[j+12], n5 = cpk[j+13], n6 = cpk[j+14], n7 = cpk[j+15];
      C2_PROC8();
      e0 = n0; e1 = n1; e2 = n2; e3 = n3;
      e4 = n4; e5 = n5; e6 = n6; e7 = n7;
    }
  }
  for (; j < je; j++) {
    int2 e0 = cpk[j];
    float av0 = __int_as_float(e0.y);
    uint2 q0 = xlb[e0.x*64 + lane];
    C2_LOAD(q0, xs0);
    float p0;
    C2_EDGE(xs0, av0, p0);
    #pragma unroll
    for (int msk = 1; msk < 64; msk <<= 1) p0 += __shfl_xor(p0, msk);
    float x0 = expf(p0);
    D += x0;
    a0 = fmaf(x0, xs0.x, a0);
    a1 = fmaf(x0, xs0.y, a1);
    a2 = fmaf(x0, xs0.z, a2);
    a3 = fmaf(x0, xs0.w, a3);
  }

  float inv = 1.f / D;
  float4 b4 = *(const float4*)&bias[c];
  float o0 = fmaf(a0, inv, b4.x);
  float o1 = fmaf(a1, inv, b4.y);
  float o2 = fmaf(a2, inv, b4.z);
  float o3 = fmaf(a3, inv, b4.w);

  float s = o0 + o1 + o2 + o3;
  #pragma unroll
  for (int msk = 1; msk < 64; msk <<= 1) s += __shfl_xor(s, msk);
  float mu = s * (1.f / 256.f);
  float d0 = o0 - mu, d1 = o1 - mu, d2 = o2 - mu, d3 = o3 - mu;
  float sq = d0*d0 + d1*d1 + d2*d2 + d3*d3;
  #pragma unroll
  for (int msk = 1; msk < 64; msk <<= 1) sq += __shfl_xor(sq, msk);
  float rstd = rsqrtf(sq * (1.f / 256.f) + 1e-5f);
  float4 g4  = *(const float4*)&g[c];
  float4 be4 = *(const float4*)&be[c];
  float oy0 = fmaxf(fmaf(d0 * rstd, g4.x, be4.x), 0.f);
  float oy1 = fmaxf(fmaf(d1 * rstd, g4.y, be4.y), 0.f);
  float oy2 = fmaxf(fmaf(d2 * rstd, g4.z, be4.z), 0.f);
  float oy3 = fmaxf(fmaf(d3 * rstd, g4.w, be4.w), 0.f);
  uint2 pk;
  pk.x = bf16rne(oy0) | (bf16rne(oy1) << 16);
  pk.y = bf16rne(oy2) | (bf16rne(oy3) << 16);
  h2b[n*64 + lane] = pk;
}

// ---------------- dual GEMM v4: bf16 MFMA 32x32x16 (unchanged, works) -------
__global__ void __launch_bounds__(256) k_gemm_dual(
    const unsigned short* __restrict__ h1b, const unsigned short* __restrict__ Wt,
    const float* __restrict__ b1, const float* __restrict__ b2,
    unsigned short* __restrict__ O1b, float* __restrict__ O2) {
  __shared__ unsigned short A_lds[64][72];
  __shared__ unsigned short W_lds[128][72];
  int t = threadIdx.x;
  int r0 = blockIdx.x * 64;
  int nb0 = blockIdx.y * 128;
  int l = t & 63;
  int wave = t >> 6;
  int wr = wave >> 1, wc = wave & 1;

  floatx16 acc[2] = {{0}, {0}};

  int sar = t >> 2, sak = (t & 3) * 16;
  int arow = min(r0 + sar, N_NODES - 1);
  int swn = t >> 1, swk = (t & 1) * 32;
  const unsigned short* Wrow = &Wt[(nb0 + swn) * 256];

  for (int kb = 0; kb < 256; kb += 64) {
    uint4 av0 = *(const uint4*)&h1b[arow*256 + kb + sak];
    uint4 av1 = *(const uint4*)&h1b[arow*256 + kb + sak + 8];
    uint4 wv0 = *(const uint4*)&Wrow[kb + swk];
    uint4 wv1 = *(const uint4*)&Wrow[kb + swk + 8];
    uint4 wv2 = *(const uint4*)&Wrow[kb + swk + 16];
    uint4 wv3 = *(const uint4*)&Wrow[kb + swk + 24];
    __syncthreads();
    *(uint4*)&A_lds[sar][sak]     = av0;
    *(uint4*)&A_lds[sar][sak + 8] = av1;
    *(uint4*)&W_lds[swn][swk]      = wv0;
    *(uint4*)&W_lds[swn][swk +  8] = wv1;
    *(uint4*)&W_lds[swn][swk + 16] = wv2;
    *(uint4*)&W_lds[swn][swk + 24] = wv3;
    __syncthreads();
    #pragma unroll
    for (int ks = 0; ks < 64; ks += 16) {
      short8 af  = *(const short8*)&A_lds[wr*32 + (l & 31)][ks + 8*(l >> 5)];
      short8 bf0 = *(const short8*)&W_lds[wc*64      + (l & 31)][ks + 8*(l >> 5)];
      short8 bf1 = *(const short8*)&W_lds[wc*64 + 32 + (l & 31)][ks + 8*(l >> 5)];
      acc[0] = __builtin_amdgcn_mfma_f32_32x32x16_bf16(af, bf0, acc[0], 0, 0, 0);
      acc[1] = __builtin_amdgcn_mfma_f32_32x32x16_bf16(af, bf1, acc[1], 0, 0, 0);
    }
  }

  bool isO1 = (nb0 < 256);
  #pragma unroll
  for (int tile = 0; tile < 2; tile++) {
    int col = nb0 + wc*64 + tile*32 + (l & 31);
    float bias = isO1 ? b1[col] : b2[col - 256];
    #pragma unroll
    for (int reg = 0; reg < 16; reg++) {
      int row = (reg & 3) + 8*(reg >> 2) + 4*(l >> 5);
      int r = r0 + wr*32 + row;
      if (r < N_NODES) {
        float v = acc[tile][reg] + bias;
        if (isO1) O1b[r*256 + col] = (unsigned short)bf16rne(v);
        else      O2[r*256 + (col - 256)] = v;
      }
    }
  }
}

// ------- policy v4: bf16 MFMA phase1 (64x128), LDS hid, phase2 + exp --------
__global__ void __launch_bounds__(256) k_policy(
    const unsigned short* __restrict__ h2b, const unsigned short* __restrict__ Wp1t,
    const float* __restrict__ bp1, const float* __restrict__ Wp2,
    const float* __restrict__ bp2, float* __restrict__ elg, float* __restrict__ tot) {
  __shared__ __align__(16) char smembuf[64 * 132 * 4];   // 33792 B union
  unsigned short* A_lds = (unsigned short*)smembuf;                  // [64][72]
  unsigned short* W_lds = (unsigned short*)(smembuf + 64*72*2);      // [128][72]
  float* hidl = (float*)smembuf;                                     // [64][132]
  __shared__ float wred[4];
  int t = threadIdx.x;
  int r0 = blockIdx.x * 64;
  int l = t & 63;
  int wave = t >> 6;
  int wr = wave >> 1, wc = wave & 1;

  floatx16 acc[2] = {{0}, {0}};

  int sar = t >> 2, sak = (t & 3) * 16;
  int arow = min(r0 + sar, N_NODES - 1);
  int swn = t >> 1, swk = (t & 1) * 32;
  const unsigned short* Wrow = &Wp1t[swn * 256];

  for (int kb = 0; kb < 256; kb += 64) {
    uint4 av0 = *(const uint4*)&h2b[arow*256 + kb + sak];
    uint4 av1 = *(const uint4*)&h2b[arow*256 + kb + sak + 8];
    uint4 wv0 = *(const uint4*)&Wrow[kb + swk];
    uint4 wv1 = *(const uint4*)&Wrow[kb + swk + 8];
    uint4 wv2 = *(const uint4*)&Wrow[kb + swk + 16];
    uint4 wv3 = *(const uint4*)&Wrow[kb + swk + 24];
    __syncthreads();
    *(uint4*)&A_lds[sar*72 + sak]     = av0;
    *(uint4*)&A_lds[sar*72 + sak + 8] = av1;
    *(uint4*)&W_lds[swn*72 + swk]      = wv0;
    *(uint4*)&W_lds[swn*72 + swk +  8] = wv1;
    *(uint4*)&W_lds[swn*72 + swk + 16] = wv2;
    *(uint4*)&W_lds[swn*72 + swk + 24] = wv3;
    __syncthreads();
    #pragma unroll
    for (int ks = 0; ks < 64; ks += 16) {
      short8 af  = *(const short8*)&A_lds[(wr*32 + (l & 31))*72 + ks + 8*(l >> 5)];
      short8 bf0 = *(const short8*)&W_lds[(wc*64      + (l & 31))*72 + ks + 8*(l >> 5)];
      short8 bf1 = *(const short8*)&W_lds[(wc*64 + 32 + (l & 31))*72 + ks + 8*(l >> 5)];
      acc[0] = __builtin_amdgcn_mfma_f32_32x32x16_bf16(af, bf0, acc[0], 0, 0, 0);
      acc[1] = __builtin_amdgcn_mfma_f32_32x32x16_bf16(af, bf1, acc[1], 0, 0, 0);
    }
  }
  __syncthreads();   // A/W dead; smem becomes hidl[64][132]
  #pragma unroll
  for (int tile = 0; tile < 2; tile++) {
    int col = wc*64 + tile*32 + (l & 31);
    float bias = bp1[col];
    #pragma unroll
    for (int reg = 0; reg < 16; reg++) {
      int row = (reg & 3) + 8*(reg >> 2) + 4*(l >> 5) + wr*32;
      hidl[row*132 + col] = fmaxf(acc[tile][reg] + bias, 0.f);
    }
  }
  __syncthreads();
  // phase 2: 256 outputs, one per thread
  int nl = t >> 2, i = t & 3;
  float s = bp2[i];
  for (int k = 0; k < 128; k += 4) {
    float4 hv = *(const float4*)&hidl[nl*132 + k];
    s = fmaf(hv.x, Wp2[(k+0)*4 + i],
        fmaf(hv.y, Wp2[(k+1)*4 + i],
        fmaf(hv.z, Wp2[(k+2)*4 + i],
        fmaf(hv.w, Wp2[(k+3)*4 + i], s))));
  }
  int n = r0 + nl;
  float esum = 0.f;
  if (n < N_NODES) {
    float e = expf(s);
    elg[n*4 + i] = e;
    esum = e;
  }
  #pragma unroll
  for (int msk = 1; msk < 64; msk <<= 1) esum += __shfl_xor(esum, msk);
  if ((t & 63) == 0) wred[t >> 6] = esum;
  __syncthreads();
  if (t == 0) atomicAdd(tot, (wred[0] + wred[1]) + (wred[2] + wred[3]));
}

// ---------------- normalize: out = elg * (1/tot) ----------------------------
__global__ void __launch_bounds__(1024) k_sm_final(const float* __restrict__ elg,
                                                   const float* __restrict__ tot,
                                                   float* __restrict__ out) {
  int i = blockIdx.x * 1024 + threadIdx.x;
  float inv = 1.f / tot[0];
  if (i < N_NODES * 4) out[i] = elg[i] * inv;
}

extern "C" void kernel_launch(void* const* d_in, const int* in_sizes, int n_in,
                              void* d_out, int out_size, void* d_ws, size_t ws_size,
                              hipStream_t stream) {
  const float* x    = (const float*)d_in[0];
  const int*   ei   = (const int*)  d_in[1];
  const float* ea   = (const float*)d_in[2];
  const float* Wl1  = (const float*)d_in[3];
  const float* bl1  = (const float*)d_in[4];
  const float* Wr1  = (const float*)d_in[5];
  const float* br1  = (const float*)d_in[6];
  const float* We1  = (const float*)d_in[7];
  const float* att1 = (const float*)d_in[8];
  const float* bias1= (const float*)d_in[9];
  const float* g1   = (const float*)d_in[10];
  const float* be1  = (const float*)d_in[11];
  const float* Wl2  = (const float*)d_in[12];
  const float* bl2  = (const float*)d_in[13];
  const float* Wr2  = (const float*)d_in[14];
  const float* br2  = (const float*)d_in[15];
  const float* We2  = (const float*)d_in[16];
  const float* att2 = (const float*)d_in[17];
  const float* bias2= (const float*)d_in[18];
  const float* g2   = (const float*)d_in[19];
  const float* be2  = (const float*)d_in[20];
  const float* Wp1  = (const float*)d_in[21];
  const float* bp1  = (const float*)d_in[22];
  const float* Wp2  = (const float*)d_in[23];
  const float* bp2  = (const float*)d_in[24];
  float* out = (float*)d_out;

  const int* srcp = ei;
  const int* dstp = ei + N_EDGES;

  // workspace layout: [deg | cursor | asum | tot] zeroed in ONE memset
  int*   deg    = (int*)d_ws;                // 10240
  int*   cursor = deg + 10240;               // 10240
  float* asum   = (float*)(cursor + 10240);  // 10240
  float* tot    = asum + 10240;              // 16
  int*   offs   = (int*)(tot + 16);          // 10240
  float* lattr  = (float*)(offs + 10240);    // 10240
  int2*  cpk    = (int2*)(lattr + 10240);    // 330752 int2 (752 pad: prefetch-safe)
  unsigned short* h1b = (unsigned short*)(cpk + 330752);   // 10000x256 bf16
  unsigned short* h2b = h1b;                 // conv2 output aliases (h1b dead)
  unsigned short* xl2bf = h1b + 2560000;     // 10000x256 bf16
  float* xr2    = (float*)(xl2bf + 2560000); // 2560000 floats
  float* elg    = xr2 + 2560000;             // 40960
  unsigned short* Wt   = (unsigned short*)(elg + 40960);   // 512x256 bf16
  unsigned short* Wp1t = Wt + 512*256;                     // 128x256 bf16

  hipMemsetAsync(deg, 0, (3 * 10240 + 16) * sizeof(int), stream);

  k_cvtw   <<<dim3(8, 8, 2), 256, 0, stream>>>(Wl2, Wr2, Wt);
  k_cvtwp  <<<dim3(8, 4), 256, 0, stream>>>(Wp1, Wp1t);
  k_deg    <<<(N_EDGES + 255)/256, 256, 0, stream>>>(dstp, ea, deg, asum);
  k_scan   <<<1, 256, 0, stream>>>(deg, asum, offs, lattr);
  k_scatter<<<(N_AUG + 255)/256, 256, 0, stream>>>(srcp, dstp, ea, lattr, offs,
                                                   cursor, cpk);
  k_conv1  <<<N_NODES/4, 256, 0, stream>>>(x, Wl1, bl1, Wr1, br1, We1, att1,
                                           offs, cpk, bias1, g1, be1, (uint2*)h1b);
  k_gemm_dual<<<dim3(157, 4), 256, 0, stream>>>(h1b, Wt, bl2, br2, xl2bf, xr2);
  k_conv2  <<<N_NODES/4, 256, 0, stream>>>((const uint2*)xl2bf, xr2, offs, cpk,
                                           We2, att2, bias2, g2, be2, (uint2*)h2b);
  k_policy <<<157, 256, 0, stream>>>(h2b, Wp1t, bp1, Wp2, bp2, elg, tot);
  k_sm_final<<<40, 1024, 0, stream>>>(elg, tot, out);
}

// Round 11
// 306.160 us; speedup vs baseline: 1.2728x; 1.0271x over previous
//
#include <hip/hip_runtime.h>
#include <math.h>

#define N_NODES 10000
#define N_EDGES 320000
#define N_AUG   (N_EDGES + N_NODES)
#define CPK_CAP 330752
#define HID     256

typedef short short8 __attribute__((ext_vector_type(8)));
typedef float floatx16 __attribute__((ext_vector_type(16)));

// bf16 round-to-nearest-even, as the low 16 bits of a uint
static __device__ __forceinline__ unsigned bf16rne(float f) {
  unsigned u = __float_as_uint(f);
  return (u + 0x7FFFu + ((u >> 16) & 1u)) >> 16;
}

// ---------------- degree + edge_attr segment sum ----------------
__global__ void k_deg(const int* __restrict__ dst, const float* __restrict__ ea,
                      int* __restrict__ deg, float* __restrict__ asum) {
  int e = blockIdx.x * blockDim.x + threadIdx.x;
  if (e < N_EDGES) {
    int d = dst[e];
    atomicAdd(&deg[d], 1);
    atomicAdd(&asum[d], ea[e]);
  }
}

// ------- exclusive scan of (deg+1) over 10000 nodes (parallel), + loop_attr --
__global__ void __launch_bounds__(256) k_scan(
    const int* __restrict__ deg, const float* __restrict__ asum,
    int* __restrict__ offs, float* __restrict__ lattr) {
  __shared__ int wsum[4];
  int t = threadIdx.x;
  int base = t * 40;
  int s = 0;
  for (int i = 0; i < 40; i++) {
    int n = base + i;
    if (n < N_NODES) s += deg[n] + 1;
  }
  int v = s;
  #pragma unroll
  for (int d = 1; d < 64; d <<= 1) {
    int u = __shfl_up(v, d);
    if ((t & 63) >= d) v += u;
  }
  if ((t & 63) == 63) wsum[t >> 6] = v;
  __syncthreads();
  int wb = 0;
  for (int i = 0; i < (t >> 6); i++) wb += wsum[i];
  int run = wb + v - s;
  for (int i = 0; i < 40; i++) {
    int n = base + i;
    if (n < N_NODES) {
      offs[n] = run;
      int d = deg[n];
      run += d + 1;
      lattr[n] = asum[n] / (float)max(d, 1);
    }
  }
  if (t == 255) offs[N_NODES] = wb + v;
}

// ------- scatter edges into CSR by dst; zero the tail pad (prefetch-safe) ---
__global__ void k_scatter(const int* __restrict__ src, const int* __restrict__ dst,
                          const float* __restrict__ ea, const float* __restrict__ lattr,
                          const int* __restrict__ offs, int* __restrict__ cursor,
                          int2* __restrict__ cpk) {
  int e = blockIdx.x * blockDim.x + threadIdx.x;
  if (e >= N_AUG) {
    if (e < CPK_CAP) cpk[e] = make_int2(0, 0);   // pad: row-0, av=0
    return;
  }
  int s, d; float a;
  if (e < N_EDGES) { s = src[e]; d = dst[e]; a = ea[e]; }
  else             { s = e - N_EDGES; d = s; a = lattr[s]; }
  int pos = offs[d] + atomicAdd(&cursor[d], 1);
  cpk[pos] = make_int2(s, __float_as_int(a));
}

// ------- convert W1|W2 (fp32 [k][n]) -> Wt (bf16 [n][k], n in 0..511) -------
__global__ void __launch_bounds__(256) k_cvtw(
    const float* __restrict__ W1, const float* __restrict__ W2,
    unsigned short* __restrict__ Wt) {
  __shared__ float tile[32][33];
  const float* W = blockIdx.z ? W2 : W1;
  int rowoff = blockIdx.z * 256;
  int kb = blockIdx.x * 32, nb = blockIdx.y * 32;
  int t = threadIdx.x;
  int tx = t & 31, ty = t >> 5;
  #pragma unroll
  for (int rep = 0; rep < 4; rep++)
    tile[ty + 8*rep][tx] = W[(kb + ty + 8*rep)*HID + nb + tx];
  __syncthreads();
  #pragma unroll
  for (int rep = 0; rep < 4; rep++) {
    int n = nb + ty + 8*rep;
    Wt[(rowoff + n)*256 + kb + tx] = (unsigned short)bf16rne(tile[tx][ty + 8*rep]);
  }
}

// ------- convert Wp1 (fp32 [256][128]) -> Wp1t (bf16 [n:128][k:256]) --------
__global__ void __launch_bounds__(256) k_cvtwp(
    const float* __restrict__ Wp1, unsigned short* __restrict__ Wp1t) {
  __shared__ float tile[32][33];
  int kb = blockIdx.x * 32, nb = blockIdx.y * 32;
  int t = threadIdx.x;
  int tx = t & 31, ty = t >> 5;
  #pragma unroll
  for (int rep = 0; rep < 4; rep++)
    tile[ty + 8*rep][tx] = Wp1[(kb + ty + 8*rep)*128 + nb + tx];
  __syncthreads();
  #pragma unroll
  for (int rep = 0; rep < 4; rep++) {
    int n = nb + ty + 8*rep;
    Wp1t[n*256 + kb + tx] = (unsigned short)bf16rne(tile[tx][ty + 8*rep]);
  }
}

// ============================ conv1 =========================================
#define C1_EDGE(xs, av, l0, l1, l2, l3, p)                                              \
  {                                                                                     \
    l0 = fmaf(xs.x,wl0.x, fmaf(xs.y,wl1.x, fmaf(xs.z,wl2.x, fmaf(xs.w,wl3.x, blv.x)))); \
    l1 = fmaf(xs.x,wl0.y, fmaf(xs.y,wl1.y, fmaf(xs.z,wl2.y, fmaf(xs.w,wl3.y, blv.y)))); \
    l2 = fmaf(xs.x,wl0.z, fmaf(xs.y,wl1.z, fmaf(xs.z,wl2.z, fmaf(xs.w,wl3.z, blv.z)))); \
    l3 = fmaf(xs.x,wl0.w, fmaf(xs.y,wl1.w, fmaf(xs.z,wl2.w, fmaf(xs.w,wl3.w, blv.w)))); \
    float m0 = l0 + fmaf(av, we.x, r4.x); m0 = fmaxf(m0, 0.2f*m0);                      \
    float m1 = l1 + fmaf(av, we.y, r4.y); m1 = fmaxf(m1, 0.2f*m1);                      \
    float m2 = l2 + fmaf(av, we.z, r4.z); m2 = fmaxf(m2, 0.2f*m2);                      \
    float m3 = l3 + fmaf(av, we.w, r4.w); m3 = fmaxf(m3, 0.2f*m3);                      \
    p = m0*at.x + m1*at.y + m2*at.z + m3*at.w;                                          \
  }

// tree-reduce 8 logits over a 16-lane head group -> 8 exps (1 expf/lane)
// after masks 1,2,4 each lane holds partial of edge (lane&7); mask 8 completes.
#define C1_PROC8()                                                              \
  {                                                                             \
    float4 xA = *(const float4*)&x[eA.x*4];                                     \
    float4 xB = *(const float4*)&x[eB.x*4];                                     \
    float4 xC = *(const float4*)&x[eC.x*4];                                     \
    float4 xD = *(const float4*)&x[eD.x*4];                                     \
    float4 xE = *(const float4*)&x[eE.x*4];                                     \
    float4 xF = *(const float4*)&x[eF.x*4];                                     \
    float4 xG = *(const float4*)&x[eG.x*4];                                     \
    float4 xH = *(const float4*)&x[eH.x*4];                                     \
    float avA = __int_as_float(eA.y), avB = __int_as_float(eB.y);               \
    float avC = __int_as_float(eC.y), avD = __int_as_float(eD.y);               \
    float avE = __int_as_float(eE.y), avF = __int_as_float(eF.y);               \
    float avG = __int_as_float(eG.y), avH = __int_as_float(eH.y);               \
    float lA0,lA1,lA2,lA3,pA, lB0,lB1,lB2,lB3,pB;                               \
    float lC0,lC1,lC2,lC3,pC, lD0,lD1,lD2,lD3,pD;                               \
    float lE0,lE1,lE2,lE3,pE, lF0,lF1,lF2,lF3,pF;                               \
    float lG0,lG1,lG2,lG3,pG, lH0,lH1,lH2,lH3,pH;                               \
    C1_EDGE(xA, avA, lA0,lA1,lA2,lA3, pA);                                      \
    C1_EDGE(xB, avB, lB0,lB1,lB2,lB3, pB);                                      \
    C1_EDGE(xC, avC, lC0,lC1,lC2,lC3, pC);                                      \
    C1_EDGE(xD, avD, lD0,lD1,lD2,lD3, pD);                                      \
    C1_EDGE(xE, avE, lE0,lE1,lE2,lE3, pE);                                      \
    C1_EDGE(xF, avF, lF0,lF1,lF2,lF3, pF);                                      \
    C1_EDGE(xG, avG, lG0,lG1,lG2,lG3, pG);                                      \
    C1_EDGE(xH, avH, lH0,lH1,lH2,lH3, pH);                                      \
    float sAB = b1 ? pA : pB, kAB = b1 ? pB : pA;                               \
    float qAB = kAB + __shfl_xor(sAB, 1);                                       \
    float sCD = b1 ? pC : pD, kCD = b1 ? pD : pC;                               \
    float qCD = kCD + __shfl_xor(sCD, 1);                                       \
    float sEF = b1 ? pE : pF, kEF = b1 ? pF : pE;                               \
    float qEF = kEF + __shfl_xor(sEF, 1);                                       \
    float sGH = b1 ? pG : pH, kGH = b1 ? pH : pG;                               \
    float qGH = kGH + __shfl_xor(sGH, 1);                                       \
    float u0s = b2 ? qAB : qCD, u0k = b2 ? qCD : qAB;                           \
    float u0 = u0k + __shfl_xor(u0s, 2);                                        \
    float u1s = b2 ? qEF : qGH, u1k = b2 ? qGH : qEF;                           \
    float u1 = u1k + __shfl_xor(u1s, 2);                                        \
    float vvs = b4 ? u0 : u1, vvk = b4 ? u1 : u0;                               \
    float vv = vvk + __shfl_xor(vvs, 4);                                        \
    vv += __shfl_xor(vv, 8);                                                    \
    float exv = expf(vv);                                                       \
    float xAe = __shfl(exv, 0, 16), xBe = __shfl(exv, 1, 16);                   \
    float xCe = __shfl(exv, 2, 16), xDe = __shfl(exv, 3, 16);                   \
    float xEe = __shfl(exv, 4, 16), xFe = __shfl(exv, 5, 16);                   \
    float xGe = __shfl(exv, 6, 16), xHe = __shfl(exv, 7, 16);                   \
    D += ((xAe + xBe) + (xCe + xDe)) + ((xEe + xFe) + (xGe + xHe));             \
    a0 = fmaf(xDe, lD0, fmaf(xCe, lC0, fmaf(xBe, lB0, fmaf(xAe, lA0, a0))));    \
    a0 = fmaf(xHe, lH0, fmaf(xGe, lG0, fmaf(xFe, lF0, fmaf(xEe, lE0, a0))));    \
    a1 = fmaf(xDe, lD1, fmaf(xCe, lC1, fmaf(xBe, lB1, fmaf(xAe, lA1, a1))));    \
    a1 = fmaf(xHe, lH1, fmaf(xGe, lG1, fmaf(xFe, lF1, fmaf(xEe, lE1, a1))));    \
    a2 = fmaf(xDe, lD2, fmaf(xCe, lC2, fmaf(xBe, lB2, fmaf(xAe, lA2, a2))));    \
    a2 = fmaf(xHe, lH2, fmaf(xGe, lG2, fmaf(xFe, lF2, fmaf(xEe, lE2, a2))));    \
    a3 = fmaf(xDe, lD3, fmaf(xCe, lC3, fmaf(xBe, lB3, fmaf(xAe, lA3, a3))));    \
    a3 = fmaf(xHe, lH3, fmaf(xGe, lG3, fmaf(xFe, lF3, fmaf(xEe, lE3, a3))));    \
  }

__global__ void __launch_bounds__(256) k_conv1(
    const float* __restrict__ x,
    const float* __restrict__ Wl, const float* __restrict__ bl,
    const float* __restrict__ Wr, const float* __restrict__ br,
    const float* __restrict__ We, const float* __restrict__ att,
    const int* __restrict__ offs, const int2* __restrict__ cpk,
    const float* __restrict__ bias, const float* __restrict__ g,
    const float* __restrict__ be, uint2* __restrict__ h1b) {
  int t = threadIdx.x;
  int n = blockIdx.x * 4 + (t >> 6);
  int c = 4 * (t & 63);
  bool b1 = (t & 1) != 0, b2 = (t & 2) != 0, b4 = (t & 4) != 0;

  float4 wl0 = *(const float4*)&Wl[0*HID + c];
  float4 wl1 = *(const float4*)&Wl[1*HID + c];
  float4 wl2 = *(const float4*)&Wl[2*HID + c];
  float4 wl3 = *(const float4*)&Wl[3*HID + c];
  float4 blv = *(const float4*)&bl[c];
  float4 we  = *(const float4*)&We[c];
  float4 at  = *(const float4*)&att[c];

  float4 xn = *(const float4*)&x[n*4];
  float4 r4;
  {
    float4 wr0 = *(const float4*)&Wr[0*HID + c];
    float4 wr1 = *(const float4*)&Wr[1*HID + c];
    float4 wr2 = *(const float4*)&Wr[2*HID + c];
    float4 wr3 = *(const float4*)&Wr[3*HID + c];
    float4 brv = *(const float4*)&br[c];
    r4.x = fmaf(xn.x,wr0.x, fmaf(xn.y,wr1.x, fmaf(xn.z,wr2.x, fmaf(xn.w,wr3.x, brv.x))));
    r4.y = fmaf(xn.x,wr0.y, fmaf(xn.y,wr1.y, fmaf(xn.z,wr2.y, fmaf(xn.w,wr3.y, brv.y))));
    r4.z = fmaf(xn.x,wr0.z, fmaf(xn.y,wr1.z, fmaf(xn.z,wr2.z, fmaf(xn.w,wr3.z, brv.z))));
    r4.w = fmaf(xn.x,wr0.w, fmaf(xn.y,wr1.w, fmaf(xn.z,wr2.w, fmaf(xn.w,wr3.w, brv.w))));
  }

  int js = __builtin_amdgcn_readfirstlane(offs[n]);
  int je = __builtin_amdgcn_readfirstlane(offs[n+1]);

  float D = 0.f, a0 = 0.f, a1 = 0.f, a2 = 0.f, a3 = 0.f;

  int j = js;
  if (j + 7 < je) {
    int2 eA = cpk[j],   eB = cpk[j+1], eC = cpk[j+2], eD = cpk[j+3];
    int2 eE = cpk[j+4], eF = cpk[j+5], eG = cpk[j+6], eH = cpk[j+7];
    for (; j + 7 < je; j += 8) {
      int2 nA = cpk[j+8],  nB = cpk[j+9],  nC = cpk[j+10], nD = cpk[j+11];
      int2 nE = cpk[j+12], nF = cpk[j+13], nG = cpk[j+14], nH = cpk[j+15];
      C1_PROC8();
      eA = nA; eB = nB; eC = nC; eD = nD;
      eE = nE; eF = nF; eG = nG; eH = nH;
    }
  }
  for (; j < je; j++) {
    int2 eA = cpk[j];
    float4 xA = *(const float4*)&x[eA.x*4];
    float avA = __int_as_float(eA.y);
    float lA0,lA1,lA2,lA3,pA;
    C1_EDGE(xA, avA, lA0,lA1,lA2,lA3, pA);
    #pragma unroll
    for (int msk = 1; msk < 16; msk <<= 1) pA += __shfl_xor(pA, msk);
    float eAx = expf(pA);
    D += eAx;
    a0 = fmaf(eAx, lA0, a0);
    a1 = fmaf(eAx, lA1, a1);
    a2 = fmaf(eAx, lA2, a2);
    a3 = fmaf(eAx, lA3, a3);
  }

  float inv = 1.f / D;
  float4 b4v = *(const float4*)&bias[c];
  float o0 = fmaf(a0, inv, b4v.x);
  float o1 = fmaf(a1, inv, b4v.y);
  float o2 = fmaf(a2, inv, b4v.z);
  float o3 = fmaf(a3, inv, b4v.w);

  float s = o0 + o1 + o2 + o3;
  #pragma unroll
  for (int msk = 1; msk < 64; msk <<= 1) s += __shfl_xor(s, msk);
  float mu = s * (1.f / 256.f);
  float d0 = o0 - mu, d1 = o1 - mu, d2 = o2 - mu, d3 = o3 - mu;
  float sq = d0*d0 + d1*d1 + d2*d2 + d3*d3;
  #pragma unroll
  for (int msk = 1; msk < 64; msk <<= 1) sq += __shfl_xor(sq, msk);
  float rstd = rsqrtf(sq * (1.f / 256.f) + 1e-5f);
  float4 g4  = *(const float4*)&g[c];
  float4 be4 = *(const float4*)&be[c];
  float oy0 = fmaxf(fmaf(d0 * rstd, g4.x, be4.x), 0.f);
  float oy1 = fmaxf(fmaf(d1 * rstd, g4.y, be4.y), 0.f);
  float oy2 = fmaxf(fmaf(d2 * rstd, g4.z, be4.z), 0.f);
  float oy3 = fmaxf(fmaf(d3 * rstd, g4.w, be4.w), 0.f);
  uint2 pk;
  pk.x = bf16rne(oy0) | (bf16rne(oy1) << 16);
  pk.y = bf16rne(oy2) | (bf16rne(oy3) << 16);
  h1b[n*64 + (t & 63)] = pk;
}

// ============================ conv2 =========================================
#define C2_LOAD(q, xs)                                  \
  float4 xs;                                            \
  xs.x = __uint_as_float(q.x << 16);                    \
  xs.y = __uint_as_float(q.x & 0xFFFF0000u);            \
  xs.z = __uint_as_float(q.y << 16);                    \
  xs.w = __uint_as_float(q.y & 0xFFFF0000u);

#define C2_EDGE(xs, av, p)                                           \
  {                                                                  \
    float m0 = xs.x + fmaf(av, we.x, r4.x); m0 = fmaxf(m0, 0.2f*m0); \
    float m1 = xs.y + fmaf(av, we.y, r4.y); m1 = fmaxf(m1, 0.2f*m1); \
    float m2 = xs.z + fmaf(av, we.z, r4.z); m2 = fmaxf(m2, 0.2f*m2); \
    float m3 = xs.w + fmaf(av, we.w, r4.w); m3 = fmaxf(m3, 0.2f*m3); \
    p = m0*at.x + m1*at.y + m2*at.z + m3*at.w;                       \
  }

// consumes metadata e0..e7 and staged rows q0..q7
#define C2_PROC8()                                                              \
  {                                                                             \
    C2_LOAD(q0, xs0); C2_LOAD(q1, xs1); C2_LOAD(q2, xs2); C2_LOAD(q3, xs3);     \
    C2_LOAD(q4, xs4); C2_LOAD(q5, xs5); C2_LOAD(q6, xs6); C2_LOAD(q7, xs7);     \
    float av0 = __int_as_float(e0.y), av1 = __int_as_float(e1.y);               \
    float av2 = __int_as_float(e2.y), av3 = __int_as_float(e3.y);               \
    float av4 = __int_as_float(e4.y), av5 = __int_as_float(e5.y);               \
    float av6 = __int_as_float(e6.y), av7 = __int_as_float(e7.y);               \
    float p0,p1,p2,p3,p4,p5,p6,p7;                                              \
    C2_EDGE(xs0, av0, p0); C2_EDGE(xs1, av1, p1);                               \
    C2_EDGE(xs2, av2, p2); C2_EDGE(xs3, av3, p3);                               \
    C2_EDGE(xs4, av4, p4); C2_EDGE(xs5, av5, p5);                               \
    C2_EDGE(xs6, av6, p6); C2_EDGE(xs7, av7, p7);                               \
    float sAB = b1 ? p0 : p1, kAB = b1 ? p1 : p0;                               \
    float qAB = kAB + __shfl_xor(sAB, 1);                                       \
    float sCD = b1 ? p2 : p3, kCD = b1 ? p3 : p2;                               \
    float qCD = kCD + __shfl_xor(sCD, 1);                                       \
    float sEF = b1 ? p4 : p5, kEF = b1 ? p5 : p4;                               \
    float qEF = kEF + __shfl_xor(sEF, 1);                                       \
    float sGH = b1 ? p6 : p7, kGH = b1 ? p7 : p6;                               \
    float qGH = kGH + __shfl_xor(sGH, 1);                                       \
    float u0s = b2 ? qAB : qCD, u0k = b2 ? qCD : qAB;                           \
    float u0 = u0k + __shfl_xor(u0s, 2);                                        \
    float u1s = b2 ? qEF : qGH, u1k = b2 ? qGH : qEF;                           \
    float u1 = u1k + __shfl_xor(u1s, 2);                                        \
    float vvs = b4 ? u0 : u1, vvk = b4 ? u1 : u0;                               \
    float vv = vvk + __shfl_xor(vvs, 4);                                        \
    vv += __shfl_xor(vv, 8);                                                    \
    vv += __shfl_xor(vv, 16);                                                   \
    vv += __shfl_xor(vv, 32);                                                   \
    float exv = expf(vv);                                                       \
    float x0 = __shfl(exv, 0), x1 = __shfl(exv, 1);                             \
    float x2 = __shfl(exv, 2), x3 = __shfl(exv, 3);                             \
    float x4 = __shfl(exv, 4), x5 = __shfl(exv, 5);                             \
    float x6 = __shfl(exv, 6), x7 = __shfl(exv, 7);                             \
    D += ((x0 + x1) + (x2 + x3)) + ((x4 + x5) + (x6 + x7));                     \
    a0 = fmaf(x3, xs3.x, fmaf(x2, xs2.x, fmaf(x1, xs1.x, fmaf(x0, xs0.x, a0))));\
    a0 = fmaf(x7, xs7.x, fmaf(x6, xs6.x, fmaf(x5, xs5.x, fmaf(x4, xs4.x, a0))));\
    a1 = fmaf(x3, xs3.y, fmaf(x2, xs2.y, fmaf(x1, xs1.y, fmaf(x0, xs0.y, a1))));\
    a1 = fmaf(x7, xs7.y, fmaf(x6, xs6.y, fmaf(x5, xs5.y, fmaf(x4, xs4.y, a1))));\
    a2 = fmaf(x3, xs3.z, fmaf(x2, xs2.z, fmaf(x1, xs1.z, fmaf(x0, xs0.z, a2))));\
    a2 = fmaf(x7, xs7.z, fmaf(x6, xs6.z, fmaf(x5, xs5.z, fmaf(x4, xs4.z, a2))));\
    a3 = fmaf(x3, xs3.w, fmaf(x2, xs2.w, fmaf(x1, xs1.w, fmaf(x0, xs0.w, a3))));\
    a3 = fmaf(x7, xs7.w, fmaf(x6, xs6.w, fmaf(x5, xs5.w, fmaf(x4, xs4.w, a3))));\
  }

__global__ void __launch_bounds__(256) k_conv2(
    const uint2* __restrict__ xlb, const float* __restrict__ xr,
    const int* __restrict__ offs, const int2* __restrict__ cpk,
    const float* __restrict__ We, const float* __restrict__ att,
    const float* __restrict__ bias, const float* __restrict__ g,
    const float* __restrict__ be, uint2* __restrict__ h2b) {
  int t = threadIdx.x;
  int n = blockIdx.x * 4 + (t >> 6);
  int lane = t & 63;
  int c = 4 * lane;
  bool b1 = (t & 1) != 0, b2 = (t & 2) != 0, b4 = (t & 4) != 0;
  float4 r4 = *(const float4*)&xr[n*HID + c];
  float4 we = *(const float4*)&We[c];
  float4 at = *(const float4*)&att[c];
  int js = __builtin_amdgcn_readfirstlane(offs[n]);
  int je = __builtin_amdgcn_readfirstlane(offs[n+1]);

  float D = 0.f, a0 = 0.f, a1 = 0.f, a2 = 0.f, a3 = 0.f;

  int j = js;
  if (je - js >= 16) {
    // two-stage pipeline: metadata 2 batches ahead, rows 1 batch ahead
    int2 e0 = cpk[j],   e1 = cpk[j+1], e2 = cpk[j+2], e3 = cpk[j+3];
    int2 e4 = cpk[j+4], e5 = cpk[j+5], e6 = cpk[j+6], e7 = cpk[j+7];
    int2 f0 = cpk[j+8],  f1 = cpk[j+9],  f2 = cpk[j+10], f3 = cpk[j+11];
    int2 f4 = cpk[j+12], f5 = cpk[j+13], f6 = cpk[j+14], f7 = cpk[j+15];
    uint2 q0 = xlb[e0.x*64 + lane];
    uint2 q1 = xlb[e1.x*64 + lane];
    uint2 q2 = xlb[e2.x*64 + lane];
    uint2 q3 = xlb[e3.x*64 + lane];
    uint2 q4 = xlb[e4.x*64 + lane];
    uint2 q5 = xlb[e5.x*64 + lane];
    uint2 q6 = xlb[e6.x*64 + lane];
    uint2 q7 = xlb[e7.x*64 + lane];
    for (; j + 15 < je; j += 8) {
      // prefetch rows for the staged metadata batch
      uint2 r0 = xlb[f0.x*64 + lane];
      uint2 r1 = xlb[f1.x*64 + lane];
      uint2 r2 = xlb[f2.x*64 + lane];
      uint2 r3 = xlb[f3.x*64 + lane];
      uint2 r4_ = xlb[f4.x*64 + lane];
      uint2 r5 = xlb[f5.x*64 + lane];
      uint2 r6 = xlb[f6.x*64 + lane];
      uint2 r7 = xlb[f7.x*64 + lane];
      // prefetch metadata two batches ahead (pad-safe: cpk zeroed past N_AUG)
      int2 g0 = cpk[j+16], g1 = cpk[j+17], g2 = cpk[j+18], g3 = cpk[j+19];
      int2 g4 = cpk[j+20], g5 = cpk[j+21], g6 = cpk[j+22], g7 = cpk[j+23];
      C2_PROC8();
      e0 = f0; e1 = f1; e2 = f2; e3 = f3; e4 = f4; e5 = f5; e6 = f6; e7 = f7;
      f0 = g0; f1 = g1; f2 = g2; f3 = g3; f4 = g4; f5 = g5; f6 = g6; f7 = g7;
      q0 = r0; q1 = r1; q2 = r2; q3 = r3; q4 = r4_; q5 = r5; q6 = r6; q7 = r7;
    }
    C2_PROC8();   // staged final full batch
    j += 8;
  }
  for (; j + 7 < je; j += 8) {   // non-pipelined (deg 8..15)
    int2 e0 = cpk[j],   e1 = cpk[j+1], e2 = cpk[j+2], e3 = cpk[j+3];
    int2 e4 = cpk[j+4], e5 = cpk[j+5], e6 = cpk[j+6], e7 = cpk[j+7];
    uint2 q0 = xlb[e0.x*64 + lane];
    uint2 q1 = xlb[e1.x*64 + lane];
    uint2 q2 = xlb[e2.x*64 + lane];
    uint2 q3 = xlb[e3.x*64 + lane];
    uint2 q4 = xlb[e4.x*64 + lane];
    uint2 q5 = xlb[e5.x*64 + lane];
    uint2 q6 = xlb[e6.x*64 + lane];
    uint2 q7 = xlb[e7.x*64 + lane];
    C2_PROC8();
  }
  for (; j < je; j++) {
    int2 e0 = cpk[j];
    float av0 = __int_as_float(e0.y);
    uint2 q0 = xlb[e0.x*64 + lane];
    C2_LOAD(q0, xs0);
    float p0;
    C2_EDGE(xs0, av0, p0);
    #pragma unroll
    for (int msk = 1; msk < 64; msk <<= 1) p0 += __shfl_xor(p0, msk);
    float x0 = expf(p0);
    D += x0;
    a0 = fmaf(x0, xs0.x, a0);
    a1 = fmaf(x0, xs0.y, a1);
    a2 = fmaf(x0, xs0.z, a2);
    a3 = fmaf(x0, xs0.w, a3);
  }

  float inv = 1.f / D;
  float4 b4v = *(const float4*)&bias[c];
  float o0 = fmaf(a0, inv, b4v.x);
  float o1 = fmaf(a1, inv, b4v.y);
  float o2 = fmaf(a2, inv, b4v.z);
  float o3 = fmaf(a3, inv, b4v.w);

  float s = o0 + o1 + o2 + o3;
  #pragma unroll
  for (int msk = 1; msk < 64; msk <<= 1) s += __shfl_xor(s, msk);
  float mu = s * (1.f / 256.f);
  float d0 = o0 - mu, d1 = o1 - mu, d2 = o2 - mu, d3 = o3 - mu;
  float sq = d0*d0 + d1*d1 + d2*d2 + d3*d3;
  #pragma unroll
  for (int msk = 1; msk < 64; msk <<= 1) sq += __shfl_xor(sq, msk);
  float rstd = rsqrtf(sq * (1.f / 256.f) + 1e-5f);
  float4 g4  = *(const float4*)&g[c];
  float4 be4 = *(const float4*)&be[c];
  float oy0 = fmaxf(fmaf(d0 * rstd, g4.x, be4.x), 0.f);
  float oy1 = fmaxf(fmaf(d1 * rstd, g4.y, be4.y), 0.f);
  float oy2 = fmaxf(fmaf(d2 * rstd, g4.z, be4.z), 0.f);
  float oy3 = fmaxf(fmaf(d3 * rstd, g4.w, be4.w), 0.f);
  uint2 pk;
  pk.x = bf16rne(oy0) | (bf16rne(oy1) << 16);
  pk.y = bf16rne(oy2) | (bf16rne(oy3) << 16);
  h2b[n*64 + lane] = pk;
}

// ---------------- dual GEMM v4: bf16 MFMA 32x32x16 (unchanged, works) -------
__global__ void __launch_bounds__(256) k_gemm_dual(
    const unsigned short* __restrict__ h1b, const unsigned short* __restrict__ Wt,
    const float* __restrict__ b1, const float* __restrict__ b2,
    unsigned short* __restrict__ O1b, float* __restrict__ O2) {
  __shared__ unsigned short A_lds[64][72];
  __shared__ unsigned short W_lds[128][72];
  int t = threadIdx.x;
  int r0 = blockIdx.x * 64;
  int nb0 = blockIdx.y * 128;
  int l = t & 63;
  int wave = t >> 6;
  int wr = wave >> 1, wc = wave & 1;

  floatx16 acc[2] = {{0}, {0}};

  int sar = t >> 2, sak = (t & 3) * 16;
  int arow = min(r0 + sar, N_NODES - 1);
  int swn = t >> 1, swk = (t & 1) * 32;
  const unsigned short* Wrow = &Wt[(nb0 + swn) * 256];

  for (int kb = 0; kb < 256; kb += 64) {
    uint4 av0 = *(const uint4*)&h1b[arow*256 + kb + sak];
    uint4 av1 = *(const uint4*)&h1b[arow*256 + kb + sak + 8];
    uint4 wv0 = *(const uint4*)&Wrow[kb + swk];
    uint4 wv1 = *(const uint4*)&Wrow[kb + swk + 8];
    uint4 wv2 = *(const uint4*)&Wrow[kb + swk + 16];
    uint4 wv3 = *(const uint4*)&Wrow[kb + swk + 24];
    __syncthreads();
    *(uint4*)&A_lds[sar][sak]     = av0;
    *(uint4*)&A_lds[sar][sak + 8] = av1;
    *(uint4*)&W_lds[swn][swk]      = wv0;
    *(uint4*)&W_lds[swn][swk +  8] = wv1;
    *(uint4*)&W_lds[swn][swk + 16] = wv2;
    *(uint4*)&W_lds[swn][swk + 24] = wv3;
    __syncthreads();
    #pragma unroll
    for (int ks = 0; ks < 64; ks += 16) {
      short8 af  = *(const short8*)&A_lds[wr*32 + (l & 31)][ks + 8*(l >> 5)];
      short8 bf0 = *(const short8*)&W_lds[wc*64      + (l & 31)][ks + 8*(l >> 5)];
      short8 bf1 = *(const short8*)&W_lds[wc*64 + 32 + (l & 31)][ks + 8*(l >> 5)];
      acc[0] = __builtin_amdgcn_mfma_f32_32x32x16_bf16(af, bf0, acc[0], 0, 0, 0);
      acc[1] = __builtin_amdgcn_mfma_f32_32x32x16_bf16(af, bf1, acc[1], 0, 0, 0);
    }
  }

  bool isO1 = (nb0 < 256);
  #pragma unroll
  for (int tile = 0; tile < 2; tile++) {
    int col = nb0 + wc*64 + tile*32 + (l & 31);
    float bias = isO1 ? b1[col] : b2[col - 256];
    #pragma unroll
    for (int reg = 0; reg < 16; reg++) {
      int row = (reg & 3) + 8*(reg >> 2) + 4*(l >> 5);
      int r = r0 + wr*32 + row;
      if (r < N_NODES) {
        float v = acc[tile][reg] + bias;
        if (isO1) O1b[r*256 + col] = (unsigned short)bf16rne(v);
        else      O2[r*256 + (col - 256)] = v;
      }
    }
  }
}

// ------- policy v4: bf16 MFMA phase1 (64x128), LDS hid, phase2 + exp --------
__global__ void __launch_bounds__(256) k_policy(
    const unsigned short* __restrict__ h2b, const unsigned short* __restrict__ Wp1t,
    const float* __restrict__ bp1, const float* __restrict__ Wp2,
    const float* __restrict__ bp2, float* __restrict__ elg, float* __restrict__ tot) {
  __shared__ __align__(16) char smembuf[64 * 132 * 4];   // 33792 B union
  unsigned short* A_lds = (unsigned short*)smembuf;                  // [64][72]
  unsigned short* W_lds = (unsigned short*)(smembuf + 64*72*2);      // [128][72]
  float* hidl = (float*)smembuf;                                     // [64][132]
  __shared__ float wred[4];
  int t = threadIdx.x;
  int r0 = blockIdx.x * 64;
  int l = t & 63;
  int wave = t >> 6;
  int wr = wave >> 1, wc = wave & 1;

  floatx16 acc[2] = {{0}, {0}};

  int sar = t >> 2, sak = (t & 3) * 16;
  int arow = min(r0 + sar, N_NODES - 1);
  int swn = t >> 1, swk = (t & 1) * 32;
  const unsigned short* Wrow = &Wp1t[swn * 256];

  for (int kb = 0; kb < 256; kb += 64) {
    uint4 av0 = *(const uint4*)&h2b[arow*256 + kb + sak];
    uint4 av1 = *(const uint4*)&h2b[arow*256 + kb + sak + 8];
    uint4 wv0 = *(const uint4*)&Wrow[kb + swk];
    uint4 wv1 = *(const uint4*)&Wrow[kb + swk + 8];
    uint4 wv2 = *(const uint4*)&Wrow[kb + swk + 16];
    uint4 wv3 = *(const uint4*)&Wrow[kb + swk + 24];
    __syncthreads();
    *(uint4*)&A_lds[sar*72 + sak]     = av0;
    *(uint4*)&A_lds[sar*72 + sak + 8] = av1;
    *(uint4*)&W_lds[swn*72 + swk]      = wv0;
    *(uint4*)&W_lds[swn*72 + swk +  8] = wv1;
    *(uint4*)&W_lds[swn*72 + swk + 16] = wv2;
    *(uint4*)&W_lds[swn*72 + swk + 24] = wv3;
    __syncthreads();
    #pragma unroll
    for (int ks = 0; ks < 64; ks += 16) {
      short8 af  = *(const short8*)&A_lds[(wr*32 + (l & 31))*72 + ks + 8*(l >> 5)];
      short8 bf0 = *(const short8*)&W_lds[(wc*64      + (l & 31))*72 + ks + 8*(l >> 5)];
      short8 bf1 = *(const short8*)&W_lds[(wc*64 + 32 + (l & 31))*72 + ks + 8*(l >> 5)];
      acc[0] = __builtin_amdgcn_mfma_f32_32x32x16_bf16(af, bf0, acc[0], 0, 0, 0);
      acc[1] = __builtin_amdgcn_mfma_f32_32x32x16_bf16(af, bf1, acc[1], 0, 0, 0);
    }
  }
  __syncthreads();   // A/W dead; smem becomes hidl[64][132]
  #pragma unroll
  for (int tile = 0; tile < 2; tile++) {
    int col = wc*64 + tile*32 + (l & 31);
    float bias = bp1[col];
    #pragma unroll
    for (int reg = 0; reg < 16; reg++) {
      int row = (reg & 3) + 8*(reg >> 2) + 4*(l >> 5) + wr*32;
      hidl[row*132 + col] = fmaxf(acc[tile][reg] + bias, 0.f);
    }
  }
  __syncthreads();
  // phase 2: 256 outputs, one per thread
  int nl = t >> 2, i = t & 3;
  float s = bp2[i];
  for (int k = 0; k < 128; k += 4) {
    float4 hv = *(const float4*)&hidl[nl*132 + k];
    s = fmaf(hv.x, Wp2[(k+0)*4 + i],
        fmaf(hv.y, Wp2[(k+1)*4 + i],
        fmaf(hv.z, Wp2[(k+2)*4 + i],
        fmaf(hv.w, Wp2[(k+3)*4 + i], s))));
  }
  int n = r0 + nl;
  float esum = 0.f;
  if (n < N_NODES) {
    float e = expf(s);
    elg[n*4 + i] = e;
    esum = e;
  }
  #pragma unroll
  for (int msk = 1; msk < 64; msk <<= 1) esum += __shfl_xor(esum, msk);
  if ((t & 63) == 0) wred[t >> 6] = esum;
  __syncthreads();
  if (t == 0) atomicAdd(tot, (wred[0] + wred[1]) + (wred[2] + wred[3]));
}

// ---------------- normalize: out = elg * (1/tot) ----------------------------
__global__ void __launch_bounds__(1024) k_sm_final(const float* __restrict__ elg,
                                                   const float* __restrict__ tot,
                                                   float* __restrict__ out) {
  int i = blockIdx.x * 1024 + threadIdx.x;
  float inv = 1.f / tot[0];
  if (i < N_NODES * 4) out[i] = elg[i] * inv;
}

extern "C" void kernel_launch(void* const* d_in, const int* in_sizes, int n_in,
                              void* d_out, int out_size, void* d_ws, size_t ws_size,
                              hipStream_t stream) {
  const float* x    = (const float*)d_in[0];
  const int*   ei   = (const int*)  d_in[1];
  const float* ea   = (const float*)d_in[2];
  const float* Wl1  = (const float*)d_in[3];
  const float* bl1  = (const float*)d_in[4];
  const float* Wr1  = (const float*)d_in[5];
  const float* br1  = (const float*)d_in[6];
  const float* We1  = (const float*)d_in[7];
  const float* att1 = (const float*)d_in[8];
  const float* bias1= (const float*)d_in[9];
  const float* g1   = (const float*)d_in[10];
  const float* be1  = (const float*)d_in[11];
  const float* Wl2  = (const float*)d_in[12];
  const float* bl2  = (const float*)d_in[13];
  const float* Wr2  = (const float*)d_in[14];
  const float* br2  = (const float*)d_in[15];
  const float* We2  = (const float*)d_in[16];
  const float* att2 = (const float*)d_in[17];
  const float* bias2= (const float*)d_in[18];
  const float* g2   = (const float*)d_in[19];
  const float* be2  = (const float*)d_in[20];
  const float* Wp1  = (const float*)d_in[21];
  const float* bp1  = (const float*)d_in[22];
  const float* Wp2  = (const float*)d_in[23];
  const float* bp2  = (const float*)d_in[24];
  float* out = (float*)d_out;

  const int* srcp = ei;
  const int* dstp = ei + N_EDGES;

  // workspace layout: [deg | cursor | asum | tot] zeroed in ONE memset
  int*   deg    = (int*)d_ws;                // 10240
  int*   cursor = deg + 10240;               // 10240
  float* asum   = (float*)(cursor + 10240);  // 10240
  float* tot    = asum + 10240;              // 16
  int*   offs   = (int*)(tot + 16);          // 10240
  float* lattr  = (float*)(offs + 10240);    // 10240
  int2*  cpk    = (int2*)(lattr + 10240);    // CPK_CAP int2 (pad zeroed by scatter)
  unsigned short* h1b = (unsigned short*)(cpk + CPK_CAP);  // 10000x256 bf16
  unsigned short* h2b = h1b;                 // conv2 output aliases (h1b dead)
  unsigned short* xl2bf = h1b + 2560000;     // 10000x256 bf16
  float* xr2    = (float*)(xl2bf + 2560000); // 2560000 floats
  float* elg    = xr2 + 2560000;             // 40960
  unsigned short* Wt   = (unsigned short*)(elg + 40960);   // 512x256 bf16
  unsigned short* Wp1t = Wt + 512*256;                     // 128x256 bf16

  hipMemsetAsync(deg, 0, (3 * 10240 + 16) * sizeof(int), stream);

  k_cvtw   <<<dim3(8, 8, 2), 256, 0, stream>>>(Wl2, Wr2, Wt);
  k_cvtwp  <<<dim3(8, 4), 256, 0, stream>>>(Wp1, Wp1t);
  k_deg    <<<(N_EDGES + 255)/256, 256, 0, stream>>>(dstp, ea, deg, asum);
  k_scan   <<<1, 256, 0, stream>>>(deg, asum, offs, lattr);
  k_scatter<<<(CPK_CAP + 255)/256, 256, 0, stream>>>(srcp, dstp, ea, lattr, offs,
                                                     cursor, cpk);
  k_conv1  <<<N_NODES/4, 256, 0, stream>>>(x, Wl1, bl1, Wr1, br1, We1, att1,
                                           offs, cpk, bias1, g1, be1, (uint2*)h1b);
  k_gemm_dual<<<dim3(157, 4), 256, 0, stream>>>(h1b, Wt, bl2, br2, xl2bf, xr2);
  k_conv2  <<<N_NODES/4, 256, 0, stream>>>((const uint2*)xl2bf, xr2, offs, cpk,
                                           We2, att2, bias2, g2, be2, (uint2*)h2b);
  k_policy <<<157, 256, 0, stream>>>(h2b, Wp1t, bp1, Wp2, bp2, elg, tot);
  k_sm_final<<<40, 1024, 0, stream>>>(elg, tot, out);
}

// Round 12
// 287.877 us; speedup vs baseline: 1.3536x; 1.0635x over previous
//
#include <hip/hip_runtime.h>
#include <math.h>

#define N_NODES 10000
#define N_EDGES 320000
#define N_AUG   (N_EDGES + N_NODES)
#define CPK_CAP 330752
#define HID     256

typedef short short8 __attribute__((ext_vector_type(8)));
typedef float floatx16 __attribute__((ext_vector_type(16)));

// bf16 round-to-nearest-even, as the low 16 bits of a uint
static __device__ __forceinline__ unsigned bf16rne(float f) {
  unsigned u = __float_as_uint(f);
  return (u + 0x7FFFu + ((u >> 16) & 1u)) >> 16;
}

// ------- degree (+rank per edge) + edge_attr segment sum --------------------
__global__ void k_deg(const int* __restrict__ dst, const float* __restrict__ ea,
                      int* __restrict__ deg, float* __restrict__ asum,
                      int* __restrict__ rank) {
  int e = blockIdx.x * blockDim.x + threadIdx.x;
  if (e < N_EDGES) {
    int d = dst[e];
    rank[e] = atomicAdd(&deg[d], 1);
    atomicAdd(&asum[d], ea[e]);
  }
}

// ------- exclusive scan of (deg+1) over 10000 nodes (parallel), + loop_attr --
__global__ void __launch_bounds__(256) k_scan(
    const int* __restrict__ deg, const float* __restrict__ asum,
    int* __restrict__ offs, float* __restrict__ lattr) {
  __shared__ int wsum[4];
  int t = threadIdx.x;
  int base = t * 40;
  int s = 0;
  for (int i = 0; i < 40; i++) {
    int n = base + i;
    if (n < N_NODES) s += deg[n] + 1;
  }
  int v = s;
  #pragma unroll
  for (int d = 1; d < 64; d <<= 1) {
    int u = __shfl_up(v, d);
    if ((t & 63) >= d) v += u;
  }
  if ((t & 63) == 63) wsum[t >> 6] = v;
  __syncthreads();
  int wb = 0;
  for (int i = 0; i < (t >> 6); i++) wb += wsum[i];
  int run = wb + v - s;
  for (int i = 0; i < 40; i++) {
    int n = base + i;
    if (n < N_NODES) {
      offs[n] = run;
      int d = deg[n];
      run += d + 1;
      lattr[n] = asum[n] / (float)max(d, 1);
    }
  }
  if (t == 255) offs[N_NODES] = wb + v;
}

// ------- scatter edges into CSR by dst (atomic-free via rank); zero pad -----
__global__ void k_scatter(const int* __restrict__ src, const int* __restrict__ dst,
                          const float* __restrict__ ea, const float* __restrict__ lattr,
                          const int* __restrict__ offs, const int* __restrict__ rank,
                          int2* __restrict__ cpk) {
  int e = blockIdx.x * blockDim.x + threadIdx.x;
  if (e >= N_AUG) {
    if (e < CPK_CAP) cpk[e] = make_int2(0, 0);   // pad: row-0, av=0
    return;
  }
  int pos, s; float a;
  if (e < N_EDGES) {
    s = src[e];
    int d = dst[e];
    a = ea[e];
    pos = offs[d] + rank[e];
  } else {
    s = e - N_EDGES;
    a = lattr[s];
    pos = offs[s + 1] - 1;    // self-loop last in segment
  }
  cpk[pos] = make_int2(s, __float_as_int(a));
}

// ------- combined weight conversion: z<2 -> Wt slices, z==2 -> Wp1t ---------
__global__ void __launch_bounds__(256) k_prep(
    const float* __restrict__ W1, const float* __restrict__ W2,
    const float* __restrict__ Wp1,
    unsigned short* __restrict__ Wt, unsigned short* __restrict__ Wp1t) {
  __shared__ float tile[32][33];
  int z = blockIdx.z;
  int kb = blockIdx.x * 32, nb = blockIdx.y * 32;
  int t = threadIdx.x;
  int tx = t & 31, ty = t >> 5;
  if (z < 2) {
    const float* W = z ? W2 : W1;
    int rowoff = z * 256;
    #pragma unroll
    for (int rep = 0; rep < 4; rep++)
      tile[ty + 8*rep][tx] = W[(kb + ty + 8*rep)*HID + nb + tx];
    __syncthreads();
    #pragma unroll
    for (int rep = 0; rep < 4; rep++) {
      int n = nb + ty + 8*rep;
      Wt[(rowoff + n)*256 + kb + tx] = (unsigned short)bf16rne(tile[tx][ty + 8*rep]);
    }
  } else {
    if (nb >= 128) return;
    #pragma unroll
    for (int rep = 0; rep < 4; rep++)
      tile[ty + 8*rep][tx] = Wp1[(kb + ty + 8*rep)*128 + nb + tx];
    __syncthreads();
    #pragma unroll
    for (int rep = 0; rep < 4; rep++) {
      int n = nb + ty + 8*rep;
      Wp1t[n*256 + kb + tx] = (unsigned short)bf16rne(tile[tx][ty + 8*rep]);
    }
  }
}

// ============================ conv1 =========================================
#define C1_EDGE(xs, av, l0, l1, l2, l3, p)                                              \
  {                                                                                     \
    l0 = fmaf(xs.x,wl0.x, fmaf(xs.y,wl1.x, fmaf(xs.z,wl2.x, fmaf(xs.w,wl3.x, blv.x)))); \
    l1 = fmaf(xs.x,wl0.y, fmaf(xs.y,wl1.y, fmaf(xs.z,wl2.y, fmaf(xs.w,wl3.y, blv.y)))); \
    l2 = fmaf(xs.x,wl0.z, fmaf(xs.y,wl1.z, fmaf(xs.z,wl2.z, fmaf(xs.w,wl3.z, blv.z)))); \
    l3 = fmaf(xs.x,wl0.w, fmaf(xs.y,wl1.w, fmaf(xs.z,wl2.w, fmaf(xs.w,wl3.w, blv.w)))); \
    float m0 = l0 + fmaf(av, we.x, r4.x); m0 = fmaxf(m0, 0.2f*m0);                      \
    float m1 = l1 + fmaf(av, we.y, r4.y); m1 = fmaxf(m1, 0.2f*m1);                      \
    float m2 = l2 + fmaf(av, we.z, r4.z); m2 = fmaxf(m2, 0.2f*m2);                      \
    float m3 = l3 + fmaf(av, we.w, r4.w); m3 = fmaxf(m3, 0.2f*m3);                      \
    p = m0*at.x + m1*at.y + m2*at.z + m3*at.w;                                          \
  }

// body over resident metadata eA..eH and resident rows xA..xH
#define C1_BODY8()                                                              \
  {                                                                             \
    float avA = __int_as_float(eA.y), avB = __int_as_float(eB.y);               \
    float avC = __int_as_float(eC.y), avD = __int_as_float(eD.y);               \
    float avE = __int_as_float(eE.y), avF = __int_as_float(eF.y);               \
    float avG = __int_as_float(eG.y), avH = __int_as_float(eH.y);               \
    float lA0,lA1,lA2,lA3,pA, lB0,lB1,lB2,lB3,pB;                               \
    float lC0,lC1,lC2,lC3,pC, lD0,lD1,lD2,lD3,pD;                               \
    float lE0,lE1,lE2,lE3,pE, lF0,lF1,lF2,lF3,pF;                               \
    float lG0,lG1,lG2,lG3,pG, lH0,lH1,lH2,lH3,pH;                               \
    C1_EDGE(xA, avA, lA0,lA1,lA2,lA3, pA);                                      \
    C1_EDGE(xB, avB, lB0,lB1,lB2,lB3, pB);                                      \
    C1_EDGE(xC, avC, lC0,lC1,lC2,lC3, pC);                                      \
    C1_EDGE(xD, avD, lD0,lD1,lD2,lD3, pD);                                      \
    C1_EDGE(xE, avE, lE0,lE1,lE2,lE3, pE);                                      \
    C1_EDGE(xF, avF, lF0,lF1,lF2,lF3, pF);                                      \
    C1_EDGE(xG, avG, lG0,lG1,lG2,lG3, pG);                                      \
    C1_EDGE(xH, avH, lH0,lH1,lH2,lH3, pH);                                      \
    float sAB = b1 ? pA : pB, kAB = b1 ? pB : pA;                               \
    float qAB = kAB + __shfl_xor(sAB, 1);                                       \
    float sCD = b1 ? pC : pD, kCD = b1 ? pD : pC;                               \
    float qCD = kCD + __shfl_xor(sCD, 1);                                       \
    float sEF = b1 ? pE : pF, kEF = b1 ? pF : pE;                               \
    float qEF = kEF + __shfl_xor(sEF, 1);                                       \
    float sGH = b1 ? pG : pH, kGH = b1 ? pH : pG;                               \
    float qGH = kGH + __shfl_xor(sGH, 1);                                       \
    float u0s = b2 ? qAB : qCD, u0k = b2 ? qCD : qAB;                           \
    float u0 = u0k + __shfl_xor(u0s, 2);                                        \
    float u1s = b2 ? qEF : qGH, u1k = b2 ? qGH : qEF;                           \
    float u1 = u1k + __shfl_xor(u1s, 2);                                        \
    float vvs = b4 ? u0 : u1, vvk = b4 ? u1 : u0;                               \
    float vv = vvk + __shfl_xor(vvs, 4);                                        \
    vv += __shfl_xor(vv, 8);                                                    \
    float exv = expf(vv);                                                       \
    float xAe = __shfl(exv, 0, 16), xBe = __shfl(exv, 1, 16);                   \
    float xCe = __shfl(exv, 2, 16), xDe = __shfl(exv, 3, 16);                   \
    float xEe = __shfl(exv, 4, 16), xFe = __shfl(exv, 5, 16);                   \
    float xGe = __shfl(exv, 6, 16), xHe = __shfl(exv, 7, 16);                   \
    D += ((xAe + xBe) + (xCe + xDe)) + ((xEe + xFe) + (xGe + xHe));             \
    a0 = fmaf(xDe, lD0, fmaf(xCe, lC0, fmaf(xBe, lB0, fmaf(xAe, lA0, a0))));    \
    a0 = fmaf(xHe, lH0, fmaf(xGe, lG0, fmaf(xFe, lF0, fmaf(xEe, lE0, a0))));    \
    a1 = fmaf(xDe, lD1, fmaf(xCe, lC1, fmaf(xBe, lB1, fmaf(xAe, lA1, a1))));    \
    a1 = fmaf(xHe, lH1, fmaf(xGe, lG1, fmaf(xFe, lF1, fmaf(xEe, lE1, a1))));    \
    a2 = fmaf(xDe, lD2, fmaf(xCe, lC2, fmaf(xBe, lB2, fmaf(xAe, lA2, a2))));    \
    a2 = fmaf(xHe, lH2, fmaf(xGe, lG2, fmaf(xFe, lF2, fmaf(xEe, lE2, a2))));    \
    a3 = fmaf(xDe, lD3, fmaf(xCe, lC3, fmaf(xBe, lB3, fmaf(xAe, lA3, a3))));    \
    a3 = fmaf(xHe, lH3, fmaf(xGe, lG3, fmaf(xFe, lF3, fmaf(xEe, lE3, a3))));    \
  }

__global__ void __launch_bounds__(256) k_conv1(
    const float* __restrict__ x,
    const float* __restrict__ Wl, const float* __restrict__ bl,
    const float* __restrict__ Wr, const float* __restrict__ br,
    const float* __restrict__ We, const float* __restrict__ att,
    const int* __restrict__ offs, const int2* __restrict__ cpk,
    const float* __restrict__ bias, const float* __restrict__ g,
    const float* __restrict__ be, uint2* __restrict__ h1b) {
  int t = threadIdx.x;
  int n = blockIdx.x * 4 + (t >> 6);
  int c = 4 * (t & 63);
  bool b1 = (t & 1) != 0, b2 = (t & 2) != 0, b4 = (t & 4) != 0;

  float4 wl0 = *(const float4*)&Wl[0*HID + c];
  float4 wl1 = *(const float4*)&Wl[1*HID + c];
  float4 wl2 = *(const float4*)&Wl[2*HID + c];
  float4 wl3 = *(const float4*)&Wl[3*HID + c];
  float4 blv = *(const float4*)&bl[c];
  float4 we  = *(const float4*)&We[c];
  float4 at  = *(const float4*)&att[c];

  float4 xn = *(const float4*)&x[n*4];
  float4 r4;
  {
    float4 wr0 = *(const float4*)&Wr[0*HID + c];
    float4 wr1 = *(const float4*)&Wr[1*HID + c];
    float4 wr2 = *(const float4*)&Wr[2*HID + c];
    float4 wr3 = *(const float4*)&Wr[3*HID + c];
    float4 brv = *(const float4*)&br[c];
    r4.x = fmaf(xn.x,wr0.x, fmaf(xn.y,wr1.x, fmaf(xn.z,wr2.x, fmaf(xn.w,wr3.x, brv.x))));
    r4.y = fmaf(xn.x,wr0.y, fmaf(xn.y,wr1.y, fmaf(xn.z,wr2.y, fmaf(xn.w,wr3.y, brv.y))));
    r4.z = fmaf(xn.x,wr0.z, fmaf(xn.y,wr1.z, fmaf(xn.z,wr2.z, fmaf(xn.w,wr3.z, brv.z))));
    r4.w = fmaf(xn.x,wr0.w, fmaf(xn.y,wr1.w, fmaf(xn.z,wr2.w, fmaf(xn.w,wr3.w, brv.w))));
  }

  int js = __builtin_amdgcn_readfirstlane(offs[n]);
  int je = __builtin_amdgcn_readfirstlane(offs[n+1]);

  float D = 0.f, a0 = 0.f, a1 = 0.f, a2 = 0.f, a3 = 0.f;

  int j = js;
  if (je - js >= 16) {
    // two-stage pipeline: metadata 2 batches ahead, x-rows 1 batch ahead
    int2 eA = cpk[j],   eB = cpk[j+1], eC = cpk[j+2], eD = cpk[j+3];
    int2 eE = cpk[j+4], eF = cpk[j+5], eG = cpk[j+6], eH = cpk[j+7];
    int2 fA = cpk[j+8],  fB = cpk[j+9],  fC = cpk[j+10], fD = cpk[j+11];
    int2 fE = cpk[j+12], fF = cpk[j+13], fG = cpk[j+14], fH = cpk[j+15];
    float4 xA = *(const float4*)&x[eA.x*4];
    float4 xB = *(const float4*)&x[eB.x*4];
    float4 xC = *(const float4*)&x[eC.x*4];
    float4 xD = *(const float4*)&x[eD.x*4];
    float4 xE = *(const float4*)&x[eE.x*4];
    float4 xF = *(const float4*)&x[eF.x*4];
    float4 xG = *(const float4*)&x[eG.x*4];
    float4 xH = *(const float4*)&x[eH.x*4];
    for (; j + 15 < je; j += 8) {
      float4 yA = *(const float4*)&x[fA.x*4];
      float4 yB = *(const float4*)&x[fB.x*4];
      float4 yC = *(const float4*)&x[fC.x*4];
      float4 yD = *(const float4*)&x[fD.x*4];
      float4 yE = *(const float4*)&x[fE.x*4];
      float4 yF = *(const float4*)&x[fF.x*4];
      float4 yG = *(const float4*)&x[fG.x*4];
      float4 yH = *(const float4*)&x[fH.x*4];
      int2 gA = cpk[j+16], gB = cpk[j+17], gC = cpk[j+18], gD = cpk[j+19];
      int2 gE = cpk[j+20], gF = cpk[j+21], gG = cpk[j+22], gH = cpk[j+23];
      C1_BODY8();
      eA = fA; eB = fB; eC = fC; eD = fD; eE = fE; eF = fF; eG = fG; eH = fH;
      fA = gA; fB = gB; fC = gC; fD = gD; fE = gE; fF = gF; fG = gG; fH = gH;
      xA = yA; xB = yB; xC = yC; xD = yD; xE = yE; xF = yF; xG = yG; xH = yH;
    }
    C1_BODY8();
    j += 8;
  }
  for (; j + 7 < je; j += 8) {
    int2 eA = cpk[j],   eB = cpk[j+1], eC = cpk[j+2], eD = cpk[j+3];
    int2 eE = cpk[j+4], eF = cpk[j+5], eG = cpk[j+6], eH = cpk[j+7];
    float4 xA = *(const float4*)&x[eA.x*4];
    float4 xB = *(const float4*)&x[eB.x*4];
    float4 xC = *(const float4*)&x[eC.x*4];
    float4 xD = *(const float4*)&x[eD.x*4];
    float4 xE = *(const float4*)&x[eE.x*4];
    float4 xF = *(const float4*)&x[eF.x*4];
    float4 xG = *(const float4*)&x[eG.x*4];
    float4 xH = *(const float4*)&x[eH.x*4];
    C1_BODY8();
  }
  for (; j < je; j++) {
    int2 eA = cpk[j];
    float4 xA = *(const float4*)&x[eA.x*4];
    float avA = __int_as_float(eA.y);
    float lA0,lA1,lA2,lA3,pA;
    C1_EDGE(xA, avA, lA0,lA1,lA2,lA3, pA);
    #pragma unroll
    for (int msk = 1; msk < 16; msk <<= 1) pA += __shfl_xor(pA, msk);
    float eAx = expf(pA);
    D += eAx;
    a0 = fmaf(eAx, lA0, a0);
    a1 = fmaf(eAx, lA1, a1);
    a2 = fmaf(eAx, lA2, a2);
    a3 = fmaf(eAx, lA3, a3);
  }

  float inv = 1.f / D;
  float4 b4v = *(const float4*)&bias[c];
  float o0 = fmaf(a0, inv, b4v.x);
  float o1 = fmaf(a1, inv, b4v.y);
  float o2 = fmaf(a2, inv, b4v.z);
  float o3 = fmaf(a3, inv, b4v.w);

  float s = o0 + o1 + o2 + o3;
  #pragma unroll
  for (int msk = 1; msk < 64; msk <<= 1) s += __shfl_xor(s, msk);
  float mu = s * (1.f / 256.f);
  float d0 = o0 - mu, d1 = o1 - mu, d2 = o2 - mu, d3 = o3 - mu;
  float sq = d0*d0 + d1*d1 + d2*d2 + d3*d3;
  #pragma unroll
  for (int msk = 1; msk < 64; msk <<= 1) sq += __shfl_xor(sq, msk);
  float rstd = rsqrtf(sq * (1.f / 256.f) + 1e-5f);
  float4 g4  = *(const float4*)&g[c];
  float4 be4 = *(const float4*)&be[c];
  float oy0 = fmaxf(fmaf(d0 * rstd, g4.x, be4.x), 0.f);
  float oy1 = fmaxf(fmaf(d1 * rstd, g4.y, be4.y), 0.f);
  float oy2 = fmaxf(fmaf(d2 * rstd, g4.z, be4.z), 0.f);
  float oy3 = fmaxf(fmaf(d3 * rstd, g4.w, be4.w), 0.f);
  uint2 pk;
  pk.x = bf16rne(oy0) | (bf16rne(oy1) << 16);
  pk.y = bf16rne(oy2) | (bf16rne(oy3) << 16);
  h1b[n*64 + (t & 63)] = pk;
}

// ============================ conv2 =========================================
#define C2_LOAD(q, xs)                                  \
  float4 xs;                                            \
  xs.x = __uint_as_float(q.x << 16);                    \
  xs.y = __uint_as_float(q.x & 0xFFFF0000u);            \
  xs.z = __uint_as_float(q.y << 16);                    \
  xs.w = __uint_as_float(q.y & 0xFFFF0000u);

#define C2_EDGE(xs, av, p)                                           \
  {                                                                  \
    float m0 = xs.x + fmaf(av, we.x, r4.x); m0 = fmaxf(m0, 0.2f*m0); \
    float m1 = xs.y + fmaf(av, we.y, r4.y); m1 = fmaxf(m1, 0.2f*m1); \
    float m2 = xs.z + fmaf(av, we.z, r4.z); m2 = fmaxf(m2, 0.2f*m2); \
    float m3 = xs.w + fmaf(av, we.w, r4.w); m3 = fmaxf(m3, 0.2f*m3); \
    p = m0*at.x + m1*at.y + m2*at.z + m3*at.w;                       \
  }

#define C2_PROC8()                                                              \
  {                                                                             \
    C2_LOAD(q0, xs0); C2_LOAD(q1, xs1); C2_LOAD(q2, xs2); C2_LOAD(q3, xs3);     \
    C2_LOAD(q4, xs4); C2_LOAD(q5, xs5); C2_LOAD(q6, xs6); C2_LOAD(q7, xs7);     \
    float av0 = __int_as_float(e0.y), av1 = __int_as_float(e1.y);               \
    float av2 = __int_as_float(e2.y), av3 = __int_as_float(e3.y);               \
    float av4 = __int_as_float(e4.y), av5 = __int_as_float(e5.y);               \
    float av6 = __int_as_float(e6.y), av7 = __int_as_float(e7.y);               \
    float p0,p1,p2,p3,p4,p5,p6,p7;                                              \
    C2_EDGE(xs0, av0, p0); C2_EDGE(xs1, av1, p1);                               \
    C2_EDGE(xs2, av2, p2); C2_EDGE(xs3, av3, p3);                               \
    C2_EDGE(xs4, av4, p4); C2_EDGE(xs5, av5, p5);                               \
    C2_EDGE(xs6, av6, p6); C2_EDGE(xs7, av7, p7);                               \
    float sAB = b1 ? p0 : p1, kAB = b1 ? p1 : p0;                               \
    float qAB = kAB + __shfl_xor(sAB, 1);                                       \
    float sCD = b1 ? p2 : p3, kCD = b1 ? p3 : p2;                               \
    float qCD = kCD + __shfl_xor(sCD, 1);                                       \
    float sEF = b1 ? p4 : p5, kEF = b1 ? p5 : p4;                               \
    float qEF = kEF + __shfl_xor(sEF, 1);                                       \
    float sGH = b1 ? p6 : p7, kGH = b1 ? p7 : p6;                               \
    float qGH = kGH + __shfl_xor(sGH, 1);                                       \
    float u0s = b2 ? qAB : qCD, u0k = b2 ? qCD : qAB;                           \
    float u0 = u0k + __shfl_xor(u0s, 2);                                        \
    float u1s = b2 ? qEF : qGH, u1k = b2 ? qGH : qEF;                           \
    float u1 = u1k + __shfl_xor(u1s, 2);                                        \
    float vvs = b4 ? u0 : u1, vvk = b4 ? u1 : u0;                               \
    float vv = vvk + __shfl_xor(vvs, 4);                                        \
    vv += __shfl_xor(vv, 8);                                                    \
    vv += __shfl_xor(vv, 16);                                                   \
    vv += __shfl_xor(vv, 32);                                                   \
    float exv = expf(vv);                                                       \
    float x0 = __shfl(exv, 0), x1 = __shfl(exv, 1);                             \
    float x2 = __shfl(exv, 2), x3 = __shfl(exv, 3);                             \
    float x4 = __shfl(exv, 4), x5 = __shfl(exv, 5);                             \
    float x6 = __shfl(exv, 6), x7 = __shfl(exv, 7);                             \
    D += ((x0 + x1) + (x2 + x3)) + ((x4 + x5) + (x6 + x7));                     \
    a0 = fmaf(x3, xs3.x, fmaf(x2, xs2.x, fmaf(x1, xs1.x, fmaf(x0, xs0.x, a0))));\
    a0 = fmaf(x7, xs7.x, fmaf(x6, xs6.x, fmaf(x5, xs5.x, fmaf(x4, xs4.x, a0))));\
    a1 = fmaf(x3, xs3.y, fmaf(x2, xs2.y, fmaf(x1, xs1.y, fmaf(x0, xs0.y, a1))));\
    a1 = fmaf(x7, xs7.y, fmaf(x6, xs6.y, fmaf(x5, xs5.y, fmaf(x4, xs4.y, a1))));\
    a2 = fmaf(x3, xs3.z, fmaf(x2, xs2.z, fmaf(x1, xs1.z, fmaf(x0, xs0.z, a2))));\
    a2 = fmaf(x7, xs7.z, fmaf(x6, xs6.z, fmaf(x5, xs5.z, fmaf(x4, xs4.z, a2))));\
    a3 = fmaf(x3, xs3.w, fmaf(x2, xs2.w, fmaf(x1, xs1.w, fmaf(x0, xs0.w, a3))));\
    a3 = fmaf(x7, xs7.w, fmaf(x6, xs6.w, fmaf(x5, xs5.w, fmaf(x4, xs4.w, a3))));\
  }

__global__ void __launch_bounds__(256) k_conv2(
    const uint2* __restrict__ xlb, const float* __restrict__ xr,
    const int* __restrict__ offs, const int2* __restrict__ cpk,
    const float* __restrict__ We, const float* __restrict__ att,
    const float* __restrict__ bias, const float* __restrict__ g,
    const float* __restrict__ be, uint2* __restrict__ h2b) {
  int t = threadIdx.x;
  int n = blockIdx.x * 4 + (t >> 6);
  int lane = t & 63;
  int c = 4 * lane;
  bool b1 = (t & 1) != 0, b2 = (t & 2) != 0, b4 = (t & 4) != 0;
  float4 r4 = *(const float4*)&xr[n*HID + c];
  float4 we = *(const float4*)&We[c];
  float4 at = *(const float4*)&att[c];
  int js = __builtin_amdgcn_readfirstlane(offs[n]);
  int je = __builtin_amdgcn_readfirstlane(offs[n+1]);

  float D = 0.f, a0 = 0.f, a1 = 0.f, a2 = 0.f, a3 = 0.f;

  int j = js;
  if (je - js >= 16) {
    int2 e0 = cpk[j],   e1 = cpk[j+1], e2 = cpk[j+2], e3 = cpk[j+3];
    int2 e4 = cpk[j+4], e5 = cpk[j+5], e6 = cpk[j+6], e7 = cpk[j+7];
    int2 f0 = cpk[j+8],  f1 = cpk[j+9],  f2 = cpk[j+10], f3 = cpk[j+11];
    int2 f4 = cpk[j+12], f5 = cpk[j+13], f6 = cpk[j+14], f7 = cpk[j+15];
    uint2 q0 = xlb[e0.x*64 + lane];
    uint2 q1 = xlb[e1.x*64 + lane];
    uint2 q2 = xlb[e2.x*64 + lane];
    uint2 q3 = xlb[e3.x*64 + lane];
    uint2 q4 = xlb[e4.x*64 + lane];
    uint2 q5 = xlb[e5.x*64 + lane];
    uint2 q6 = xlb[e6.x*64 + lane];
    uint2 q7 = xlb[e7.x*64 + lane];
    for (; j + 15 < je; j += 8) {
      uint2 r0 = xlb[f0.x*64 + lane];
      uint2 r1 = xlb[f1.x*64 + lane];
      uint2 r2 = xlb[f2.x*64 + lane];
      uint2 r3 = xlb[f3.x*64 + lane];
      uint2 r4_ = xlb[f4.x*64 + lane];
      uint2 r5 = xlb[f5.x*64 + lane];
      uint2 r6 = xlb[f6.x*64 + lane];
      uint2 r7 = xlb[f7.x*64 + lane];
      int2 g0 = cpk[j+16], g1 = cpk[j+17], g2 = cpk[j+18], g3 = cpk[j+19];
      int2 g4 = cpk[j+20], g5 = cpk[j+21], g6 = cpk[j+22], g7 = cpk[j+23];
      C2_PROC8();
      e0 = f0; e1 = f1; e2 = f2; e3 = f3; e4 = f4; e5 = f5; e6 = f6; e7 = f7;
      f0 = g0; f1 = g1; f2 = g2; f3 = g3; f4 = g4; f5 = g5; f6 = g6; f7 = g7;
      q0 = r0; q1 = r1; q2 = r2; q3 = r3; q4 = r4_; q5 = r5; q6 = r6; q7 = r7;
    }
    C2_PROC8();
    j += 8;
  }
  for (; j + 7 < je; j += 8) {
    int2 e0 = cpk[j],   e1 = cpk[j+1], e2 = cpk[j+2], e3 = cpk[j+3];
    int2 e4 = cpk[j+4], e5 = cpk[j+5], e6 = cpk[j+6], e7 = cpk[j+7];
    uint2 q0 = xlb[e0.x*64 + lane];
    uint2 q1 = xlb[e1.x*64 + lane];
    uint2 q2 = xlb[e2.x*64 + lane];
    uint2 q3 = xlb[e3.x*64 + lane];
    uint2 q4 = xlb[e4.x*64 + lane];
    uint2 q5 = xlb[e5.x*64 + lane];
    uint2 q6 = xlb[e6.x*64 + lane];
    uint2 q7 = xlb[e7.x*64 + lane];
    C2_PROC8();
  }
  for (; j < je; j++) {
    int2 e0 = cpk[j];
    float av0 = __int_as_float(e0.y);
    uint2 q0 = xlb[e0.x*64 + lane];
    C2_LOAD(q0, xs0);
    float p0;
    C2_EDGE(xs0, av0, p0);
    #pragma unroll
    for (int msk = 1; msk < 64; msk <<= 1) p0 += __shfl_xor(p0, msk);
    float x0 = expf(p0);
    D += x0;
    a0 = fmaf(x0, xs0.x, a0);
    a1 = fmaf(x0, xs0.y, a1);
    a2 = fmaf(x0, xs0.z, a2);
    a3 = fmaf(x0, xs0.w, a3);
  }

  float inv = 1.f / D;
  float4 b4v = *(const float4*)&bias[c];
  float o0 = fmaf(a0, inv, b4v.x);
  float o1 = fmaf(a1, inv, b4v.y);
  float o2 = fmaf(a2, inv, b4v.z);
  float o3 = fmaf(a3, inv, b4v.w);

  float s = o0 + o1 + o2 + o3;
  #pragma unroll
  for (int msk = 1; msk < 64; msk <<= 1) s += __shfl_xor(s, msk);
  float mu = s * (1.f / 256.f);
  float d0 = o0 - mu, d1 = o1 - mu, d2 = o2 - mu, d3 = o3 - mu;
  float sq = d0*d0 + d1*d1 + d2*d2 + d3*d3;
  #pragma unroll
  for (int msk = 1; msk < 64; msk <<= 1) sq += __shfl_xor(sq, msk);
  float rstd = rsqrtf(sq * (1.f / 256.f) + 1e-5f);
  float4 g4  = *(const float4*)&g[c];
  float4 be4 = *(const float4*)&be[c];
  float oy0 = fmaxf(fmaf(d0 * rstd, g4.x, be4.x), 0.f);
  float oy1 = fmaxf(fmaf(d1 * rstd, g4.y, be4.y), 0.f);
  float oy2 = fmaxf(fmaf(d2 * rstd, g4.z, be4.z), 0.f);
  float oy3 = fmaxf(fmaf(d3 * rstd, g4.w, be4.w), 0.f);
  uint2 pk;
  pk.x = bf16rne(oy0) | (bf16rne(oy1) << 16);
  pk.y = bf16rne(oy2) | (bf16rne(oy3) << 16);
  h2b[n*64 + lane] = pk;
}

// ---------------- dual GEMM v4: bf16 MFMA 32x32x16 --------------------------
__global__ void __launch_bounds__(256) k_gemm_dual(
    const unsigned short* __restrict__ h1b, const unsigned short* __restrict__ Wt,
    const float* __restrict__ b1, const float* __restrict__ b2,
    unsigned short* __restrict__ O1b, float* __restrict__ O2) {
  __shared__ unsigned short A_lds[64][72];
  __shared__ unsigned short W_lds[128][72];
  int t = threadIdx.x;
  int r0 = blockIdx.x * 64;
  int nb0 = blockIdx.y * 128;
  int l = t & 63;
  int wave = t >> 6;
  int wr = wave >> 1, wc = wave & 1;

  floatx16 acc[2] = {{0}, {0}};

  int sar = t >> 2, sak = (t & 3) * 16;
  int arow = min(r0 + sar, N_NODES - 1);
  int swn = t >> 1, swk = (t & 1) * 32;
  const unsigned short* Wrow = &Wt[(nb0 + swn) * 256];

  for (int kb = 0; kb < 256; kb += 64) {
    uint4 av0 = *(const uint4*)&h1b[arow*256 + kb + sak];
    uint4 av1 = *(const uint4*)&h1b[arow*256 + kb + sak + 8];
    uint4 wv0 = *(const uint4*)&Wrow[kb + swk];
    uint4 wv1 = *(const uint4*)&Wrow[kb + swk + 8];
    uint4 wv2 = *(const uint4*)&Wrow[kb + swk + 16];
    uint4 wv3 = *(const uint4*)&Wrow[kb + swk + 24];
    __syncthreads();
    *(uint4*)&A_lds[sar][sak]     = av0;
    *(uint4*)&A_lds[sar][sak + 8] = av1;
    *(uint4*)&W_lds[swn][swk]      = wv0;
    *(uint4*)&W_lds[swn][swk +  8] = wv1;
    *(uint4*)&W_lds[swn][swk + 16] = wv2;
    *(uint4*)&W_lds[swn][swk + 24] = wv3;
    __syncthreads();
    #pragma unroll
    for (int ks = 0; ks < 64; ks += 16) {
      short8 af  = *(const short8*)&A_lds[wr*32 + (l & 31)][ks + 8*(l >> 5)];
      short8 bf0 = *(const short8*)&W_lds[wc*64      + (l & 31)][ks + 8*(l >> 5)];
      short8 bf1 = *(const short8*)&W_lds[wc*64 + 32 + (l & 31)][ks + 8*(l >> 5)];
      acc[0] = __builtin_amdgcn_mfma_f32_32x32x16_bf16(af, bf0, acc[0], 0, 0, 0);
      acc[1] = __builtin_amdgcn_mfma_f32_32x32x16_bf16(af, bf1, acc[1], 0, 0, 0);
    }
  }

  bool isO1 = (nb0 < 256);
  #pragma unroll
  for (int tile = 0; tile < 2; tile++) {
    int col = nb0 + wc*64 + tile*32 + (l & 31);
    float bias = isO1 ? b1[col] : b2[col - 256];
    #pragma unroll
    for (int reg = 0; reg < 16; reg++) {
      int row = (reg & 3) + 8*(reg >> 2) + 4*(l >> 5);
      int r = r0 + wr*32 + row;
      if (r < N_NODES) {
        float v = acc[tile][reg] + bias;
        if (isO1) O1b[r*256 + col] = (unsigned short)bf16rne(v);
        else      O2[r*256 + (col - 256)] = v;
      }
    }
  }
}

// ------- policy v4: bf16 MFMA phase1 (64x128), LDS hid, phase2 + exp --------
__global__ void __launch_bounds__(256) k_policy(
    const unsigned short* __restrict__ h2b, const unsigned short* __restrict__ Wp1t,
    const float* __restrict__ bp1, const float* __restrict__ Wp2,
    const float* __restrict__ bp2, float* __restrict__ elg, float* __restrict__ tot) {
  __shared__ __align__(16) char smembuf[64 * 132 * 4];   // 33792 B union
  unsigned short* A_lds = (unsigned short*)smembuf;                  // [64][72]
  unsigned short* W_lds = (unsigned short*)(smembuf + 64*72*2);      // [128][72]
  float* hidl = (float*)smembuf;                                     // [64][132]
  __shared__ float wred[4];
  int t = threadIdx.x;
  int r0 = blockIdx.x * 64;
  int l = t & 63;
  int wave = t >> 6;
  int wr = wave >> 1, wc = wave & 1;

  floatx16 acc[2] = {{0}, {0}};

  int sar = t >> 2, sak = (t & 3) * 16;
  int arow = min(r0 + sar, N_NODES - 1);
  int swn = t >> 1, swk = (t & 1) * 32;
  const unsigned short* Wrow = &Wp1t[swn * 256];

  for (int kb = 0; kb < 256; kb += 64) {
    uint4 av0 = *(const uint4*)&h2b[arow*256 + kb + sak];
    uint4 av1 = *(const uint4*)&h2b[arow*256 + kb + sak + 8];
    uint4 wv0 = *(const uint4*)&Wrow[kb + swk];
    uint4 wv1 = *(const uint4*)&Wrow[kb + swk + 8];
    uint4 wv2 = *(const uint4*)&Wrow[kb + swk + 16];
    uint4 wv3 = *(const uint4*)&Wrow[kb + swk + 24];
    __syncthreads();
    *(uint4*)&A_lds[sar*72 + sak]     = av0;
    *(uint4*)&A_lds[sar*72 + sak + 8] = av1;
    *(uint4*)&W_lds[swn*72 + swk]      = wv0;
    *(uint4*)&W_lds[swn*72 + swk +  8] = wv1;
    *(uint4*)&W_lds[swn*72 + swk + 16] = wv2;
    *(uint4*)&W_lds[swn*72 + swk + 24] = wv3;
    __syncthreads();
    #pragma unroll
    for (int ks = 0; ks < 64; ks += 16) {
      short8 af  = *(const short8*)&A_lds[(wr*32 + (l & 31))*72 + ks + 8*(l >> 5)];
      short8 bf0 = *(const short8*)&W_lds[(wc*64      + (l & 31))*72 + ks + 8*(l >> 5)];
      short8 bf1 = *(const short8*)&W_lds[(wc*64 + 32 + (l & 31))*72 + ks + 8*(l >> 5)];
      acc[0] = __builtin_amdgcn_mfma_f32_32x32x16_bf16(af, bf0, acc[0], 0, 0, 0);
      acc[1] = __builtin_amdgcn_mfma_f32_32x32x16_bf16(af, bf1, acc[1], 0, 0, 0);
    }
  }
  __syncthreads();   // A/W dead; smem becomes hidl[64][132]
  #pragma unroll
  for (int tile = 0; tile < 2; tile++) {
    int col = wc*64 + tile*32 + (l & 31);
    float bias = bp1[col];
    #pragma unroll
    for (int reg = 0; reg < 16; reg++) {
      int row = (reg & 3) + 8*(reg >> 2) + 4*(l >> 5) + wr*32;
      hidl[row*132 + col] = fmaxf(acc[tile][reg] + bias, 0.f);
    }
  }
  __syncthreads();
  int nl = t >> 2, i = t & 3;
  float s = bp2[i];
  for (int k = 0; k < 128; k += 4) {
    float4 hv = *(const float4*)&hidl[nl*132 + k];
    s = fmaf(hv.x, Wp2[(k+0)*4 + i],
        fmaf(hv.y, Wp2[(k+1)*4 + i],
        fmaf(hv.z, Wp2[(k+2)*4 + i],
        fmaf(hv.w, Wp2[(k+3)*4 + i], s))));
  }
  int n = r0 + nl;
  float esum = 0.f;
  if (n < N_NODES) {
    float e = expf(s);
    elg[n*4 + i] = e;
    esum = e;
  }
  #pragma unroll
  for (int msk = 1; msk < 64; msk <<= 1) esum += __shfl_xor(esum, msk);
  if ((t & 63) == 0) wred[t >> 6] = esum;
  __syncthreads();
  if (t == 0) atomicAdd(tot, (wred[0] + wred[1]) + (wred[2] + wred[3]));
}

// ---------------- normalize: out = elg * (1/tot) ----------------------------
__global__ void __launch_bounds__(1024) k_sm_final(const float* __restrict__ elg,
                                                   const float* __restrict__ tot,
                                                   float* __restrict__ out) {
  int i = blockIdx.x * 1024 + threadIdx.x;
  float inv = 1.f / tot[0];
  if (i < N_NODES * 4) out[i] = elg[i] * inv;
}

extern "C" void kernel_launch(void* const* d_in, const int* in_sizes, int n_in,
                              void* d_out, int out_size, void* d_ws, size_t ws_size,
                              hipStream_t stream) {
  const float* x    = (const float*)d_in[0];
  const int*   ei   = (const int*)  d_in[1];
  const float* ea   = (const float*)d_in[2];
  const float* Wl1  = (const float*)d_in[3];
  const float* bl1  = (const float*)d_in[4];
  const float* Wr1  = (const float*)d_in[5];
  const float* br1  = (const float*)d_in[6];
  const float* We1  = (const float*)d_in[7];
  const float* att1 = (const float*)d_in[8];
  const float* bias1= (const float*)d_in[9];
  const float* g1   = (const float*)d_in[10];
  const float* be1  = (const float*)d_in[11];
  const float* Wl2  = (const float*)d_in[12];
  const float* bl2  = (const float*)d_in[13];
  const float* Wr2  = (const float*)d_in[14];
  const float* br2  = (const float*)d_in[15];
  const float* We2  = (const float*)d_in[16];
  const float* att2 = (const float*)d_in[17];
  const float* bias2= (const float*)d_in[18];
  const float* g2   = (const float*)d_in[19];
  const float* be2  = (const float*)d_in[20];
  const float* Wp1  = (const float*)d_in[21];
  const float* bp1  = (const float*)d_in[22];
  const float* Wp2  = (const float*)d_in[23];
  const float* bp2  = (const float*)d_in[24];
  float* out = (float*)d_out;

  const int* srcp = ei;
  const int* dstp = ei + N_EDGES;

  // workspace layout: [deg | asum | tot] zeroed in ONE memset
  int*   deg    = (int*)d_ws;                // 10240
  float* asum   = (float*)(deg + 10240);     // 10240
  float* tot    = asum + 10240;              // 16
  int*   offs   = (int*)(tot + 16);          // 10240
  float* lattr  = (float*)(offs + 10240);    // 10240
  int*   rank   = (int*)(lattr + 10240);     // 320000 (+192 pad)
  int2*  cpk    = (int2*)(rank + 320192);    // CPK_CAP int2 (pad zeroed by scatter)
  unsigned short* h1b = (unsigned short*)(cpk + CPK_CAP);  // 10000x256 bf16
  unsigned short* h2b = h1b;                 // conv2 output aliases (h1b dead)
  unsigned short* xl2bf = h1b + 2560000;     // 10000x256 bf16
  float* xr2    = (float*)(xl2bf + 2560000); // 2560000 floats
  float* elg    = xr2 + 2560000;             // 40960
  unsigned short* Wt   = (unsigned short*)(elg + 40960);   // 512x256 bf16
  unsigned short* Wp1t = Wt + 512*256;                     // 128x256 bf16

  hipMemsetAsync(deg, 0, (2 * 10240 + 16) * sizeof(int), stream);

  k_prep   <<<dim3(8, 8, 3), 256, 0, stream>>>(Wl2, Wr2, Wp1, Wt, Wp1t);
  k_deg    <<<(N_EDGES + 255)/256, 256, 0, stream>>>(dstp, ea, deg, asum, rank);
  k_scan   <<<1, 256, 0, stream>>>(deg, asum, offs, lattr);
  k_scatter<<<(CPK_CAP + 255)/256, 256, 0, stream>>>(srcp, dstp, ea, lattr, offs,
                                                     rank, cpk);
  k_conv1  <<<N_NODES/4, 256, 0, stream>>>(x, Wl1, bl1, Wr1, br1, We1, att1,
                                           offs, cpk, bias1, g1, be1, (uint2*)h1b);
  k_gemm_dual<<<dim3(157, 4), 256, 0, stream>>>(h1b, Wt, bl2, br2, xl2bf, xr2);
  k_conv2  <<<N_NODES/4, 256, 0, stream>>>((const uint2*)xl2bf, xr2, offs, cpk,
                                           We2, att2, bias2, g2, be2, (uint2*)h2b);
  k_policy <<<157, 256, 0, stream>>>(h2b, Wp1t, bp1, Wp2, bp2, elg, tot);
  k_sm_final<<<40, 1024, 0, stream>>>(elg, tot, out);
}

// Round 13
// 253.854 us; speedup vs baseline: 1.5350x; 1.1340x over previous
//
#include <hip/hip_runtime.h>
#include <math.h>

#define N_NODES 10000
#define N_EDGES 320000
#define N_AUG   (N_EDGES + N_NODES)
#define CPK_CAP 330752
#define HID     256

typedef short short8 __attribute__((ext_vector_type(8)));
typedef float floatx16 __attribute__((ext_vector_type(16)));

// bf16 round-to-nearest-even, as the low 16 bits of a uint
static __device__ __forceinline__ unsigned bf16rne(float f) {
  unsigned u = __float_as_uint(f);
  return (u + 0x7FFFu + ((u >> 16) & 1u)) >> 16;
}

// ------- fused front kernel ------------------------------------------------
// blocks [0,1250): degree+rank+attr-sum via ONE packed 64-bit atomic per edge
//   (count in high word; attr as biased fixed-point 2^-18 in low word --
//    addend in [0.6e6, 3.6e6], sum <= 70*3.6e6 < 2^31: no carry into count)
// blocks [1250,1442): weight conversion (W1|W2 -> Wt bf16 T, Wp1 -> Wp1t)
__global__ void __launch_bounds__(256) k_front(
    const int* __restrict__ dst, const float* __restrict__ ea,
    unsigned long long* __restrict__ pdeg, int* __restrict__ rank,
    const float* __restrict__ W1, const float* __restrict__ W2,
    const float* __restrict__ Wp1,
    unsigned short* __restrict__ Wt, unsigned short* __restrict__ Wp1t) {
  __shared__ float tile[32][33];
  int bi = blockIdx.x;
  int t = threadIdx.x;
  if (bi < 1250) {
    int e = bi * 256 + t;
    int d = dst[e];
    int fx = __float2int_rn(ea[e] * 262144.0f);       // 2^18 scale
    unsigned long long pk = 0x100000000ull
                          + (unsigned long long)(unsigned)(fx + 2097152);
    unsigned long long old = atomicAdd(&pdeg[d], pk);
    rank[e] = (int)(old >> 32);
    return;
  }
  int pb = bi - 1250;
  int z = pb >> 6;
  int rem = pb & 63;
  int kb = (rem & 7) * 32, nb = (rem >> 3) * 32;
  int tx = t & 31, ty = t >> 5;
  if (z < 2) {
    const float* W = z ? W2 : W1;
    int rowoff = z * 256;
    #pragma unroll
    for (int rep = 0; rep < 4; rep++)
      tile[ty + 8*rep][tx] = W[(kb + ty + 8*rep)*HID + nb + tx];
    __syncthreads();
    #pragma unroll
    for (int rep = 0; rep < 4; rep++) {
      int n = nb + ty + 8*rep;
      Wt[(rowoff + n)*256 + kb + tx] = (unsigned short)bf16rne(tile[tx][ty + 8*rep]);
    }
  } else {
    if (nb >= 128) return;
    #pragma unroll
    for (int rep = 0; rep < 4; rep++)
      tile[ty + 8*rep][tx] = Wp1[(kb + ty + 8*rep)*128 + nb + tx];
    __syncthreads();
    #pragma unroll
    for (int rep = 0; rep < 4; rep++) {
      int n = nb + ty + 8*rep;
      Wp1t[n*256 + kb + tx] = (unsigned short)bf16rne(tile[tx][ty + 8*rep]);
    }
  }
}

// ------- exclusive scan of (deg+1) over 10000 nodes (parallel), + loop_attr --
__global__ void __launch_bounds__(256) k_scan(
    const unsigned long long* __restrict__ pdeg,
    int* __restrict__ offs, float* __restrict__ lattr) {
  __shared__ int wsum[4];
  int t = threadIdx.x;
  int base = t * 40;
  int s = 0;
  for (int i = 0; i < 40; i++) {
    int n = base + i;
    if (n < N_NODES) s += (int)(pdeg[n] >> 32) + 1;
  }
  int v = s;
  #pragma unroll
  for (int d = 1; d < 64; d <<= 1) {
    int u = __shfl_up(v, d);
    if ((t & 63) >= d) v += u;
  }
  if ((t & 63) == 63) wsum[t >> 6] = v;
  __syncthreads();
  int wb = 0;
  for (int i = 0; i < (t >> 6); i++) wb += wsum[i];
  int run = wb + v - s;
  for (int i = 0; i < 40; i++) {
    int n = base + i;
    if (n < N_NODES) {
      offs[n] = run;
      unsigned long long pv = pdeg[n];
      int d = (int)(pv >> 32);
      run += d + 1;
      int lower = (int)(pv & 0xFFFFFFFFull);
      float asum = (float)(lower - d * 2097152) * (1.f / 262144.f);
      lattr[n] = asum / (float)max(d, 1);
    }
  }
  if (t == 255) offs[N_NODES] = wb + v;
}

// ------- scatter edges into CSR by dst (atomic-free via rank); zero pad -----
__global__ void k_scatter(const int* __restrict__ src, const int* __restrict__ dst,
                          const float* __restrict__ ea, const float* __restrict__ lattr,
                          const int* __restrict__ offs, const int* __restrict__ rank,
                          int2* __restrict__ cpk) {
  int e = blockIdx.x * blockDim.x + threadIdx.x;
  if (e >= N_AUG) {
    if (e < CPK_CAP) cpk[e] = make_int2(0, 0);   // pad: row-0, av=0
    return;
  }
  int pos, s; float a;
  if (e < N_EDGES) {
    s = src[e];
    int d = dst[e];
    a = ea[e];
    pos = offs[d] + rank[e];
  } else {
    s = e - N_EDGES;
    a = lattr[s];
    pos = offs[s + 1] - 1;    // self-loop last in segment
  }
  cpk[pos] = make_int2(s, __float_as_int(a));
}

// ============================ conv1 =========================================
#define C1_EDGE(xs, av, l0, l1, l2, l3, p)                                              \
  {                                                                                     \
    l0 = fmaf(xs.x,wl0.x, fmaf(xs.y,wl1.x, fmaf(xs.z,wl2.x, fmaf(xs.w,wl3.x, blv.x)))); \
    l1 = fmaf(xs.x,wl0.y, fmaf(xs.y,wl1.y, fmaf(xs.z,wl2.y, fmaf(xs.w,wl3.y, blv.y)))); \
    l2 = fmaf(xs.x,wl0.z, fmaf(xs.y,wl1.z, fmaf(xs.z,wl2.z, fmaf(xs.w,wl3.z, blv.z)))); \
    l3 = fmaf(xs.x,wl0.w, fmaf(xs.y,wl1.w, fmaf(xs.z,wl2.w, fmaf(xs.w,wl3.w, blv.w)))); \
    float m0 = l0 + fmaf(av, we.x, r4.x); m0 = fmaxf(m0, 0.2f*m0);                      \
    float m1 = l1 + fmaf(av, we.y, r4.y); m1 = fmaxf(m1, 0.2f*m1);                      \
    float m2 = l2 + fmaf(av, we.z, r4.z); m2 = fmaxf(m2, 0.2f*m2);                      \
    float m3 = l3 + fmaf(av, we.w, r4.w); m3 = fmaxf(m3, 0.2f*m3);                      \
    p = m0*at.x + m1*at.y + m2*at.z + m3*at.w;                                          \
  }

#define C1_BODY8()                                                              \
  {                                                                             \
    float avA = __int_as_float(eA.y), avB = __int_as_float(eB.y);               \
    float avC = __int_as_float(eC.y), avD = __int_as_float(eD.y);               \
    float avE = __int_as_float(eE.y), avF = __int_as_float(eF.y);               \
    float avG = __int_as_float(eG.y), avH = __int_as_float(eH.y);               \
    float lA0,lA1,lA2,lA3,pA, lB0,lB1,lB2,lB3,pB;                               \
    float lC0,lC1,lC2,lC3,pC, lD0,lD1,lD2,lD3,pD;                               \
    float lE0,lE1,lE2,lE3,pE, lF0,lF1,lF2,lF3,pF;                               \
    float lG0,lG1,lG2,lG3,pG, lH0,lH1,lH2,lH3,pH;                               \
    C1_EDGE(xA, avA, lA0,lA1,lA2,lA3, pA);                                      \
    C1_EDGE(xB, avB, lB0,lB1,lB2,lB3, pB);                                      \
    C1_EDGE(xC, avC, lC0,lC1,lC2,lC3, pC);                                      \
    C1_EDGE(xD, avD, lD0,lD1,lD2,lD3, pD);                                      \
    C1_EDGE(xE, avE, lE0,lE1,lE2,lE3, pE);                                      \
    C1_EDGE(xF, avF, lF0,lF1,lF2,lF3, pF);                                      \
    C1_EDGE(xG, avG, lG0,lG1,lG2,lG3, pG);                                      \
    C1_EDGE(xH, avH, lH0,lH1,lH2,lH3, pH);                                      \
    float sAB = b1 ? pA : pB, kAB = b1 ? pB : pA;                               \
    float qAB = kAB + __shfl_xor(sAB, 1);                                       \
    float sCD = b1 ? pC : pD, kCD = b1 ? pD : pC;                               \
    float qCD = kCD + __shfl_xor(sCD, 1);                                       \
    float sEF = b1 ? pE : pF, kEF = b1 ? pF : pE;                               \
    float qEF = kEF + __shfl_xor(sEF, 1);                                       \
    float sGH = b1 ? pG : pH, kGH = b1 ? pH : pG;                               \
    float qGH = kGH + __shfl_xor(sGH, 1);                                       \
    float u0s = b2 ? qAB : qCD, u0k = b2 ? qCD : qAB;                           \
    float u0 = u0k + __shfl_xor(u0s, 2);                                        \
    float u1s = b2 ? qEF : qGH, u1k = b2 ? qGH : qEF;                           \
    float u1 = u1k + __shfl_xor(u1s, 2);                                        \
    float vvs = b4 ? u0 : u1, vvk = b4 ? u1 : u0;                               \
    float vv = vvk + __shfl_xor(vvs, 4);                                        \
    vv += __shfl_xor(vv, 8);                                                    \
    float exv = expf(vv);                                                       \
    float xAe = __shfl(exv, 0, 16), xBe = __shfl(exv, 1, 16);                   \
    float xCe = __shfl(exv, 2, 16), xDe = __shfl(exv, 3, 16);                   \
    float xEe = __shfl(exv, 4, 16), xFe = __shfl(exv, 5, 16);                   \
    float xGe = __shfl(exv, 6, 16), xHe = __shfl(exv, 7, 16);                   \
    D += ((xAe + xBe) + (xCe + xDe)) + ((xEe + xFe) + (xGe + xHe));             \
    a0 = fmaf(xDe, lD0, fmaf(xCe, lC0, fmaf(xBe, lB0, fmaf(xAe, lA0, a0))));    \
    a0 = fmaf(xHe, lH0, fmaf(xGe, lG0, fmaf(xFe, lF0, fmaf(xEe, lE0, a0))));    \
    a1 = fmaf(xDe, lD1, fmaf(xCe, lC1, fmaf(xBe, lB1, fmaf(xAe, lA1, a1))));    \
    a1 = fmaf(xHe, lH1, fmaf(xGe, lG1, fmaf(xFe, lF1, fmaf(xEe, lE1, a1))));    \
    a2 = fmaf(xDe, lD2, fmaf(xCe, lC2, fmaf(xBe, lB2, fmaf(xAe, lA2, a2))));    \
    a2 = fmaf(xHe, lH2, fmaf(xGe, lG2, fmaf(xFe, lF2, fmaf(xEe, lE2, a2))));    \
    a3 = fmaf(xDe, lD3, fmaf(xCe, lC3, fmaf(xBe, lB3, fmaf(xAe, lA3, a3))));    \
    a3 = fmaf(xHe, lH3, fmaf(xGe, lG3, fmaf(xFe, lF3, fmaf(xEe, lE3, a3))));    \
  }

__global__ void __launch_bounds__(256) k_conv1(
    const float* __restrict__ x,
    const float* __restrict__ Wl, const float* __restrict__ bl,
    const float* __restrict__ Wr, const float* __restrict__ br,
    const float* __restrict__ We, const float* __restrict__ att,
    const int* __restrict__ offs, const int2* __restrict__ cpk,
    const float* __restrict__ bias, const float* __restrict__ g,
    const float* __restrict__ be, uint2* __restrict__ h1b) {
  int t = threadIdx.x;
  int n = blockIdx.x * 4 + (t >> 6);
  int c = 4 * (t & 63);
  bool b1 = (t & 1) != 0, b2 = (t & 2) != 0, b4 = (t & 4) != 0;

  float4 wl0 = *(const float4*)&Wl[0*HID + c];
  float4 wl1 = *(const float4*)&Wl[1*HID + c];
  float4 wl2 = *(const float4*)&Wl[2*HID + c];
  float4 wl3 = *(const float4*)&Wl[3*HID + c];
  float4 blv = *(const float4*)&bl[c];
  float4 we  = *(const float4*)&We[c];
  float4 at  = *(const float4*)&att[c];

  float4 xn = *(const float4*)&x[n*4];
  float4 r4;
  {
    float4 wr0 = *(const float4*)&Wr[0*HID + c];
    float4 wr1 = *(const float4*)&Wr[1*HID + c];
    float4 wr2 = *(const float4*)&Wr[2*HID + c];
    float4 wr3 = *(const float4*)&Wr[3*HID + c];
    float4 brv = *(const float4*)&br[c];
    r4.x = fmaf(xn.x,wr0.x, fmaf(xn.y,wr1.x, fmaf(xn.z,wr2.x, fmaf(xn.w,wr3.x, brv.x))));
    r4.y = fmaf(xn.x,wr0.y, fmaf(xn.y,wr1.y, fmaf(xn.z,wr2.y, fmaf(xn.w,wr3.y, brv.y))));
    r4.z = fmaf(xn.x,wr0.z, fmaf(xn.y,wr1.z, fmaf(xn.z,wr2.z, fmaf(xn.w,wr3.z, brv.z))));
    r4.w = fmaf(xn.x,wr0.w, fmaf(xn.y,wr1.w, fmaf(xn.z,wr2.w, fmaf(xn.w,wr3.w, brv.w))));
  }

  int js = __builtin_amdgcn_readfirstlane(offs[n]);
  int je = __builtin_amdgcn_readfirstlane(offs[n+1]);

  float D = 0.f, a0 = 0.f, a1 = 0.f, a2 = 0.f, a3 = 0.f;

  int j = js;
  if (je - js >= 16) {
    int2 eA = cpk[j],   eB = cpk[j+1], eC = cpk[j+2], eD = cpk[j+3];
    int2 eE = cpk[j+4], eF = cpk[j+5], eG = cpk[j+6], eH = cpk[j+7];
    int2 fA = cpk[j+8],  fB = cpk[j+9],  fC = cpk[j+10], fD = cpk[j+11];
    int2 fE = cpk[j+12], fF = cpk[j+13], fG = cpk[j+14], fH = cpk[j+15];
    float4 xA = *(const float4*)&x[eA.x*4];
    float4 xB = *(const float4*)&x[eB.x*4];
    float4 xC = *(const float4*)&x[eC.x*4];
    float4 xD = *(const float4*)&x[eD.x*4];
    float4 xE = *(const float4*)&x[eE.x*4];
    float4 xF = *(const float4*)&x[eF.x*4];
    float4 xG = *(const float4*)&x[eG.x*4];
    float4 xH = *(const float4*)&x[eH.x*4];
    for (; j + 15 < je; j += 8) {
      float4 yA = *(const float4*)&x[fA.x*4];
      float4 yB = *(const float4*)&x[fB.x*4];
      float4 yC = *(const float4*)&x[fC.x*4];
      float4 yD = *(const float4*)&x[fD.x*4];
      float4 yE = *(const float4*)&x[fE.x*4];
      float4 yF = *(const float4*)&x[fF.x*4];
      float4 yG = *(const float4*)&x[fG.x*4];
      float4 yH = *(const float4*)&x[fH.x*4];
      int2 gA = cpk[j+16], gB = cpk[j+17], gC = cpk[j+18], gD = cpk[j+19];
      int2 gE = cpk[j+20], gF = cpk[j+21], gG = cpk[j+22], gH = cpk[j+23];
      C1_BODY8();
      eA = fA; eB = fB; eC = fC; eD = fD; eE = fE; eF = fF; eG = fG; eH = fH;
      fA = gA; fB = gB; fC = gC; fD = gD; fE = gE; fF = gF; fG = gG; fH = gH;
      xA = yA; xB = yB; xC = yC; xD = yD; xE = yE; xF = yF; xG = yG; xH = yH;
    }
    C1_BODY8();
    j += 8;
  }
  for (; j + 7 < je; j += 8) {
    int2 eA = cpk[j],   eB = cpk[j+1], eC = cpk[j+2], eD = cpk[j+3];
    int2 eE = cpk[j+4], eF = cpk[j+5], eG = cpk[j+6], eH = cpk[j+7];
    float4 xA = *(const float4*)&x[eA.x*4];
    float4 xB = *(const float4*)&x[eB.x*4];
    float4 xC = *(const float4*)&x[eC.x*4];
    float4 xD = *(const float4*)&x[eD.x*4];
    float4 xE = *(const float4*)&x[eE.x*4];
    float4 xF = *(const float4*)&x[eF.x*4];
    float4 xG = *(const float4*)&x[eG.x*4];
    float4 xH = *(const float4*)&x[eH.x*4];
    C1_BODY8();
  }
  for (; j < je; j++) {
    int2 eA = cpk[j];
    float4 xA = *(const float4*)&x[eA.x*4];
    float avA = __int_as_float(eA.y);
    float lA0,lA1,lA2,lA3,pA;
    C1_EDGE(xA, avA, lA0,lA1,lA2,lA3, pA);
    #pragma unroll
    for (int msk = 1; msk < 16; msk <<= 1) pA += __shfl_xor(pA, msk);
    float eAx = expf(pA);
    D += eAx;
    a0 = fmaf(eAx, lA0, a0);
    a1 = fmaf(eAx, lA1, a1);
    a2 = fmaf(eAx, lA2, a2);
    a3 = fmaf(eAx, lA3, a3);
  }

  float inv = 1.f / D;
  float4 b4v = *(const float4*)&bias[c];
  float o0 = fmaf(a0, inv, b4v.x);
  float o1 = fmaf(a1, inv, b4v.y);
  float o2 = fmaf(a2, inv, b4v.z);
  float o3 = fmaf(a3, inv, b4v.w);

  float s = o0 + o1 + o2 + o3;
  #pragma unroll
  for (int msk = 1; msk < 64; msk <<= 1) s += __shfl_xor(s, msk);
  float mu = s * (1.f / 256.f);
  float d0 = o0 - mu, d1 = o1 - mu, d2 = o2 - mu, d3 = o3 - mu;
  float sq = d0*d0 + d1*d1 + d2*d2 + d3*d3;
  #pragma unroll
  for (int msk = 1; msk < 64; msk <<= 1) sq += __shfl_xor(sq, msk);
  float rstd = rsqrtf(sq * (1.f / 256.f) + 1e-5f);
  float4 g4  = *(const float4*)&g[c];
  float4 be4 = *(const float4*)&be[c];
  float oy0 = fmaxf(fmaf(d0 * rstd, g4.x, be4.x), 0.f);
  float oy1 = fmaxf(fmaf(d1 * rstd, g4.y, be4.y), 0.f);
  float oy2 = fmaxf(fmaf(d2 * rstd, g4.z, be4.z), 0.f);
  float oy3 = fmaxf(fmaf(d3 * rstd, g4.w, be4.w), 0.f);
  uint2 pk;
  pk.x = bf16rne(oy0) | (bf16rne(oy1) << 16);
  pk.y = bf16rne(oy2) | (bf16rne(oy3) << 16);
  h1b[n*64 + (t & 63)] = pk;
}

// ============================ conv2 =========================================
#define C2_LOAD(q, xs)                                  \
  float4 xs;                                            \
  xs.x = __uint_as_float(q.x << 16);                    \
  xs.y = __uint_as_float(q.x & 0xFFFF0000u);            \
  xs.z = __uint_as_float(q.y << 16);                    \
  xs.w = __uint_as_float(q.y & 0xFFFF0000u);

#define C2_EDGE(xs, av, p)                                           \
  {                                                                  \
    float m0 = xs.x + fmaf(av, we.x, r4.x); m0 = fmaxf(m0, 0.2f*m0); \
    float m1 = xs.y + fmaf(av, we.y, r4.y); m1 = fmaxf(m1, 0.2f*m1); \
    float m2 = xs.z + fmaf(av, we.z, r4.z); m2 = fmaxf(m2, 0.2f*m2); \
    float m3 = xs.w + fmaf(av, we.w, r4.w); m3 = fmaxf(m3, 0.2f*m3); \
    p = m0*at.x + m1*at.y + m2*at.z + m3*at.w;                       \
  }

#define C2_PROC8()                                                              \
  {                                                                             \
    C2_LOAD(q0, xs0); C2_LOAD(q1, xs1); C2_LOAD(q2, xs2); C2_LOAD(q3, xs3);     \
    C2_LOAD(q4, xs4); C2_LOAD(q5, xs5); C2_LOAD(q6, xs6); C2_LOAD(q7, xs7);     \
    float av0 = __int_as_float(e0.y), av1 = __int_as_float(e1.y);               \
    float av2 = __int_as_float(e2.y), av3 = __int_as_float(e3.y);               \
    float av4 = __int_as_float(e4.y), av5 = __int_as_float(e5.y);               \
    float av6 = __int_as_float(e6.y), av7 = __int_as_float(e7.y);               \
    float p0,p1,p2,p3,p4,p5,p6,p7;                                              \
    C2_EDGE(xs0, av0, p0); C2_EDGE(xs1, av1, p1);                               \
    C2_EDGE(xs2, av2, p2); C2_EDGE(xs3, av3, p3);                               \
    C2_EDGE(xs4, av4, p4); C2_EDGE(xs5, av5, p5);                               \
    C2_EDGE(xs6, av6, p6); C2_EDGE(xs7, av7, p7);                               \
    float sAB = b1 ? p0 : p1, kAB = b1 ? p1 : p0;                               \
    float qAB = kAB + __shfl_xor(sAB, 1);                                       \
    float sCD = b1 ? p2 : p3, kCD = b1 ? p3 : p2;                               \
    float qCD = kCD + __shfl_xor(sCD, 1);                                       \
    float sEF = b1 ? p4 : p5, kEF = b1 ? p5 : p4;                               \
    float qEF = kEF + __shfl_xor(sEF, 1);                                       \
    float sGH = b1 ? p6 : p7, kGH = b1 ? p7 : p6;                               \
    float qGH = kGH + __shfl_xor(sGH, 1);                                       \
    float u0s = b2 ? qAB : qCD, u0k = b2 ? qCD : qAB;                           \
    float u0 = u0k + __shfl_xor(u0s, 2);                                        \
    float u1s = b2 ? qEF : qGH, u1k = b2 ? qGH : qEF;                           \
    float u1 = u1k + __shfl_xor(u1s, 2);                                        \
    float vvs = b4 ? u0 : u1, vvk = b4 ? u1 : u0;                               \
    float vv = vvk + __shfl_xor(vvs, 4);                                        \
    vv += __shfl_xor(vv, 8);                                                    \
    vv += __shfl_xor(vv, 16);                                                   \
    vv += __shfl_xor(vv, 32);                                                   \
    float exv = expf(vv);                                                       \
    float x0 = __shfl(exv, 0), x1 = __shfl(exv, 1);                             \
    float x2 = __shfl(exv, 2), x3 = __shfl(exv, 3);                             \
    float x4 = __shfl(exv, 4), x5 = __shfl(exv, 5);                             \
    float x6 = __shfl(exv, 6), x7 = __shfl(exv, 7);                             \
    D += ((x0 + x1) + (x2 + x3)) + ((x4 + x5) + (x6 + x7));                     \
    a0 = fmaf(x3, xs3.x, fmaf(x2, xs2.x, fmaf(x1, xs1.x, fmaf(x0, xs0.x, a0))));\
    a0 = fmaf(x7, xs7.x, fmaf(x6, xs6.x, fmaf(x5, xs5.x, fmaf(x4, xs4.x, a0))));\
    a1 = fmaf(x3, xs3.y, fmaf(x2, xs2.y, fmaf(x1, xs1.y, fmaf(x0, xs0.y, a1))));\
    a1 = fmaf(x7, xs7.y, fmaf(x6, xs6.y, fmaf(x5, xs5.y, fmaf(x4, xs4.y, a1))));\
    a2 = fmaf(x3, xs3.z, fmaf(x2, xs2.z, fmaf(x1, xs1.z, fmaf(x0, xs0.z, a2))));\
    a2 = fmaf(x7, xs7.z, fmaf(x6, xs6.z, fmaf(x5, xs5.z, fmaf(x4, xs4.z, a2))));\
    a3 = fmaf(x3, xs3.w, fmaf(x2, xs2.w, fmaf(x1, xs1.w, fmaf(x0, xs0.w, a3))));\
    a3 = fmaf(x7, xs7.w, fmaf(x6, xs6.w, fmaf(x5, xs5.w, fmaf(x4, xs4.w, a3))));\
  }

__global__ void __launch_bounds__(256) k_conv2(
    const uint2* __restrict__ xlb, const uint2* __restrict__ xrb,
    const int* __restrict__ offs, const int2* __restrict__ cpk,
    const float* __restrict__ We, const float* __restrict__ att,
    const float* __restrict__ bias, const float* __restrict__ g,
    const float* __restrict__ be, uint2* __restrict__ h2b) {
  int t = threadIdx.x;
  int n = blockIdx.x * 4 + (t >> 6);
  int lane = t & 63;
  int c = 4 * lane;
  bool b1 = (t & 1) != 0, b2 = (t & 2) != 0, b4 = (t & 4) != 0;
  uint2 rq = xrb[n*64 + lane];
  C2_LOAD(rq, r4);
  float4 we = *(const float4*)&We[c];
  float4 at = *(const float4*)&att[c];
  int js = __builtin_amdgcn_readfirstlane(offs[n]);
  int je = __builtin_amdgcn_readfirstlane(offs[n+1]);

  float D = 0.f, a0 = 0.f, a1 = 0.f, a2 = 0.f, a3 = 0.f;

  int j = js;
  if (je - js >= 16) {
    int2 e0 = cpk[j],   e1 = cpk[j+1], e2 = cpk[j+2], e3 = cpk[j+3];
    int2 e4 = cpk[j+4], e5 = cpk[j+5], e6 = cpk[j+6], e7 = cpk[j+7];
    int2 f0 = cpk[j+8],  f1 = cpk[j+9],  f2 = cpk[j+10], f3 = cpk[j+11];
    int2 f4 = cpk[j+12], f5 = cpk[j+13], f6 = cpk[j+14], f7 = cpk[j+15];
    uint2 q0 = xlb[e0.x*64 + lane];
    uint2 q1 = xlb[e1.x*64 + lane];
    uint2 q2 = xlb[e2.x*64 + lane];
    uint2 q3 = xlb[e3.x*64 + lane];
    uint2 q4 = xlb[e4.x*64 + lane];
    uint2 q5 = xlb[e5.x*64 + lane];
    uint2 q6 = xlb[e6.x*64 + lane];
    uint2 q7 = xlb[e7.x*64 + lane];
    for (; j + 15 < je; j += 8) {
      uint2 r0 = xlb[f0.x*64 + lane];
      uint2 r1 = xlb[f1.x*64 + lane];
      uint2 r2 = xlb[f2.x*64 + lane];
      uint2 r3 = xlb[f3.x*64 + lane];
      uint2 r4_ = xlb[f4.x*64 + lane];
      uint2 r5 = xlb[f5.x*64 + lane];
      uint2 r6 = xlb[f6.x*64 + lane];
      uint2 r7 = xlb[f7.x*64 + lane];
      int2 g0 = cpk[j+16], g1 = cpk[j+17], g2 = cpk[j+18], g3 = cpk[j+19];
      int2 g4 = cpk[j+20], g5 = cpk[j+21], g6 = cpk[j+22], g7 = cpk[j+23];
      C2_PROC8();
      e0 = f0; e1 = f1; e2 = f2; e3 = f3; e4 = f4; e5 = f5; e6 = f6; e7 = f7;
      f0 = g0; f1 = g1; f2 = g2; f3 = g3; f4 = g4; f5 = g5; f6 = g6; f7 = g7;
      q0 = r0; q1 = r1; q2 = r2; q3 = r3; q4 = r4_; q5 = r5; q6 = r6; q7 = r7;
    }
    C2_PROC8();
    j += 8;
  }
  for (; j + 7 < je; j += 8) {
    int2 e0 = cpk[j],   e1 = cpk[j+1], e2 = cpk[j+2], e3 = cpk[j+3];
    int2 e4 = cpk[j+4], e5 = cpk[j+5], e6 = cpk[j+6], e7 = cpk[j+7];
    uint2 q0 = xlb[e0.x*64 + lane];
    uint2 q1 = xlb[e1.x*64 + lane];
    uint2 q2 = xlb[e2.x*64 + lane];
    uint2 q3 = xlb[e3.x*64 + lane];
    uint2 q4 = xlb[e4.x*64 + lane];
    uint2 q5 = xlb[e5.x*64 + lane];
    uint2 q6 = xlb[e6.x*64 + lane];
    uint2 q7 = xlb[e7.x*64 + lane];
    C2_PROC8();
  }
  for (; j < je; j++) {
    int2 e0 = cpk[j];
    float av0 = __int_as_float(e0.y);
    uint2 q0 = xlb[e0.x*64 + lane];
    C2_LOAD(q0, xs0);
    float p0;
    C2_EDGE(xs0, av0, p0);
    #pragma unroll
    for (int msk = 1; msk < 64; msk <<= 1) p0 += __shfl_xor(p0, msk);
    float x0 = expf(p0);
    D += x0;
    a0 = fmaf(x0, xs0.x, a0);
    a1 = fmaf(x0, xs0.y, a1);
    a2 = fmaf(x0, xs0.z, a2);
    a3 = fmaf(x0, xs0.w, a3);
  }

  float inv = 1.f / D;
  float4 b4v = *(const float4*)&bias[c];
  float o0 = fmaf(a0, inv, b4v.x);
  float o1 = fmaf(a1, inv, b4v.y);
  float o2 = fmaf(a2, inv, b4v.z);
  float o3 = fmaf(a3, inv, b4v.w);

  float s = o0 + o1 + o2 + o3;
  #pragma unroll
  for (int msk = 1; msk < 64; msk <<= 1) s += __shfl_xor(s, msk);
  float mu = s * (1.f / 256.f);
  float d0 = o0 - mu, d1 = o1 - mu, d2 = o2 - mu, d3 = o3 - mu;
  float sq = d0*d0 + d1*d1 + d2*d2 + d3*d3;
  #pragma unroll
  for (int msk = 1; msk < 64; msk <<= 1) sq += __shfl_xor(sq, msk);
  float rstd = rsqrtf(sq * (1.f / 256.f) + 1e-5f);
  float4 g4  = *(const float4*)&g[c];
  float4 be4 = *(const float4*)&be[c];
  float oy0 = fmaxf(fmaf(d0 * rstd, g4.x, be4.x), 0.f);
  float oy1 = fmaxf(fmaf(d1 * rstd, g4.y, be4.y), 0.f);
  float oy2 = fmaxf(fmaf(d2 * rstd, g4.z, be4.z), 0.f);
  float oy3 = fmaxf(fmaf(d3 * rstd, g4.w, be4.w), 0.f);
  uint2 pk;
  pk.x = bf16rne(oy0) | (bf16rne(oy1) << 16);
  pk.y = bf16rne(oy2) | (bf16rne(oy3) << 16);
  h2b[n*64 + lane] = pk;
}

// ---------------- dual GEMM: bf16 MFMA 32x32x16; O1 and O2 both bf16 --------
__global__ void __launch_bounds__(256) k_gemm_dual(
    const unsigned short* __restrict__ h1b, const unsigned short* __restrict__ Wt,
    const float* __restrict__ b1, const float* __restrict__ b2,
    unsigned short* __restrict__ O1b, unsigned short* __restrict__ O2b) {
  __shared__ unsigned short A_lds[64][72];
  __shared__ unsigned short W_lds[128][72];
  int t = threadIdx.x;
  int r0 = blockIdx.x * 64;
  int nb0 = blockIdx.y * 128;
  int l = t & 63;
  int wave = t >> 6;
  int wr = wave >> 1, wc = wave & 1;

  floatx16 acc[2] = {{0}, {0}};

  int sar = t >> 2, sak = (t & 3) * 16;
  int arow = min(r0 + sar, N_NODES - 1);
  int swn = t >> 1, swk = (t & 1) * 32;
  const unsigned short* Wrow = &Wt[(nb0 + swn) * 256];

  for (int kb = 0; kb < 256; kb += 64) {
    uint4 av0 = *(const uint4*)&h1b[arow*256 + kb + sak];
    uint4 av1 = *(const uint4*)&h1b[arow*256 + kb + sak + 8];
    uint4 wv0 = *(const uint4*)&Wrow[kb + swk];
    uint4 wv1 = *(const uint4*)&Wrow[kb + swk + 8];
    uint4 wv2 = *(const uint4*)&Wrow[kb + swk + 16];
    uint4 wv3 = *(const uint4*)&Wrow[kb + swk + 24];
    __syncthreads();
    *(uint4*)&A_lds[sar][sak]     = av0;
    *(uint4*)&A_lds[sar][sak + 8] = av1;
    *(uint4*)&W_lds[swn][swk]      = wv0;
    *(uint4*)&W_lds[swn][swk +  8] = wv1;
    *(uint4*)&W_lds[swn][swk + 16] = wv2;
    *(uint4*)&W_lds[swn][swk + 24] = wv3;
    __syncthreads();
    #pragma unroll
    for (int ks = 0; ks < 64; ks += 16) {
      short8 af  = *(const short8*)&A_lds[wr*32 + (l & 31)][ks + 8*(l >> 5)];
      short8 bf0 = *(const short8*)&W_lds[wc*64      + (l & 31)][ks + 8*(l >> 5)];
      short8 bf1 = *(const short8*)&W_lds[wc*64 + 32 + (l & 31)][ks + 8*(l >> 5)];
      acc[0] = __builtin_amdgcn_mfma_f32_32x32x16_bf16(af, bf0, acc[0], 0, 0, 0);
      acc[1] = __builtin_amdgcn_mfma_f32_32x32x16_bf16(af, bf1, acc[1], 0, 0, 0);
    }
  }

  bool isO1 = (nb0 < 256);
  #pragma unroll
  for (int tile = 0; tile < 2; tile++) {
    int col = nb0 + wc*64 + tile*32 + (l & 31);
    float bias = isO1 ? b1[col] : b2[col - 256];
    #pragma unroll
    for (int reg = 0; reg < 16; reg++) {
      int row = (reg & 3) + 8*(reg >> 2) + 4*(l >> 5);
      int r = r0 + wr*32 + row;
      if (r < N_NODES) {
        float v = acc[tile][reg] + bias;
        if (isO1) O1b[r*256 + col] = (unsigned short)bf16rne(v);
        else      O2b[r*256 + (col - 256)] = (unsigned short)bf16rne(v);
      }
    }
  }
}

// ------- policy: bf16 MFMA phase1 (64x128), LDS hid, phase2 + exp -----------
__global__ void __launch_bounds__(256) k_policy(
    const unsigned short* __restrict__ h2b, const unsigned short* __restrict__ Wp1t,
    const float* __restrict__ bp1, const float* __restrict__ Wp2,
    const float* __restrict__ bp2, float* __restrict__ elg, float* __restrict__ tot) {
  __shared__ __align__(16) char smembuf[64 * 132 * 4];   // 33792 B union
  unsigned short* A_lds = (unsigned short*)smembuf;                  // [64][72]
  unsigned short* W_lds = (unsigned short*)(smembuf + 64*72*2);      // [128][72]
  float* hidl = (float*)smembuf;                                     // [64][132]
  __shared__ float wred[4];
  int t = threadIdx.x;
  int r0 = blockIdx.x * 64;
  int l = t & 63;
  int wave = t >> 6;
  int wr = wave >> 1, wc = wave & 1;

  floatx16 acc[2] = {{0}, {0}};

  int sar = t >> 2, sak = (t & 3) * 16;
  int arow = min(r0 + sar, N_NODES - 1);
  int swn = t >> 1, swk = (t & 1) * 32;
  const unsigned short* Wrow = &Wp1t[swn * 256];

  for (int kb = 0; kb < 256; kb += 64) {
    uint4 av0 = *(const uint4*)&h2b[arow*256 + kb + sak];
    uint4 av1 = *(const uint4*)&h2b[arow*256 + kb + sak + 8];
    uint4 wv0 = *(const uint4*)&Wrow[kb + swk];
    uint4 wv1 = *(const uint4*)&Wrow[kb + swk + 8];
    uint4 wv2 = *(const uint4*)&Wrow[kb + swk + 16];
    uint4 wv3 = *(const uint4*)&Wrow[kb + swk + 24];
    __syncthreads();
    *(uint4*)&A_lds[sar*72 + sak]     = av0;
    *(uint4*)&A_lds[sar*72 + sak + 8] = av1;
    *(uint4*)&W_lds[swn*72 + swk]      = wv0;
    *(uint4*)&W_lds[swn*72 + swk +  8] = wv1;
    *(uint4*)&W_lds[swn*72 + swk + 16] = wv2;
    *(uint4*)&W_lds[swn*72 + swk + 24] = wv3;
    __syncthreads();
    #pragma unroll
    for (int ks = 0; ks < 64; ks += 16) {
      short8 af  = *(const short8*)&A_lds[(wr*32 + (l & 31))*72 + ks + 8*(l >> 5)];
      short8 bf0 = *(const short8*)&W_lds[(wc*64      + (l & 31))*72 + ks + 8*(l >> 5)];
      short8 bf1 = *(const short8*)&W_lds[(wc*64 + 32 + (l & 31))*72 + ks + 8*(l >> 5)];
      acc[0] = __builtin_amdgcn_mfma_f32_32x32x16_bf16(af, bf0, acc[0], 0, 0, 0);
      acc[1] = __builtin_amdgcn_mfma_f32_32x32x16_bf16(af, bf1, acc[1], 0, 0, 0);
    }
  }
  __syncthreads();   // A/W dead; smem becomes hidl[64][132]
  #pragma unroll
  for (int tile = 0; tile < 2; tile++) {
    int col = wc*64 + tile*32 + (l & 31);
    float bias = bp1[col];
    #pragma unroll
    for (int reg = 0; reg < 16; reg++) {
      int row = (reg & 3) + 8*(reg >> 2) + 4*(l >> 5) + wr*32;
      hidl[row*132 + col] = fmaxf(acc[tile][reg] + bias, 0.f);
    }
  }
  __syncthreads();
  int nl = t >> 2, i = t & 3;
  float s = bp2[i];
  for (int k = 0; k < 128; k += 4) {
    float4 hv = *(const float4*)&hidl[nl*132 + k];
    s = fmaf(hv.x, Wp2[(k+0)*4 + i],
        fmaf(hv.y, Wp2[(k+1)*4 + i],
        fmaf(hv.z, Wp2[(k+2)*4 + i],
        fmaf(hv.w, Wp2[(k+3)*4 + i], s))));
  }
  int n = r0 + nl;
  float esum = 0.f;
  if (n < N_NODES) {
    float e = expf(s);
    elg[n*4 + i] = e;
    esum = e;
  }
  #pragma unroll
  for (int msk = 1; msk < 64; msk <<= 1) esum += __shfl_xor(esum, msk);
  if ((t & 63) == 0) wred[t >> 6] = esum;
  __syncthreads();
  if (t == 0) atomicAdd(tot, (wred[0] + wred[1]) + (wred[2] + wred[3]));
}

// ---------------- normalize: out = elg * (1/tot) ----------------------------
__global__ void __launch_bounds__(1024) k_sm_final(const float* __restrict__ elg,
                                                   const float* __restrict__ tot,
                                                   float* __restrict__ out) {
  int i = blockIdx.x * 1024 + threadIdx.x;
  float inv = 1.f / tot[0];
  if (i < N_NODES * 4) out[i] = elg[i] * inv;
}

extern "C" void kernel_launch(void* const* d_in, const int* in_sizes, int n_in,
                              void* d_out, int out_size, void* d_ws, size_t ws_size,
                              hipStream_t stream) {
  const float* x    = (const float*)d_in[0];
  const int*   ei   = (const int*)  d_in[1];
  const float* ea   = (const float*)d_in[2];
  const float* Wl1  = (const float*)d_in[3];
  const float* bl1  = (const float*)d_in[4];
  const float* Wr1  = (const float*)d_in[5];
  const float* br1  = (const float*)d_in[6];
  const float* We1  = (const float*)d_in[7];
  const float* att1 = (const float*)d_in[8];
  const float* bias1= (const float*)d_in[9];
  const float* g1   = (const float*)d_in[10];
  const float* be1  = (const float*)d_in[11];
  const float* Wl2  = (const float*)d_in[12];
  const float* bl2  = (const float*)d_in[13];
  const float* Wr2  = (const float*)d_in[14];
  const float* br2  = (const float*)d_in[15];
  const float* We2  = (const float*)d_in[16];
  const float* att2 = (const float*)d_in[17];
  const float* bias2= (const float*)d_in[18];
  const float* g2   = (const float*)d_in[19];
  const float* be2  = (const float*)d_in[20];
  const float* Wp1  = (const float*)d_in[21];
  const float* bp1  = (const float*)d_in[22];
  const float* Wp2  = (const float*)d_in[23];
  const float* bp2  = (const float*)d_in[24];
  float* out = (float*)d_out;

  const int* srcp = ei;
  const int* dstp = ei + N_EDGES;

  // workspace layout: [pdeg | tot] zeroed in ONE memset
  unsigned long long* pdeg = (unsigned long long*)d_ws;    // 10240 x 8B
  float* tot   = (float*)(pdeg + 10240);     // 16
  int*   offs  = (int*)(tot + 16);           // 10240
  float* lattr = (float*)(offs + 10240);     // 10240
  int*   rank  = (int*)(lattr + 10240);      // 320192
  int2*  cpk   = (int2*)(rank + 320192);     // CPK_CAP int2 (pad zeroed by scatter)
  unsigned short* h1b   = (unsigned short*)(cpk + CPK_CAP);  // 10000x256 bf16
  unsigned short* h2b   = h1b;               // conv2 output aliases (h1b dead)
  unsigned short* xl2bf = h1b + 2560000;     // 10000x256 bf16
  unsigned short* xr2b  = xl2bf + 2560000;   // 10000x256 bf16
  float* elg   = (float*)(xr2b + 2560000);   // 40960
  unsigned short* Wt   = (unsigned short*)(elg + 40960);   // 512x256 bf16
  unsigned short* Wp1t = Wt + 512*256;                     // 128x256 bf16

  hipMemsetAsync(pdeg, 0, 10240 * 8 + 64, stream);

  k_front  <<<1250 + 192, 256, 0, stream>>>(dstp, ea, pdeg, rank,
                                            Wl2, Wr2, Wp1, Wt, Wp1t);
  k_scan   <<<1, 256, 0, stream>>>(pdeg, offs, lattr);
  k_scatter<<<(CPK_CAP + 255)/256, 256, 0, stream>>>(srcp, dstp, ea, lattr, offs,
                                                     rank, cpk);
  k_conv1  <<<N_NODES/4, 256, 0, stream>>>(x, Wl1, bl1, Wr1, br1, We1, att1,
                                           offs, cpk, bias1, g1, be1, (uint2*)h1b);
  k_gemm_dual<<<dim3(157, 4), 256, 0, stream>>>(h1b, Wt, bl2, br2, xl2bf, xr2b);
  k_conv2  <<<N_NODES/4, 256, 0, stream>>>((const uint2*)xl2bf, (const uint2*)xr2b,
                                           offs, cpk, We2, att2, bias2, g2, be2,
                                           (uint2*)h2b);
  k_policy <<<157, 256, 0, stream>>>(h2b, Wp1t, bp1, Wp2, bp2, elg, tot);
  k_sm_final<<<40, 1024, 0, stream>>>(elg, tot, out);
}